// Round 3
// baseline (517.176 us; speedup 1.0000x reference)
//
#include <hip/hip_runtime.h>
#include <hip/hip_bf16.h>

typedef __hip_bfloat16 bf16;
typedef short s16x8 __attribute__((ext_vector_type(8)));
typedef float f32x4 __attribute__((ext_vector_type(4)));
union V16 { uint4 u4; s16x8 s8; unsigned u[4]; unsigned short s[8]; };

static __device__ __forceinline__ float b2f(bf16 v){ return __bfloat162float(v); }
static __device__ __forceinline__ bf16  f2b(float v){ return __float2bfloat16(v); }
static __device__ __forceinline__ unsigned short f2bs(float x){
    union { float f; unsigned u; } c; c.f = x;
    unsigned r = c.u + 0x7fff + ((c.u >> 16) & 1);
    return (unsigned short)(r >> 16);
}
static __device__ __forceinline__ float bu2f(unsigned short b){
    union { unsigned u; float f; } c; c.u = ((unsigned)b) << 16; return c.f;
}
static __device__ __forceinline__ s16x8 ld16g(const bf16* p){
    V16 u; u.u4 = *(const uint4*)p; return u.s8;
}
static __device__ __forceinline__ void glds16(const void* g, void* l){
    __builtin_amdgcn_global_load_lds(
        (const __attribute__((address_space(1))) unsigned*)g,
        (__attribute__((address_space(3))) unsigned*)l, 16, 0, 0);
}

#define SCALE_T 0.17677669529663687f   // 32^-0.5

// ---------------------------------------------------------------------------
// prep_weights: transpose+convert weights to bf16 Wt[N][K] layouts.
//   [0,196608)        qkv_w   -> Wt[768][256]
//   [196608,262144)   q_proj  -> Wt[256][256]
//   [262144,327680)   proj    -> Wt[256][256]
//   [327680,475136)   glob_k  -> Wt_kv rows 0..383   [384]
//   [475136,622592)   glob_v  -> Wt_kv rows 384..767 [384]
// ---------------------------------------------------------------------------
__global__ __launch_bounds__(256) void prep_weights(
    const float* __restrict__ qkvw, const float* __restrict__ qpw,
    const float* __restrict__ pw,   const float* __restrict__ gkw,
    const float* __restrict__ gvw,  bf16* __restrict__ Wt)
{
    int idx = blockIdx.x * 256 + threadIdx.x;   // < 622592 exact
    float v;
    if (idx < 196608)      { int j = idx;          int n = j >> 8, k = j & 255; v = qkvw[k * 768 + n]; }
    else if (idx < 262144) { int j = idx - 196608; int n = j >> 8, k = j & 255; v = qpw[k * 256 + n]; }
    else if (idx < 327680) { int j = idx - 262144; int n = j >> 8, k = j & 255; v = pw[k * 256 + n]; }
    else if (idx < 475136) { int j = idx - 327680; int n = j / 384, k = j - n * 384; v = gkw[k * 384 + n]; }
    else                   { int j = idx - 475136; int n = j / 384, k = j - n * 384; v = gvw[k * 384 + n]; }
    ((unsigned short*)Wt)[idx] = f2bs(v);
}

// f32 -> bf16 packed conversion (4 elems per thread). grid*256*4 == n exactly.
__global__ __launch_bounds__(256) void convert_f32_bf16(
    const float* __restrict__ in, bf16* __restrict__ out)
{
    int i = blockIdx.x * 256 + threadIdx.x;
    float4 v = ((const float4*)in)[i];
    ushort4 o;
    o.x = f2bs(v.x); o.y = f2bs(v.y); o.z = f2bs(v.z); o.w = f2bs(v.w);
    ((ushort4*)out)[i] = o;
}

// tokb[row][0:64] = bf16(dth[row]);  tokb[row][64:128] = bf16(seg[row]).
// 8 elems/thread, grid = 1568 blocks (401408 threads exact).
__global__ __launch_bounds__(256) void tok2b_kernel(
    const float* __restrict__ dth, const float* __restrict__ seg,
    bf16* __restrict__ tokb)
{
    int i = blockIdx.x * 256 + threadIdx.x;   // < 401408
    int row = i >> 4, j8 = i & 15;
    const float* src = (j8 < 8) ? (dth + (size_t)row * 64 + j8 * 8)
                                : (seg + (size_t)row * 64 + (j8 - 8) * 8);
    float4 u0 = ((const float4*)src)[0];
    float4 u1 = ((const float4*)src)[1];
    V16 o;
    o.s[0] = f2bs(u0.x); o.s[1] = f2bs(u0.y);
    o.s[2] = f2bs(u0.z); o.s[3] = f2bs(u0.w);
    o.s[4] = f2bs(u1.x); o.s[5] = f2bs(u1.y);
    o.s[6] = f2bs(u1.z); o.s[7] = f2bs(u1.w);
    *(uint4*)(tokb + (size_t)row * 128 + j8 * 8) = o.u4;
}

// ---------------------------------------------------------------------------
// gemm_bb: out = (A[M,K]bf16 @ Wt[N,K]^T + bias [+ add]) * scale
// 128x128 tile, BK=32, 4 waves (2x2), double-buffered LDS, pure
// global_load_lds staging with k-quad XOR swizzle baked into global source.
// TOK: K-tiles >= 256 come from A2 (bf16, lda 128) -> still pure glds.
// ---------------------------------------------------------------------------
template<int TOK>
__global__ __launch_bounds__(256, 4) void gemm_bb(
    const bf16* __restrict__ A, int lda, const bf16* __restrict__ A2,
    const bf16* __restrict__ Wt, const float* __restrict__ bias,
    const float* __restrict__ bias2,
    const bf16* __restrict__ addp, int addStride,
    float* __restrict__ outF, bf16* __restrict__ outB, int outStrideB,
    int K, int N, float scale)
{
    __shared__ char lds[2][16384];            // per buf: A 8KB | B 8KB

    const int tid = threadIdx.x;
    const int wv = tid >> 6, lane = tid & 63;
    const int quad = lane >> 4, l15 = lane & 15;
    const int wr = wv >> 1, wc = wv & 1;

    const int gx = (int)gridDim.x;
    const int nwg = gx * (int)gridDim.y;
    int bid = (int)blockIdx.y * gx + (int)blockIdx.x;
    if ((nwg & 7) == 0) bid = (bid & 7) * (nwg >> 3) + (bid >> 3);
    const int bx = bid % gx, by = bid / gx;
    const int rowBase = by * 128, colBase = bx * 128;

    const int srow = tid >> 2;
    const int kOffE = (((tid & 3) ^ ((srow >> 1) & 3)) << 3);   // elems

    const unsigned swz = (unsigned)((quad ^ ((l15 >> 1) & 3)) << 4);
    const unsigned aoff0 = (unsigned)(wr * 4096 + l15 * 64) + swz;
    const unsigned boff0 = (unsigned)(wc * 4096 + l15 * 64) + swz;

    f32x4 acc[4][4];
    #pragma unroll
    for (int m = 0; m < 4; ++m)
        #pragma unroll
        for (int n = 0; n < 4; ++n)
            #pragma unroll
            for (int r = 0; r < 4; ++r) acc[m][n][r] = 0.f;

    auto stage = [&](int sbuf, int kt) {
        char* base = &lds[sbuf][0];
        #pragma unroll
        for (int c = 0; c < 2; ++c)
            glds16(Wt + (size_t)(colBase + c * 64 + srow) * K + (kt + kOffE),
                   base + 8192 + c * 4096 + tid * 16);
        if (!TOK || kt < 256) {
            #pragma unroll
            for (int c = 0; c < 2; ++c)
                glds16(A + (size_t)(rowBase + c * 64 + srow) * lda + (kt + kOffE),
                       base + c * 4096 + tid * 16);
        } else {
            #pragma unroll
            for (int c = 0; c < 2; ++c)
                glds16(A2 + (size_t)(rowBase + c * 64 + srow) * 128 + (kt - 256 + kOffE),
                       base + c * 4096 + tid * 16);
        }
    };

    stage(0, 0);
    __syncthreads();
    int buf = 0;
    for (int kt = 0; kt < K; kt += 32) {
        if (kt + 32 < K) stage(buf ^ 1, kt + 32);
        const char* Ab2 = &lds[buf][0];
        const char* Bb2 = Ab2 + 8192;
        s16x8 af[4], bfr[4];
        #pragma unroll
        for (int m = 0; m < 4; ++m) af[m]  = *(const s16x8*)(Ab2 + aoff0 + m * 1024);
        #pragma unroll
        for (int n = 0; n < 4; ++n) bfr[n] = *(const s16x8*)(Bb2 + boff0 + n * 1024);
        #pragma unroll
        for (int m = 0; m < 4; ++m)
            #pragma unroll
            for (int n = 0; n < 4; ++n)
                acc[m][n] = __builtin_amdgcn_mfma_f32_16x16x32_bf16(af[m], bfr[n], acc[m][n], 0, 0, 0);
        __syncthreads();
        buf ^= 1;
    }

    // ---- epilogue ----
    if (outB) {
        #pragma unroll
        for (int n = 0; n < 4; ++n) {
            int col = colBase + wc * 64 + n * 16 + l15;
            float bb = bias2 ? (col < 384 ? bias[col] : bias2[col - 384]) : bias[col];
            #pragma unroll
            for (int m = 0; m < 4; ++m) {
                #pragma unroll
                for (int r = 0; r < 4; ++r) {
                    int rl = wr * 64 + m * 16 + quad * 4 + r;
                    float v = acc[m][n][r] + bb;
                    if (addp) v += b2f(addp[(size_t)(rowBase + rl) * addStride + col]);
                    v *= scale;
                    if (outF) outF[(size_t)(rowBase + rl) * N + col] = v;
                    int cbyte = (wc * 64 + n * 16 + l15) * 2;
                    int blk = ((cbyte >> 5) ^ ((rl >> 2) & 7)) & 7;
                    *(unsigned short*)((char*)lds + rl * 256 + (blk << 5) + (cbyte & 31)) = f2bs(v);
                }
            }
        }
        __syncthreads();
        #pragma unroll
        for (int i = 0; i < 8; ++i) {
            int lin = i * 256 + tid;
            int rl = lin >> 4, cb = lin & 15;
            int cb2 = ((((cb >> 1) ^ ((rl >> 2) & 7)) & 7) << 1) | (cb & 1);
            uint4 val = *(const uint4*)((const char*)lds + rl * 256 + cb2 * 16);
            *(uint4*)(outB + (size_t)(rowBase + rl) * outStrideB + colBase + cb * 8) = val;
        }
    } else {
        #pragma unroll
        for (int n = 0; n < 4; ++n) {
            int col = colBase + wc * 64 + n * 16 + l15;
            float bb = bias2 ? (col < 384 ? bias[col] : bias2[col - 384]) : bias[col];
            #pragma unroll
            for (int m = 0; m < 4; ++m) {
                #pragma unroll
                for (int r = 0; r < 4; ++r) {
                    int rl = wr * 64 + m * 16 + quad * 4 + r;
                    float v = acc[m][n][r] + bb;
                    if (addp) v += b2f(addp[(size_t)(rowBase + rl) * addStride + col]);
                    v *= scale;
                    if (outF) outF[(size_t)(rowBase + rl) * N + col] = v;
                }
            }
        }
    }
}

// ---------------------------------------------------------------------------
// small64: out[M,64] = (A[M,64] @ W[64,64] + bias) * scale, two tasks via
// blockIdx.y. W f32 transposed to bf16 via LDS once per block; A fragments
// loaded straight to registers; 8 MFMA per wave; 64 rows per block.
// ---------------------------------------------------------------------------
template<int AF32, int OF32>
__global__ __launch_bounds__(256) void small64(
    const void* __restrict__ a0, const void* __restrict__ a1,
    const float* __restrict__ w0, const float* __restrict__ w1,
    const float* __restrict__ b0, const float* __restrict__ b1,
    void* __restrict__ o0, void* __restrict__ o1, float scale)
{
    __shared__ unsigned short WT[64 * 72];
    __shared__ float bsh[64];
    const int task = blockIdx.y;
    const void*  A    = task ? a1 : a0;
    const float* W    = task ? w1 : w0;
    const float* bias = task ? b1 : b0;
    void*        outp = task ? o1 : o0;

    int tid = threadIdx.x;
    for (int l = tid; l < 4096; l += 256) {
        int k = l >> 6, n = l & 63;
        WT[n * 72 + k] = f2bs(W[l]);
    }
    if (tid < 64) bsh[tid] = bias[tid];
    __syncthreads();

    const int wv = tid >> 6, lane = tid & 63;
    const int quad = lane >> 4, l15 = lane & 15;
    const int rowBase = blockIdx.x * 64;
    const int arow = rowBase + wv * 16 + l15;

    s16x8 a[2];
    if (AF32) {
        const float* Ar = (const float*)A + (size_t)arow * 64;
        #pragma unroll
        for (int ks = 0; ks < 2; ++ks) {
            float4 u0 = *(const float4*)(Ar + ks * 32 + quad * 8);
            float4 u1 = *(const float4*)(Ar + ks * 32 + quad * 8 + 4);
            V16 o;
            o.s[0] = f2bs(u0.x); o.s[1] = f2bs(u0.y);
            o.s[2] = f2bs(u0.z); o.s[3] = f2bs(u0.w);
            o.s[4] = f2bs(u1.x); o.s[5] = f2bs(u1.y);
            o.s[6] = f2bs(u1.z); o.s[7] = f2bs(u1.w);
            a[ks] = o.s8;
        }
    } else {
        const bf16* Ar = (const bf16*)A + (size_t)arow * 64;
        #pragma unroll
        for (int ks = 0; ks < 2; ++ks)
            a[ks] = ld16g(Ar + ks * 32 + quad * 8);
    }

    f32x4 acc[4];
    #pragma unroll
    for (int n = 0; n < 4; ++n)
        #pragma unroll
        for (int r = 0; r < 4; ++r) acc[n][r] = 0.f;

    #pragma unroll
    for (int ks = 0; ks < 2; ++ks)
        #pragma unroll
        for (int n = 0; n < 4; ++n) {
            s16x8 b = *(const s16x8*)&WT[(n * 16 + l15) * 72 + ks * 32 + quad * 8];
            acc[n] = __builtin_amdgcn_mfma_f32_16x16x32_bf16(a[ks], b, acc[n], 0, 0, 0);
        }

    #pragma unroll
    for (int n = 0; n < 4; ++n) {
        int col = n * 16 + l15;
        float bb = bsh[col];
        #pragma unroll
        for (int r = 0; r < 4; ++r) {
            int row = rowBase + wv * 16 + quad * 4 + r;
            float v = (acc[n][r] + bb) * scale;
            if (OF32) ((float*)outp)[(size_t)row * 64 + col] = v;
            else      ((bf16*)outp)[(size_t)row * 64 + col] = f2b(v);
        }
    }
}

// ---------------------------------------------------------------------------
// Small MFMA GEMM (kept for step 2's tiny 256x512 shape).
// ---------------------------------------------------------------------------
__global__ __launch_bounds__(256) void mfma_gemm(
    const void* __restrict__ A, int a_mode,
    const float* __restrict__ W, const float* __restrict__ bias,
    float* __restrict__ outF, bf16* __restrict__ outB,
    int M, int K, int N, float scale)
{
    __shared__ __hip_bfloat16 Al[64][48];
    __shared__ __hip_bfloat16 Bl[64][48];

    const int tid  = threadIdx.x;
    const int wv   = tid >> 6, lane = tid & 63;
    const int quad = lane >> 4, l15 = lane & 15;
    const int rowBase = blockIdx.y * 64, colBase = blockIdx.x * 64;

    const int am = tid >> 2, ak = (tid & 3) * 8;
    const int bn = tid & 63, bk = (tid >> 6) * 8;

    f32x4 acc[4];
    #pragma unroll
    for (int t = 0; t < 4; ++t)
        #pragma unroll
        for (int r = 0; r < 4; ++r) acc[t][r] = 0.f;

    for (int kt = 0; kt < K; kt += 32) {
        s16x8 sa;
        if (a_mode == 1) {
            const bf16* Ab = (const bf16*)A;
            V16 u; u.u4 = *(const uint4*)(Ab + (size_t)(rowBase + am) * K + kt + ak);
            sa = u.s8;
        } else {
            const float* src = (const float*)A;
            const float4* p = (const float4*)(src + (size_t)(rowBase + am) * K + kt + ak);
            float4 u0 = p[0], u1 = p[1];
            sa[0] = (short)f2bs(u0.x); sa[1] = (short)f2bs(u0.y);
            sa[2] = (short)f2bs(u0.z); sa[3] = (short)f2bs(u0.w);
            sa[4] = (short)f2bs(u1.x); sa[5] = (short)f2bs(u1.y);
            sa[6] = (short)f2bs(u1.z); sa[7] = (short)f2bs(u1.w);
        }
        *(s16x8*)&Al[am][ak] = sa;

        s16x8 sb;
        #pragma unroll
        for (int j = 0; j < 8; ++j)
            sb[j] = (short)f2bs(W[(size_t)(kt + bk + j) * N + colBase + bn]);
        *(s16x8*)&Bl[bn][bk] = sb;

        __syncthreads();

        s16x8 a = *(const s16x8*)&Al[wv * 16 + l15][quad * 8];
        #pragma unroll
        for (int t = 0; t < 4; ++t) {
            s16x8 b = *(const s16x8*)&Bl[t * 16 + l15][quad * 8];
            acc[t] = __builtin_amdgcn_mfma_f32_16x16x32_bf16(a, b, acc[t], 0, 0, 0);
        }
        __syncthreads();
    }

    #pragma unroll
    for (int t = 0; t < 4; ++t) {
        int col = colBase + t * 16 + l15;
        float bb = bias[col];
        #pragma unroll
        for (int r = 0; r < 4; ++r) {
            int row = rowBase + wv * 16 + quad * 4 + r;
            float v = (acc[t][r] + bb) * scale;
            if (outF) outF[(size_t)row * N + col] = v;
            if (outB) outB[(size_t)row * N + col] = f2b(v);
        }
    }
}

// ---------------------------------------------------------------------------
// ref_q_t[r,h,f,d] = mu[c] + exp(ls[c]) * ref_qk[r*32+f, c];  ref_v_t from +256
// ---------------------------------------------------------------------------
__global__ __launch_bounds__(256) void refprep_kernel(
    const float* __restrict__ ref_qk, const float* __restrict__ mu,
    const float* __restrict__ ls, float* __restrict__ ref_q_t,
    float* __restrict__ ref_v_t)
{
    int idx = blockIdx.x * 256 + threadIdx.x;          // [r,h,f,d]
    int d = idx & 31, f = (idx >> 5) & 31, h = (idx >> 10) & 7, r = idx >> 13;
    int c = h * 32 + d;
    size_t src = (size_t)(r * 32 + f) * 512 + c;
    ref_q_t[idx] = mu[c] + __expf(ls[c]) * ref_qk[src];
    ref_v_t[idx] = ref_qk[src + 256];
}

// ---------------------------------------------------------------------------
// ref_attn[r,h,w,n,f] = sum_d (q[b,h,n,d]*SCALE) * ref_q_t[r,h,f,d]
// Also zeroes the 384-float statsA slab (block 0) for the diffusion loop.
// ---------------------------------------------------------------------------
__global__ __launch_bounds__(256) void refattn_kernel(
    const bf16* __restrict__ qkv, const float* __restrict__ ref_q_t,
    bf16* __restrict__ ref_attn, float* __restrict__ statsA)
{
    int blk = blockIdx.x;
    int tid = threadIdx.x;
    if (blk == 0 && tid < 384) statsA[tid] = 0.f;
    int w = blk & 63, h = (blk >> 6) & 7, r = blk >> 9;
    int b = r * 64 + w;
    __shared__ float qt[49 * 32];
    __shared__ float rq[32 * 33];
    for (int l = tid; l < 1568; l += 256) {
        int n = l >> 5, d = l & 31;
        qt[l] = b2f(qkv[(size_t)(b * 49 + n) * 768 + h * 32 + d]) * SCALE_T;
    }
    for (int l = tid; l < 1024; l += 256) {
        int f = l >> 5, d = l & 31;
        rq[f * 33 + d] = ref_q_t[(size_t)((r * 8 + h) * 32 + f) * 32 + d];
    }
    __syncthreads();
    for (int l = tid; l < 1568; l += 256) {
        int n = l >> 5, f = l & 31;
        float acc = 0.f;
        #pragma unroll
        for (int d2 = 0; d2 < 32; ++d2) acc += qt[n * 32 + d2] * rq[f * 33 + d2];
        ref_attn[(size_t)(((r * 8 + h) * 64 + w) * 49 + n) * 32 + f] = f2b(acc);
    }
}

// ---------------------------------------------------------------------------
// 3x3 SAME conv over [RB=8, 8ch, 3136, 32] + fused LN-stats partial sums
// (per-(r,o) sum / sumsq atomically accumulated into statsIt[g*2(+1)]).
// ---------------------------------------------------------------------------
__global__ __launch_bounds__(256) void conv_kernel(
    const bf16* __restrict__ in, const float* __restrict__ conv_w,
    const float* __restrict__ conv_b, bf16* __restrict__ u,
    float* __restrict__ statsIt)
{
    __shared__ float w_s[576];
    __shared__ float b_s[8];
    __shared__ float red1[4][8], red2[4][8];
    int tid = threadIdx.x;
    for (int l = tid; l < 576; l += 256) w_s[l] = conv_w[l];
    if (tid < 8) b_s[tid] = conv_b[tid];
    __syncthreads();

    int idx = blockIdx.x * 256 + tid;          // < 100352
    int fb = idx & 3;
    int p  = (idx >> 2) % 3136;
    int r  = idx / 12544;
    int f0 = fb * 8;

    float acc[8][8];
    #pragma unroll
    for (int o = 0; o < 8; ++o) {
        float bo = b_s[o];
        #pragma unroll
        for (int f = 0; f < 8; ++f) acc[o][f] = bo;
    }

    for (int i = 0; i < 8; ++i) {
        float ext[3][10];
        #pragma unroll
        for (int dy = 0; dy < 3; ++dy) {
            int pp = p + dy - 1;
            bool pv = (unsigned)pp < 3136u;
            size_t base = ((size_t)((r * 8 + i) * 3136 + (pv ? pp : 0))) * 32 + f0;
            V16 uv;
            uv.u4 = pv ? *(const uint4*)(in + base) : make_uint4(0, 0, 0, 0);
            #pragma unroll
            for (int j = 0; j < 8; ++j) {
                unsigned sh = uv.u[j >> 1];
                unsigned bits = (j & 1) ? (sh & 0xffff0000u) : (sh << 16);
                union { unsigned uu; float fl; } cv; cv.uu = bits;
                ext[dy][j + 1] = cv.fl;
            }
            ext[dy][0] = (pv && f0 > 0)      ? b2f(in[base - 1]) : 0.f;
            ext[dy][9] = (pv && f0 + 8 < 32) ? b2f(in[base + 8]) : 0.f;
        }
        #pragma unroll
        for (int o = 0; o < 8; ++o) {
            #pragma unroll
            for (int ky = 0; ky < 3; ++ky) {
                const float* wp = &w_s[((o * 8 + i) * 3 + ky) * 3];
                float w0 = wp[0], w1 = wp[1], w2 = wp[2];
                #pragma unroll
                for (int f = 0; f < 8; ++f)
                    acc[o][f] += ext[ky][f] * w0 + ext[ky][f + 1] * w1 + ext[ky][f + 2] * w2;
            }
        }
    }

    float so[8], s2o[8];
    #pragma unroll
    for (int o = 0; o < 8; ++o) {
        bf16 ov[8];
        float s = 0.f, s2 = 0.f;
        #pragma unroll
        for (int f = 0; f < 8; ++f) {
            ov[f] = f2b(acc[o][f]);
            s += acc[o][f]; s2 += acc[o][f] * acc[o][f];
        }
        so[o] = s; s2o[o] = s2;
        *(uint4*)(u + ((size_t)((r * 8 + o) * 3136 + p)) * 32 + f0) = *(uint4*)ov;
    }

    // wave butterfly then cross-wave + 16 atomics per block
    #pragma unroll
    for (int o = 0; o < 8; ++o) {
        #pragma unroll
        for (int off = 32; off > 0; off >>= 1) {
            so[o]  += __shfl_xor(so[o],  off);
            s2o[o] += __shfl_xor(s2o[o], off);
        }
    }
    int wv = tid >> 6, lane = tid & 63;
    if (lane == 0) {
        #pragma unroll
        for (int o = 0; o < 8; ++o) { red1[wv][o] = so[o]; red2[wv][o] = s2o[o]; }
    }
    __syncthreads();
    if (tid < 8) {
        float s = red1[0][tid] + red1[1][tid] + red1[2][tid] + red1[3][tid];
        float s2 = red2[0][tid] + red2[1][tid] + red2[2][tid] + red2[3][tid];
        int g = r * 8 + tid;
        atomicAdd(&statsIt[g * 2], s);
        atomicAdd(&statsIt[g * 2 + 1], s2);
    }
}

// ref_attn += gelu_exact( (u - mean) * rstd );  bf16x8, grid = 3136 blocks.
__global__ __launch_bounds__(256) void lngelu_kernel(
    const bf16* __restrict__ u, const float* __restrict__ statsIt,
    bf16* __restrict__ ref_attn)
{
    int idx8 = blockIdx.x * 256 + threadIdx.x;    // < 802816
    int g = idx8 / 12544;
    size_t base = (size_t)idx8 * 8;
    float sum = statsIt[g * 2], sq = statsIt[g * 2 + 1];
    float mean = sum * (1.f / 100352.f);
    float var  = sq * (1.f / 100352.f) - mean * mean;
    var = fmaxf(var, 0.f);
    float rstd = rsqrtf(var + 1e-5f);
    V16 uv; uv.u4 = *(const uint4*)(u + base);
    V16 rv; rv.u4 = *(const uint4*)(ref_attn + base);
    bf16 outv[8];
    #pragma unroll
    for (int j = 0; j < 8; ++j) {
        unsigned shu = uv.u[j >> 1];
        unsigned shr = rv.u[j >> 1];
        unsigned bu = (j & 1) ? (shu & 0xffff0000u) : (shu << 16);
        unsigned br = (j & 1) ? (shr & 0xffff0000u) : (shr << 16);
        union { unsigned uu; float fl; } cu, cr; cu.uu = bu; cr.uu = br;
        float v = (cu.fl - mean) * rstd;
        float ge = 0.5f * v * (1.f + erff(v * 0.7071067811865476f));
        outv[j] = f2b(cr.fl + ge);
    }
    *(uint4*)(ref_attn + base) = *(uint4*)outv;
}

// ---------------------------------------------------------------------------
// qnew_pre: per row (b,n): softmax(32)@ref_v + q_sc, LN(256) -> ln_t (bf16).
// ---------------------------------------------------------------------------
__global__ __launch_bounds__(256) void qnew_pre_kernel(
    const bf16* __restrict__ qkv, const bf16* __restrict__ ref_attn,
    const float* __restrict__ ref_v_t,
    const float* __restrict__ qnw, const float* __restrict__ qnb,
    bf16* __restrict__ ln_t)
{
    int ww = threadIdx.x >> 6, lane = threadIdx.x & 63;
    int row = blockIdx.x * 4 + ww;            // < 25088
    int b = row / 49, n = row % 49;
    int r = b >> 6, w = b & 63;
    int h = lane >> 3, d0 = (lane & 7) * 4;

    const bf16* la = ref_attn + ((size_t)(((r * 8 + h) * 64 + w) * 49 + n)) * 32 + d0;
    ushort4 lu = *(const ushort4*)la;
    float lg[4] = { bu2f(lu.x), bu2f(lu.y), bu2f(lu.z), bu2f(lu.w) };

    float m = fmaxf(fmaxf(lg[0], lg[1]), fmaxf(lg[2], lg[3]));
    m = fmaxf(m, __shfl_xor(m, 1));
    m = fmaxf(m, __shfl_xor(m, 2));
    m = fmaxf(m, __shfl_xor(m, 4));
    float p[4], s = 0.f;
    #pragma unroll
    for (int j = 0; j < 4; ++j) { p[j] = __expf(lg[j] - m); s += p[j]; }
    s += __shfl_xor(s, 1);
    s += __shfl_xor(s, 2);
    s += __shfl_xor(s, 4);
    float inv = 1.f / s;
    #pragma unroll
    for (int j = 0; j < 4; ++j) p[j] *= inv;

    const float* rv = ref_v_t + ((size_t)(r * 8 + h) * 32) * 32 + d0;
    float y[4] = {0.f, 0.f, 0.f, 0.f};
    #pragma unroll
    for (int f = 0; f < 32; ++f) {
        int src = (lane & 56) | (f >> 2);
        float pf = __shfl(p[f & 3], src);
        float4 rvf = *(const float4*)(rv + f * 32);
        y[0] += pf * rvf.x; y[1] += pf * rvf.y;
        y[2] += pf * rvf.z; y[3] += pf * rvf.w;
    }

    ushort4 qu = *(const ushort4*)(qkv + (size_t)row * 768 + lane * 4);
    float z[4] = { y[0] + bu2f(qu.x), y[1] + bu2f(qu.y),
                   y[2] + bu2f(qu.z), y[3] + bu2f(qu.w) };

    float s1 = z[0] + z[1] + z[2] + z[3];
    #pragma unroll
    for (int off = 1; off < 64; off <<= 1) s1 += __shfl_xor(s1, off);
    float mean = s1 * (1.f / 256.f);
    float zc[4] = { z[0] - mean, z[1] - mean, z[2] - mean, z[3] - mean };
    float s2 = zc[0]*zc[0] + zc[1]*zc[1] + zc[2]*zc[2] + zc[3]*zc[3];
    #pragma unroll
    for (int off = 1; off < 64; off <<= 1) s2 += __shfl_xor(s2, off);
    float rstd = rsqrtf(s2 * (1.f / 256.f) + 1e-5f);

    float4 wv = *(const float4*)(qnw + lane * 4);
    float4 bv = *(const float4*)(qnb + lane * 4);
    bf16 outv[4];
    outv[0] = f2b(zc[0] * rstd * wv.x + bv.x);
    outv[1] = f2b(zc[1] * rstd * wv.y + bv.y);
    outv[2] = f2b(zc[2] * rstd * wv.z + bv.z);
    outv[3] = f2b(zc[3] * rstd * wv.w + bv.w);
    *(ushort4*)(ln_t + (size_t)row * 256 + lane * 4) = *(ushort4*)outv;
}

// ---------------------------------------------------------------------------
// MFMA window attention: ONE WAVE per (b,h), no __syncthreads.
// ---------------------------------------------------------------------------
__global__ __launch_bounds__(256) void winattn_kernel(
    const bf16* __restrict__ qkv, const bf16* __restrict__ q_new,
    const float* __restrict__ rel_bias, bf16* __restrict__ attn_out)
{
    const int wv = threadIdx.x >> 6, lane = threadIdx.x & 63;
    const int quad = lane >> 4, l15 = lane & 15;
    const int b = blockIdx.x >> 1;
    const int h = (blockIdx.x & 1) * 4 + wv;

    __shared__ bf16 lds[4 * 6912];           // per wave: P[64*72] + vT[32*72]
    bf16* P  = &lds[wv * 6912];
    bf16* vT = P + 4608;

    {
        int m = lane;
        if (m < 49) {
            const bf16* vp = qkv + ((size_t)(b * 49 + m)) * 768 + 512 + h * 32;
            V16 v0, v1, v2, v3;
            v0.u4 = *(const uint4*)(vp);
            v1.u4 = *(const uint4*)(vp + 8);
            v2.u4 = *(const uint4*)(vp + 16);
            v3.u4 = *(const uint4*)(vp + 24);
            #pragma unroll
            for (int d = 0; d < 8; ++d) {
                ((unsigned short*)vT)[d * 72 + m]        = v0.s[d];
                ((unsigned short*)vT)[(d + 8) * 72 + m]  = v1.s[d];
                ((unsigned short*)vT)[(d + 16) * 72 + m] = v2.s[d];
                ((unsigned short*)vT)[(d + 24) * 72 + m] = v3.s[d];
            }
        } else {
            #pragma unroll
            for (int d = 0; d < 32; ++d)
                ((unsigned short*)vT)[d * 72 + m] = 0;
        }
    }

    s16x8 aq[4], bk[4];
    #pragma unroll
    for (int t = 0; t < 4; ++t) {
        int qr = t * 16 + l15; qr = qr > 48 ? 48 : qr;
        aq[t] = ld16g(q_new + ((size_t)(b * 49 + qr)) * 256 + h * 32 + quad * 8);
        bk[t] = ld16g(qkv + ((size_t)(b * 49 + qr)) * 768 + 256 + h * 32 + quad * 8);
    }
    f32x4 S[4][4];
    #pragma unroll
    for (int tn = 0; tn < 4; ++tn)
        #pragma unroll
        for (int tm = 0; tm < 4; ++tm) {
            #pragma unroll
            for (int r = 0; r < 4; ++r) S[tn][tm][r] = 0.f;
            S[tn][tm] = __builtin_amdgcn_mfma_f32_16x16x32_bf16(aq[tn], bk[tm], S[tn][tm], 0, 0, 0);
        }

    int mvalid[4], mi[4], mj[4];
    #pragma unroll
    for (int tm = 0; tm < 4; ++tm) {
        int m0 = tm * 16 + l15;
        mvalid[tm] = (m0 < 49);
        int mc = m0 > 48 ? 48 : m0;
        mi[tm] = mc / 7; mj[tm] = mc - mi[tm] * 7;
    }
    #pragma unroll
    for (int tn = 0; tn < 4; ++tn) {
        #pragma unroll
        for (int r = 0; r < 4; ++r) {
            int n0 = tn * 16 + quad * 4 + r;
            int nc = n0 > 48 ? 48 : n0;
            int ni = nc / 7, nj = nc - (nc / 7) * 7;
            float vals[4];
            float mx = -1e30f;
            #pragma unroll
            for (int tm = 0; tm < 4; ++tm) {
                float v = S[tn][tm][r]
                        + rel_bias[((ni - mi[tm] + 6) * 13 + (nj - mj[tm] + 6)) * 8 + h];
                if (!mvalid[tm]) v = -1e30f;
                vals[tm] = v;
                mx = fmaxf(mx, v);
            }
            mx = fmaxf(mx, __shfl_xor(mx, 1));
            mx = fmaxf(mx, __shfl_xor(mx, 2));
            mx = fmaxf(mx, __shfl_xor(mx, 4));
            mx = fmaxf(mx, __shfl_xor(mx, 8));
            float s = 0.f;
            #pragma unroll
            for (int tm = 0; tm < 4; ++tm) { vals[tm] = __expf(vals[tm] - mx); s += vals[tm]; }
            s += __shfl_xor(s, 1);
            s += __shfl_xor(s, 2);
            s += __shfl_xor(s, 4);
            s += __shfl_xor(s, 8);
            float inv = 1.f / s;
            #pragma unroll
            for (int tm = 0; tm < 4; ++tm)
                ((unsigned short*)P)[n0 * 72 + tm * 16 + l15] = f2bs(vals[tm] * inv);
        }
    }

    f32x4 O[4][2];
    #pragma unroll
    for (int tn = 0; tn < 4; ++tn)
        #pragma unroll
        for (int td = 0; td < 2; ++td)
            #pragma unroll
            for (int r = 0; r < 4; ++r) O[tn][td][r] = 0.f;

    #pragma unroll
    for (int ks = 0; ks < 2; ++ks) {
        s16x8 bv0 = *(const s16x8*)&vT[(0 * 16 + l15) * 72 + ks * 32 + quad * 8];
        s16x8 bv1 = *(const s16x8*)&vT[(1 * 16 + l15) * 72 + ks * 32 + quad * 8];
        #pragma unroll
        for (int tn = 0; tn < 4; ++tn) {
            s16x8 ap = *(const s16x8*)&P[(tn * 16 + l15) * 72 + ks * 32 + quad * 8];
            O[tn][0] = __builtin_amdgcn_mfma_f32_16x16x32_bf16(ap, bv0, O[tn][0], 0, 0, 0);
            O[tn][1] = __builtin_amdgcn_mfma_f32_16x16x32_bf16(ap, bv1, O[tn][1], 0, 0, 0);
        }
    }

    #pragma unroll
    for (int tn = 0; tn < 4; ++tn)
        #pragma unroll
        for (int r = 0; r < 4; ++r) {
            int n0 = tn * 16 + quad * 4 + r;
            if (n0 < 49) {
                size_t base = ((size_t)(b * 49 + n0)) * 256 + h * 32;
                attn_out[base + l15]      = f2b(O[tn][0][r]);
                attn_out[base + 16 + l15] = f2b(O[tn][1][r]);
            }
        }
}

// ---------------------------------------------------------------------------
// MFMA class-token attention: ONE WAVE per (b,h), no __syncthreads.
// t_k = tkv[:, 0:384], t_v = tkv[:, 384:768] (fused kv GEMM output, stride 768)
// ---------------------------------------------------------------------------
__global__ __launch_bounds__(256) void clsattn_kernel(
    const bf16* __restrict__ tkv,
    const bf16* __restrict__ depth_q, const bf16* __restrict__ seg_q,
    bf16* __restrict__ d_pre, bf16* __restrict__ s_pre)
{
    const int wv = threadIdx.x >> 6, lane = threadIdx.x & 63;
    const int quad = lane >> 4, l15 = lane & 15;
    const int bh = blockIdx.x * 4 + wv;      // < 4096
    const int b = bh >> 3, h = bh & 7;

    __shared__ bf16 lds[4 * 5760];
    unsigned short* QP = (unsigned short*)&lds[wv * 5760];   // 16 x 72
    unsigned short* KV = QP + 1152;                          // 64 x 72 (max use 4608)

    {
        int n = lane;
        V16 dv, sv;
        if (n < 49) {
            dv.u4 = *(const uint4*)(depth_q + ((size_t)(b * 49 + n)) * 64 + h * 8);
            sv.u4 = *(const uint4*)(seg_q   + ((size_t)(b * 49 + n)) * 64 + h * 8);
        } else {
            dv.u4 = make_uint4(0, 0, 0, 0); sv.u4 = make_uint4(0, 0, 0, 0);
        }
        #pragma unroll
        for (int c = 0; c < 8; ++c) {
            QP[c * 72 + n]       = dv.s[c];
            QP[(8 + c) * 72 + n] = sv.s[c];
        }
    }
    {
        int n = lane;
        V16 k[6];
        if (n < 49) {
            const bf16* kp = tkv + ((size_t)(b * 49 + n)) * 768 + h * 48;
            #pragma unroll
            for (int c6 = 0; c6 < 6; ++c6) k[c6].u4 = *(const uint4*)(kp + c6 * 8);
        } else {
            #pragma unroll
            for (int c6 = 0; c6 < 6; ++c6) k[c6].u4 = make_uint4(0, 0, 0, 0);
        }
        #pragma unroll
        for (int c6 = 0; c6 < 6; ++c6)
            #pragma unroll
            for (int j = 0; j < 8; ++j)
                KV[(c6 * 8 + j) * 72 + n] = k[c6].s[j];
    }

    f32x4 S[3];
    #pragma unroll
    for (int t3 = 0; t3 < 3; ++t3)
        #pragma unroll
        for (int r = 0; r < 4; ++r) S[t3][r] = 0.f;
    #pragma unroll
    for (int ks = 0; ks < 2; ++ks) {
        s16x8 a = *(const s16x8*)&QP[l15 * 72 + ks * 32 + quad * 8];
        #pragma unroll
        for (int t3 = 0; t3 < 3; ++t3) {
            s16x8 bf = *(const s16x8*)&KV[(t3 * 16 + l15) * 72 + ks * 32 + quad * 8];
            S[t3] = __builtin_amdgcn_mfma_f32_16x16x32_bf16(a, bf, S[t3], 0, 0, 0);
        }
    }

    #pragma unroll
    for (int r = 0; r < 4; ++r) {
        float v0 = S[0][r], v1 = S[1][r], v2 = S[2][r];
        float mx = fmaxf(fmaxf(v0, v1), v2);
        mx = fmaxf(mx, __shfl_xor(mx, 1));
        mx = fmaxf(mx, __shfl_xor(mx, 2));
        mx = fmaxf(mx, __shfl_xor(mx, 4));
        mx = fmaxf(mx, __shfl_xor(mx, 8));
        float e0 = __expf(v0 - mx), e1 = __expf(v1 - mx), e2 = __expf(v2 - mx);
        float s = e0 + e1 + e2;
        s += __shfl_xor(s, 1);
        s += __shfl_xor(s, 2);
        s += __shfl_xor(s, 4);
        s += __shfl_xor(s, 8);
        float inv = 1.f / s;
        int c = quad * 4 + r;
        QP[c * 72 + 0 * 16 + l15] = f2bs(e0 * inv);
        QP[c * 72 + 1 * 16 + l15] = f2bs(e1 * inv);
        QP[c * 72 + 2 * 16 + l15] = f2bs(e2 * inv);
    }
    #pragma unroll
    for (int z = 0; z < 4; ++z)
        QP[(lane & 15) * 72 + 48 + (lane >> 4) * 4 + z] = 0;

    {
        int n = lane;
        V16 v[6], zv; zv.u4 = make_uint4(0, 0, 0, 0);
        if (n < 49) {
            const bf16* vp = tkv + ((size_t)(b * 49 + n)) * 768 + 384 + h * 48;
            #pragma unroll
            for (int c6 = 0; c6 < 6; ++c6) v[c6].u4 = *(const uint4*)(vp + c6 * 8);
        } else {
            #pragma unroll
            for (int c6 = 0; c6 < 6; ++c6) v[c6].u4 = zv.u4;
        }
        #pragma unroll
        for (int c6 = 0; c6 < 6; ++c6)
            *(uint4*)&KV[n * 72 + c6 * 8] = v[c6].u4;
        *(uint4*)&KV[n * 72 + 48] = zv.u4;
        *(uint4*)&KV[n * 72 + 56] = zv.u4;
    }

    f32x4 O[4];
    #pragma unroll
    for (int t4 = 0; t4 < 4; ++t4)
        #pragma unroll
        for (int r = 0; r < 4; ++r) O[t4][r] = 0.f;
    #pragma unroll
    for (int ks = 0; ks < 2; ++ks) {
        s16x8 a = *(const s16x8*)&QP[l15 * 72 + ks * 32 + quad * 8];
        #pragma unroll
        for (int t4 = 0; t4 < 4; ++t4) {
            s16x8 bf = *(const s16x8*)&KV[(t4 * 16 + l15) * 72 + ks * 32 + quad * 8];
            O[t4] = __builtin_amdgcn_mfma_f32_16x16x32_bf16(a, bf, O[t4], 0, 0, 0);
        }
    }

    #pragma unroll
    for (int t4 = 0; t4 < 4; ++t4) {
        int n = t4 * 16 + l15;
        if (n < 49) {
            size_t base = ((size_t)(b * 49 + n)) * 64 + h * 8;
            #pragma unroll
            for (int r = 0; r < 4; ++r) {
                int c = quad * 4 + r;
                if (c < 8) d_pre[base + c] = f2b(O[t4][r]);
                else       s_pre[base + c - 8] = f2b(O[t4][r]);
            }
        }
    }
}

// ---------------------------------------------------------------------------
extern "C" void kernel_launch(void* const* d_in, const int* in_sizes, int n_in,
                              void* d_out, int out_size, void* d_ws, size_t ws_size,
                              hipStream_t stream)
{
    const float* x          = (const float*)d_in[0];
    const float* x_ref      = (const float*)d_in[1];
    const float* dth_tok    = (const float*)d_in[2];
    const float* seg_tok    = (const float*)d_in[3];
    const float* qkv_w      = (const float*)d_in[4];
    const float* qkv_b      = (const float*)d_in[5];
    const float* proj_w     = (const float*)d_in[6];
    const float* proj_b     = (const float*)d_in[7];
    const float* rel_bias   = (const float*)d_in[8];
    const float* diff_mu    = (const float*)d_in[9];
    const float* diff_ls    = (const float*)d_in[10];
    const float* ref_qk_w   = (const float*)d_in[11];
    const float* ref_qk_b   = (const float*)d_in[12];
    const float* conv_w     = (const float*)d_in[13];
    const float* conv_b     = (const float*)d_in[14];
    const float* q_norm_w   = (const float*)d_in[15];
    const float* q_norm_b   = (const float*)d_in[16];
    const float* q_proj_w   = (const float*)d_in[17];
    const float* q_proj_b   = (const float*)d_in[18];
    const float* cls_dth_w  = (const float*)d_in[19];
    const float* cls_dth_b  = (const float*)d_in[20];
    const float* cls_seg_w  = (const float*)d_in[21];
    const float* cls_seg_b  = (const float*)d_in[22];
    const float* glob_k_w   = (const float*)d_in[23];
    const float* glob_k_b   = (const float*)d_in[24];
    const float* glob_v_w   = (const float*)d_in[25];
    const float* glob_v_b   = (const float*)d_in[26];
    const float* proj_dth_w = (const float*)d_in[27];
    const float* proj_dth_b = (const float*)d_in[28];

    // ---- workspace layout (same footprint as before) ----
    bf16* wsb = (bf16*)d_ws;
    bf16* qkv      = wsb;                      // [25088,768]; later tkv [25088,768]
    bf16* tkv      = wsb;
    bf16* ref_attn = wsb + 19267584;           // R1: ref_attn -> q_new -> out0b -> dq/sq/dpre/spre
    bf16* q_new    = ref_attn;
    bf16* out0b    = ref_attn;                 // [25088,256] bf16 (written step 9, read step 10)
    bf16* depth_q  = ref_attn;
    bf16* seg_q    = ref_attn + 1605632;
    bf16* d_pre    = ref_attn + 3211264;
    bf16* s_pre    = ref_attn + 4816896;
    bf16* u_buf    = wsb + 25690112;           // R3: xb -> u -> ln_t -> attn_out
    bf16* xb       = u_buf;                    // [25088,256] bf16 (dead before step 5)
    bf16* ln_t     = u_buf;
    bf16* attn_out = u_buf;
    float* ref_qk  = (float*)((char*)d_ws + 64225280);
    float* ref_q_t = ref_qk + 131072;
    float* ref_v_t = ref_q_t + 65536;
    float* statsA  = ref_qk;                   // 384 f32 (3 slices), zeroed in refattn

    float* out0  = (float*)d_out;
    float* out_d = out0 + 6422528;
    float* out_s = out0 + 8028160;

    // scratch in output regions (dead until steps 15/16)
    bf16* Wt_all = (bf16*)out_d;               // 622592 elems = 1.19 MiB
    bf16* tokb   = (bf16*)out_s;               // [25088,128] bf16 = 6.125 MiB (exact fit)

    // 0. weight prep + input conversions
    prep_weights<<<2432, 256, 0, stream>>>(qkv_w, q_proj_w, proj_w, glob_k_w, glob_v_w, Wt_all);
    convert_f32_bf16<<<6272, 256, 0, stream>>>(x, xb);
    tok2b_kernel<<<1568, 256, 0, stream>>>(dth_tok, seg_tok, tokb);

    // 1. qkv = x @ qkv_w + b
    gemm_bb<0><<<dim3(6, 196), 256, 0, stream>>>(xb, 256, nullptr,
        Wt_all, qkv_b, nullptr, nullptr, 0, nullptr, qkv, 768, 256, 768, 1.f);
    // 2. ref_qk = x_ref @ ref_qk_w + b (small)
    mfma_gemm<<<dim3(8, 4), 256, 0, stream>>>(x_ref, 0, ref_qk_w, ref_qk_b,
                                              ref_qk, nullptr, 256, 256, 512, 1.f);
    // 3. ref_q_t / ref_v_t
    refprep_kernel<<<256, 256, 0, stream>>>(ref_qk, diff_mu, diff_ls, ref_q_t, ref_v_t);
    // 4. ref_attn scores (+ statsA zero)
    refattn_kernel<<<4096, 256, 0, stream>>>(qkv, ref_q_t, ref_attn, statsA);
    // 5. 3x diffusion (conv computes LN stats via atomics; lnstats kernel gone)
    for (int it = 0; it < 3; ++it) {
        conv_kernel<<<392, 256, 0, stream>>>(ref_attn, conv_w, conv_b, u_buf, statsA + it * 128);
        lngelu_kernel<<<3136, 256, 0, stream>>>(u_buf, statsA + it * 128, ref_attn);
    }
    // 6. softmax @ ref_v + shortcut + LN -> ln_t
    qnew_pre_kernel<<<6272, 256, 0, stream>>>(qkv, ref_attn, ref_v_t,
                                              q_norm_w, q_norm_b, ln_t);
    // 7. q_new = (ln_t @ q_proj_w + b + qsc) * SCALE
    gemm_bb<0><<<dim3(2, 196), 256, 0, stream>>>(ln_t, 256, nullptr,
        Wt_all + 196608, q_proj_b, nullptr, qkv, 768, nullptr, q_new, 256, 256, 256, SCALE_T);
    // 8. window attention
    winattn_kernel<<<1024, 256, 0, stream>>>(qkv, q_new, rel_bias, attn_out);
    // 9. out0 = attn_out @ proj_w + b   (f32 to d_out, bf16 copy to out0b)
    gemm_bb<0><<<dim3(2, 196), 256, 0, stream>>>(attn_out, 256, nullptr,
        Wt_all + 262144, proj_b, nullptr, nullptr, 0, out0, out0b, 256, 256, 256, 1.f);
    // 10. fused t_k|t_v = concat(out0b, tokb) @ [gk|gv] + b -> tkv [25088,768]
    gemm_bb<1><<<dim3(6, 196), 256, 0, stream>>>(out0b, 256, tokb,
        Wt_all + 327680, glob_k_b, glob_v_b, nullptr, 0, nullptr, tkv, 768, 384, 768, 1.f);
    // 12/13. depth_q, seg_q in ONE launch
    small64<1, 0><<<dim3(392, 2), 256, 0, stream>>>(dth_tok, seg_tok,
        cls_dth_w, cls_seg_w, cls_dth_b, cls_seg_b, depth_q, seg_q, SCALE_T);
    // 14. class-token attention
    clsattn_kernel<<<1024, 256, 0, stream>>>(tkv, depth_q, seg_q, d_pre, s_pre);
    // 15/16. final proj_dth in ONE launch (f32 out; overwrites Wt/tokb scratch)
    small64<0, 1><<<dim3(392, 2), 256, 0, stream>>>(d_pre, s_pre,
        proj_dth_w, proj_dth_w, proj_dth_b, proj_dth_b, out_d, out_s, 1.f);
}

// Round 4
// 496.272 us; speedup vs baseline: 1.0421x; 1.0421x over previous
//
#include <hip/hip_runtime.h>
#include <hip/hip_bf16.h>

typedef __hip_bfloat16 bf16;
typedef short s16x8 __attribute__((ext_vector_type(8)));
typedef float f32x4 __attribute__((ext_vector_type(4)));
union V16 { uint4 u4; s16x8 s8; unsigned u[4]; unsigned short s[8]; };

static __device__ __forceinline__ float b2f(bf16 v){ return __bfloat162float(v); }
static __device__ __forceinline__ bf16  f2b(float v){ return __float2bfloat16(v); }
static __device__ __forceinline__ unsigned short f2bs(float x){
    union { float f; unsigned u; } c; c.f = x;
    unsigned r = c.u + 0x7fff + ((c.u >> 16) & 1);
    return (unsigned short)(r >> 16);
}
static __device__ __forceinline__ float bu2f(unsigned short b){
    union { unsigned u; float f; } c; c.u = ((unsigned)b) << 16; return c.f;
}
static __device__ __forceinline__ s16x8 ld16g(const bf16* p){
    V16 u; u.u4 = *(const uint4*)p; return u.s8;
}
static __device__ __forceinline__ void glds16(const void* g, void* l){
    __builtin_amdgcn_global_load_lds(
        (const __attribute__((address_space(1))) unsigned*)g,
        (__attribute__((address_space(3))) unsigned*)l, 16, 0, 0);
}

#define SCALE_T 0.17677669529663687f   // 32^-0.5

// ---------------------------------------------------------------------------
// prep_weights: transpose+convert weights to bf16 Wt[N][K] layouts.
// ---------------------------------------------------------------------------
__global__ __launch_bounds__(256) void prep_weights(
    const float* __restrict__ qkvw, const float* __restrict__ qpw,
    const float* __restrict__ pw,   const float* __restrict__ gkw,
    const float* __restrict__ gvw,  bf16* __restrict__ Wt)
{
    int idx = blockIdx.x * 256 + threadIdx.x;   // < 622592 exact
    float v;
    if (idx < 196608)      { int j = idx;          int n = j >> 8, k = j & 255; v = qkvw[k * 768 + n]; }
    else if (idx < 262144) { int j = idx - 196608; int n = j >> 8, k = j & 255; v = qpw[k * 256 + n]; }
    else if (idx < 327680) { int j = idx - 262144; int n = j >> 8, k = j & 255; v = pw[k * 256 + n]; }
    else if (idx < 475136) { int j = idx - 327680; int n = j / 384, k = j - n * 384; v = gkw[k * 384 + n]; }
    else                   { int j = idx - 475136; int n = j / 384, k = j - n * 384; v = gvw[k * 384 + n]; }
    ((unsigned short*)Wt)[idx] = f2bs(v);
}

// f32 -> bf16 packed conversion (4 elems per thread). grid*256*4 == n exactly.
__global__ __launch_bounds__(256) void convert_f32_bf16(
    const float* __restrict__ in, bf16* __restrict__ out)
{
    int i = blockIdx.x * 256 + threadIdx.x;
    float4 v = ((const float4*)in)[i];
    ushort4 o;
    o.x = f2bs(v.x); o.y = f2bs(v.y); o.z = f2bs(v.z); o.w = f2bs(v.w);
    ((ushort4*)out)[i] = o;
}

// tokb[row][0:64] = bf16(dth[row]);  tokb[row][64:128] = bf16(seg[row]).
__global__ __launch_bounds__(256) void tok2b_kernel(
    const float* __restrict__ dth, const float* __restrict__ seg,
    bf16* __restrict__ tokb)
{
    int i = blockIdx.x * 256 + threadIdx.x;   // < 401408
    int row = i >> 4, j8 = i & 15;
    const float* src = (j8 < 8) ? (dth + (size_t)row * 64 + j8 * 8)
                                : (seg + (size_t)row * 64 + (j8 - 8) * 8);
    float4 u0 = ((const float4*)src)[0];
    float4 u1 = ((const float4*)src)[1];
    V16 o;
    o.s[0] = f2bs(u0.x); o.s[1] = f2bs(u0.y);
    o.s[2] = f2bs(u0.z); o.s[3] = f2bs(u0.w);
    o.s[4] = f2bs(u1.x); o.s[5] = f2bs(u1.y);
    o.s[6] = f2bs(u1.z); o.s[7] = f2bs(u1.w);
    *(uint4*)(tokb + (size_t)row * 128 + j8 * 8) = o.u4;
}

// ---------------------------------------------------------------------------
// gemm_pipe: out = (A[M,K]bf16 @ Wt[N,K]^T + bias [+ add]) * scale
// 128x128 tile, BK=32, 4 waves (2x2). 4-deep LDS ring (64KB), counted-vmcnt
// software pipeline: prologue stages steps 0..2; each iter waits ONLY the
// oldest stage (vmcnt(8)), raw s_barrier, issues stage i+3, computes buf i.
// One barrier per K-step; 8 loads stay in flight across barriers.
// TOK: K-tiles >= 256 come from A2 (bf16, lda 128).
// ---------------------------------------------------------------------------
template<int TOK>
__global__ __launch_bounds__(256, 2) void gemm_pipe(
    const bf16* __restrict__ A, int lda, const bf16* __restrict__ A2,
    const bf16* __restrict__ Wt, const float* __restrict__ bias,
    const float* __restrict__ bias2,
    const bf16* __restrict__ addp, int addStride,
    float* __restrict__ outF, bf16* __restrict__ outB, int outStrideB,
    int K, int N, float scale)
{
    __shared__ char lds[4][16384];            // ring: per buf A 8KB | B 8KB

    const int tid = threadIdx.x;
    const int wv = tid >> 6, lane = tid & 63;
    const int quad = lane >> 4, l15 = lane & 15;
    const int wr = wv >> 1, wc = wv & 1;

    const int gx = (int)gridDim.x;
    const int nwg = gx * (int)gridDim.y;
    int bid = (int)blockIdx.y * gx + (int)blockIdx.x;
    if ((nwg & 7) == 0) bid = (bid & 7) * (nwg >> 3) + (bid >> 3);
    const int bx = bid % gx, by = bid / gx;
    const int rowBase = by * 128, colBase = bx * 128;

    // staging: row srow = tid>>2, slot s = tid&3 holds k-quad (s ^ ((srow>>1)&3))
    const int srow = tid >> 2;
    const int kOffE = (((tid & 3) ^ ((srow >> 1) & 3)) << 3);   // elems

    // read: quad q of row l15 lives at slot (q ^ ((l15>>1)&3))
    const unsigned swz = (unsigned)((quad ^ ((l15 >> 1) & 3)) << 4);
    const unsigned aoff0 = (unsigned)(wr * 4096 + l15 * 64) + swz;
    const unsigned boff0 = (unsigned)(wc * 4096 + l15 * 64) + swz;

    f32x4 acc[4][4];
    #pragma unroll
    for (int m = 0; m < 4; ++m)
        #pragma unroll
        for (int n = 0; n < 4; ++n)
            #pragma unroll
            for (int r = 0; r < 4; ++r) acc[m][n][r] = 0.f;

    const int nsteps = K >> 5;

    auto stageN = [&](int i) {                // stage K-step i into buf i&3
        int kt = i << 5;
        char* base = &lds[i & 3][0];
        #pragma unroll
        for (int c = 0; c < 2; ++c)
            glds16(Wt + (size_t)(colBase + c * 64 + srow) * K + (kt + kOffE),
                   base + 8192 + c * 4096 + tid * 16);
        if (!TOK || kt < 256) {
            #pragma unroll
            for (int c = 0; c < 2; ++c)
                glds16(A + (size_t)(rowBase + c * 64 + srow) * lda + (kt + kOffE),
                       base + c * 4096 + tid * 16);
        } else {
            #pragma unroll
            for (int c = 0; c < 2; ++c)
                glds16(A2 + (size_t)(rowBase + c * 64 + srow) * 128 + (kt - 256 + kOffE),
                       base + c * 4096 + tid * 16);
        }
    };

    stageN(0);
    if (nsteps > 1) stageN(1);
    if (nsteps > 2) stageN(2);

    for (int i = 0; i < nsteps; ++i) {
        // wait only for stage i (leave younger stages in flight)
        int a = nsteps - 1 - i; if (a > 2) a = 2;
        if (a == 2)      asm volatile("s_waitcnt vmcnt(8)" ::: "memory");
        else if (a == 1) asm volatile("s_waitcnt vmcnt(4)" ::: "memory");
        else             asm volatile("s_waitcnt vmcnt(0)" ::: "memory");
        __builtin_amdgcn_sched_barrier(0);
        __builtin_amdgcn_s_barrier();        // all waves: stage i landed in LDS
        __builtin_amdgcn_sched_barrier(0);

        if (i + 3 < nsteps) stageN(i + 3);   // targets buf (i-1)&3: readers done

        const char* Ab2 = &lds[i & 3][0];
        const char* Bb2 = Ab2 + 8192;
        s16x8 af[4], bfr[4];
        #pragma unroll
        for (int m = 0; m < 4; ++m) af[m]  = *(const s16x8*)(Ab2 + aoff0 + m * 1024);
        #pragma unroll
        for (int n = 0; n < 4; ++n) bfr[n] = *(const s16x8*)(Bb2 + boff0 + n * 1024);
        #pragma unroll
        for (int m = 0; m < 4; ++m)
            #pragma unroll
            for (int n = 0; n < 4; ++n)
                acc[m][n] = __builtin_amdgcn_mfma_f32_16x16x32_bf16(af[m], bfr[n], acc[m][n], 0, 0, 0);
    }
    // last compute reads buf 3 (K=256/384 -> (nsteps-1)&3 == 3); epilogue
    // scratch uses bytes 0..32767 (bufs 0-1) -> disjoint; __syncthreads below
    // orders the repack phases.

    // ---- epilogue ----
    if (outB) {
        #pragma unroll
        for (int n = 0; n < 4; ++n) {
            int col = colBase + wc * 64 + n * 16 + l15;
            float bb = bias2 ? (col < 384 ? bias[col] : bias2[col - 384]) : bias[col];
            #pragma unroll
            for (int m = 0; m < 4; ++m) {
                #pragma unroll
                for (int r = 0; r < 4; ++r) {
                    int rl = wr * 64 + m * 16 + quad * 4 + r;
                    float v = acc[m][n][r] + bb;
                    if (addp) v += b2f(addp[(size_t)(rowBase + rl) * addStride + col]);
                    v *= scale;
                    if (outF) outF[(size_t)(rowBase + rl) * N + col] = v;
                    int cbyte = (wc * 64 + n * 16 + l15) * 2;
                    int blk = ((cbyte >> 5) ^ ((rl >> 2) & 7)) & 7;
                    *(unsigned short*)((char*)lds + rl * 256 + (blk << 5) + (cbyte & 31)) = f2bs(v);
                }
            }
        }
        __syncthreads();
        #pragma unroll
        for (int i = 0; i < 8; ++i) {
            int lin = i * 256 + tid;
            int rl = lin >> 4, cb = lin & 15;
            int cb2 = ((((cb >> 1) ^ ((rl >> 2) & 7)) & 7) << 1) | (cb & 1);
            uint4 val = *(const uint4*)((const char*)lds + rl * 256 + cb2 * 16);
            *(uint4*)(outB + (size_t)(rowBase + rl) * outStrideB + colBase + cb * 8) = val;
        }
    } else {
        #pragma unroll
        for (int n = 0; n < 4; ++n) {
            int col = colBase + wc * 64 + n * 16 + l15;
            float bb = bias2 ? (col < 384 ? bias[col] : bias2[col - 384]) : bias[col];
            #pragma unroll
            for (int m = 0; m < 4; ++m) {
                #pragma unroll
                for (int r = 0; r < 4; ++r) {
                    int rl = wr * 64 + m * 16 + quad * 4 + r;
                    float v = acc[m][n][r] + bb;
                    if (addp) v += b2f(addp[(size_t)(rowBase + rl) * addStride + col]);
                    v *= scale;
                    if (outF) outF[(size_t)(rowBase + rl) * N + col] = v;
                }
            }
        }
    }
}

// ---------------------------------------------------------------------------
// small64: out[M,64] = (A[M,64] @ W[64,64] + bias) * scale, two tasks via
// blockIdx.y.
// ---------------------------------------------------------------------------
template<int AF32, int OF32>
__global__ __launch_bounds__(256) void small64(
    const void* __restrict__ a0, const void* __restrict__ a1,
    const float* __restrict__ w0, const float* __restrict__ w1,
    const float* __restrict__ b0, const float* __restrict__ b1,
    void* __restrict__ o0, void* __restrict__ o1, float scale)
{
    __shared__ unsigned short WT[64 * 72];
    __shared__ float bsh[64];
    const int task = blockIdx.y;
    const void*  A    = task ? a1 : a0;
    const float* W    = task ? w1 : w0;
    const float* bias = task ? b1 : b0;
    void*        outp = task ? o1 : o0;

    int tid = threadIdx.x;
    for (int l = tid; l < 4096; l += 256) {
        int k = l >> 6, n = l & 63;
        WT[n * 72 + k] = f2bs(W[l]);
    }
    if (tid < 64) bsh[tid] = bias[tid];
    __syncthreads();

    const int wv = tid >> 6, lane = tid & 63;
    const int quad = lane >> 4, l15 = lane & 15;
    const int rowBase = blockIdx.x * 64;
    const int arow = rowBase + wv * 16 + l15;

    s16x8 a[2];
    if (AF32) {
        const float* Ar = (const float*)A + (size_t)arow * 64;
        #pragma unroll
        for (int ks = 0; ks < 2; ++ks) {
            float4 u0 = *(const float4*)(Ar + ks * 32 + quad * 8);
            float4 u1 = *(const float4*)(Ar + ks * 32 + quad * 8 + 4);
            V16 o;
            o.s[0] = f2bs(u0.x); o.s[1] = f2bs(u0.y);
            o.s[2] = f2bs(u0.z); o.s[3] = f2bs(u0.w);
            o.s[4] = f2bs(u1.x); o.s[5] = f2bs(u1.y);
            o.s[6] = f2bs(u1.z); o.s[7] = f2bs(u1.w);
            a[ks] = o.s8;
        }
    } else {
        const bf16* Ar = (const bf16*)A + (size_t)arow * 64;
        #pragma unroll
        for (int ks = 0; ks < 2; ++ks)
            a[ks] = ld16g(Ar + ks * 32 + quad * 8);
    }

    f32x4 acc[4];
    #pragma unroll
    for (int n = 0; n < 4; ++n)
        #pragma unroll
        for (int r = 0; r < 4; ++r) acc[n][r] = 0.f;

    #pragma unroll
    for (int ks = 0; ks < 2; ++ks)
        #pragma unroll
        for (int n = 0; n < 4; ++n) {
            s16x8 b = *(const s16x8*)&WT[(n * 16 + l15) * 72 + ks * 32 + quad * 8];
            acc[n] = __builtin_amdgcn_mfma_f32_16x16x32_bf16(a[ks], b, acc[n], 0, 0, 0);
        }

    #pragma unroll
    for (int n = 0; n < 4; ++n) {
        int col = n * 16 + l15;
        float bb = bsh[col];
        #pragma unroll
        for (int r = 0; r < 4; ++r) {
            int row = rowBase + wv * 16 + quad * 4 + r;
            float v = (acc[n][r] + bb) * scale;
            if (OF32) ((float*)outp)[(size_t)row * 64 + col] = v;
            else      ((bf16*)outp)[(size_t)row * 64 + col] = f2b(v);
        }
    }
}

// ---------------------------------------------------------------------------
// Small MFMA GEMM (kept for step 2's tiny 256x512 shape).
// ---------------------------------------------------------------------------
__global__ __launch_bounds__(256) void mfma_gemm(
    const void* __restrict__ A, int a_mode,
    const float* __restrict__ W, const float* __restrict__ bias,
    float* __restrict__ outF, bf16* __restrict__ outB,
    int M, int K, int N, float scale)
{
    __shared__ __hip_bfloat16 Al[64][48];
    __shared__ __hip_bfloat16 Bl[64][48];

    const int tid  = threadIdx.x;
    const int wv   = tid >> 6, lane = tid & 63;
    const int quad = lane >> 4, l15 = lane & 15;
    const int rowBase = blockIdx.y * 64, colBase = blockIdx.x * 64;

    const int am = tid >> 2, ak = (tid & 3) * 8;
    const int bn = tid & 63, bk = (tid >> 6) * 8;

    f32x4 acc[4];
    #pragma unroll
    for (int t = 0; t < 4; ++t)
        #pragma unroll
        for (int r = 0; r < 4; ++r) acc[t][r] = 0.f;

    for (int kt = 0; kt < K; kt += 32) {
        s16x8 sa;
        if (a_mode == 1) {
            const bf16* Ab = (const bf16*)A;
            V16 u; u.u4 = *(const uint4*)(Ab + (size_t)(rowBase + am) * K + kt + ak);
            sa = u.s8;
        } else {
            const float* src = (const float*)A;
            const float4* p = (const float4*)(src + (size_t)(rowBase + am) * K + kt + ak);
            float4 u0 = p[0], u1 = p[1];
            sa[0] = (short)f2bs(u0.x); sa[1] = (short)f2bs(u0.y);
            sa[2] = (short)f2bs(u0.z); sa[3] = (short)f2bs(u0.w);
            sa[4] = (short)f2bs(u1.x); sa[5] = (short)f2bs(u1.y);
            sa[6] = (short)f2bs(u1.z); sa[7] = (short)f2bs(u1.w);
        }
        *(s16x8*)&Al[am][ak] = sa;

        s16x8 sb;
        #pragma unroll
        for (int j = 0; j < 8; ++j)
            sb[j] = (short)f2bs(W[(size_t)(kt + bk + j) * N + colBase + bn]);
        *(s16x8*)&Bl[bn][bk] = sb;

        __syncthreads();

        s16x8 a = *(const s16x8*)&Al[wv * 16 + l15][quad * 8];
        #pragma unroll
        for (int t = 0; t < 4; ++t) {
            s16x8 b = *(const s16x8*)&Bl[t * 16 + l15][quad * 8];
            acc[t] = __builtin_amdgcn_mfma_f32_16x16x32_bf16(a, b, acc[t], 0, 0, 0);
        }
        __syncthreads();
    }

    #pragma unroll
    for (int t = 0; t < 4; ++t) {
        int col = colBase + t * 16 + l15;
        float bb = bias[col];
        #pragma unroll
        for (int r = 0; r < 4; ++r) {
            int row = rowBase + wv * 16 + quad * 4 + r;
            float v = (acc[t][r] + bb) * scale;
            if (outF) outF[(size_t)row * N + col] = v;
            if (outB) outB[(size_t)row * N + col] = f2b(v);
        }
    }
}

// ---------------------------------------------------------------------------
// ref_q_t[r,h,f,d] = mu[c] + exp(ls[c]) * ref_qk[r*32+f, c];  ref_v_t from +256
// ---------------------------------------------------------------------------
__global__ __launch_bounds__(256) void refprep_kernel(
    const float* __restrict__ ref_qk, const float* __restrict__ mu,
    const float* __restrict__ ls, float* __restrict__ ref_q_t,
    float* __restrict__ ref_v_t)
{
    int idx = blockIdx.x * 256 + threadIdx.x;          // [r,h,f,d]
    int d = idx & 31, f = (idx >> 5) & 31, h = (idx >> 10) & 7, r = idx >> 13;
    int c = h * 32 + d;
    size_t src = (size_t)(r * 32 + f) * 512 + c;
    ref_q_t[idx] = mu[c] + __expf(ls[c]) * ref_qk[src];
    ref_v_t[idx] = ref_qk[src + 256];
}

// ---------------------------------------------------------------------------
// ref_attn[r,h,w,n,f] = sum_d (q[b,h,n,d]*SCALE) * ref_q_t[r,h,f,d]
// ---------------------------------------------------------------------------
__global__ __launch_bounds__(256) void refattn_kernel(
    const bf16* __restrict__ qkv, const float* __restrict__ ref_q_t,
    bf16* __restrict__ ref_attn)
{
    int blk = blockIdx.x;
    int w = blk & 63, h = (blk >> 6) & 7, r = blk >> 9;
    int b = r * 64 + w;
    __shared__ float qt[49 * 32];
    __shared__ float rq[32 * 33];
    int tid = threadIdx.x;
    for (int l = tid; l < 1568; l += 256) {
        int n = l >> 5, d = l & 31;
        qt[l] = b2f(qkv[(size_t)(b * 49 + n) * 768 + h * 32 + d]) * SCALE_T;
    }
    for (int l = tid; l < 1024; l += 256) {
        int f = l >> 5, d = l & 31;
        rq[f * 33 + d] = ref_q_t[(size_t)((r * 8 + h) * 32 + f) * 32 + d];
    }
    __syncthreads();
    for (int l = tid; l < 1568; l += 256) {
        int n = l >> 5, f = l & 31;
        float acc = 0.f;
        #pragma unroll
        for (int d2 = 0; d2 < 32; ++d2) acc += qt[n * 32 + d2] * rq[f * 33 + d2];
        ref_attn[(size_t)(((r * 8 + h) * 64 + w) * 49 + n) * 32 + f] = f2b(acc);
    }
}

// ---------------------------------------------------------------------------
// 3x3 SAME conv over [RB=8, 8ch, 3136, 32].
// ---------------------------------------------------------------------------
__global__ __launch_bounds__(256) void conv_kernel(
    const bf16* __restrict__ in, const float* __restrict__ conv_w,
    const float* __restrict__ conv_b, bf16* __restrict__ u)
{
    __shared__ float w_s[576];
    __shared__ float b_s[8];
    int tid = threadIdx.x;
    for (int l = tid; l < 576; l += 256) w_s[l] = conv_w[l];
    if (tid < 8) b_s[tid] = conv_b[tid];
    __syncthreads();

    int idx = blockIdx.x * 256 + tid;          // < 100352
    int fb = idx & 3;
    int p  = (idx >> 2) % 3136;
    int r  = idx / 12544;
    int f0 = fb * 8;

    float acc[8][8];
    #pragma unroll
    for (int o = 0; o < 8; ++o) {
        float bo = b_s[o];
        #pragma unroll
        for (int f = 0; f < 8; ++f) acc[o][f] = bo;
    }

    for (int i = 0; i < 8; ++i) {
        float ext[3][10];
        #pragma unroll
        for (int dy = 0; dy < 3; ++dy) {
            int pp = p + dy - 1;
            bool pv = (unsigned)pp < 3136u;
            size_t base = ((size_t)((r * 8 + i) * 3136 + (pv ? pp : 0))) * 32 + f0;
            V16 uv;
            uv.u4 = pv ? *(const uint4*)(in + base) : make_uint4(0, 0, 0, 0);
            #pragma unroll
            for (int j = 0; j < 8; ++j) {
                unsigned sh = uv.u[j >> 1];
                unsigned bits = (j & 1) ? (sh & 0xffff0000u) : (sh << 16);
                union { unsigned uu; float fl; } cv; cv.uu = bits;
                ext[dy][j + 1] = cv.fl;
            }
            ext[dy][0] = (pv && f0 > 0)      ? b2f(in[base - 1]) : 0.f;
            ext[dy][9] = (pv && f0 + 8 < 32) ? b2f(in[base + 8]) : 0.f;
        }
        #pragma unroll
        for (int o = 0; o < 8; ++o) {
            #pragma unroll
            for (int ky = 0; ky < 3; ++ky) {
                const float* wp = &w_s[((o * 8 + i) * 3 + ky) * 3];
                float w0 = wp[0], w1 = wp[1], w2 = wp[2];
                #pragma unroll
                for (int f = 0; f < 8; ++f)
                    acc[o][f] += ext[ky][f] * w0 + ext[ky][f + 1] * w1 + ext[ky][f + 2] * w2;
            }
        }
    }

    #pragma unroll
    for (int o = 0; o < 8; ++o) {
        bf16 ov[8];
        #pragma unroll
        for (int f = 0; f < 8; ++f) ov[f] = f2b(acc[o][f]);
        *(uint4*)(u + ((size_t)((r * 8 + o) * 3136 + p)) * 32 + f0) = *(uint4*)ov;
    }
}

// ---------------------------------------------------------------------------
// Partial sums per (group, quarter): 256 blocks, each reduces 25088 elems.
// ---------------------------------------------------------------------------
__global__ __launch_bounds__(256) void lnstats_kernel(
    const bf16* __restrict__ u, float* __restrict__ stats4)
{
    int g4 = blockIdx.x;
    const bf16* p = u + (size_t)g4 * 25088;
    int tid = threadIdx.x;
    float s = 0.f, s2 = 0.f;
    for (int it = tid; it < 3136; it += 256) {
        V16 uv; uv.u4 = *(const uint4*)(p + it * 8);
        #pragma unroll
        for (int j = 0; j < 8; ++j) {
            unsigned sh = uv.u[j >> 1];
            unsigned bits = (j & 1) ? (sh & 0xffff0000u) : (sh << 16);
            union { unsigned uu; float fl; } cv; cv.uu = bits;
            s += cv.fl; s2 += cv.fl * cv.fl;
        }
    }
    __shared__ float r1[256], r2[256];
    r1[tid] = s; r2[tid] = s2; __syncthreads();
    for (int st = 128; st > 0; st >>= 1) {
        if (tid < st) { r1[tid] += r1[tid + st]; r2[tid] += r2[tid + st]; }
        __syncthreads();
    }
    if (tid == 0) {
        stats4[g4 * 2]     = r1[0];
        stats4[g4 * 2 + 1] = r2[0];
    }
}

// ref_attn += gelu_exact( (u - mean) * rstd );  bf16x8, grid = 3136 blocks.
__global__ __launch_bounds__(256) void lngelu_kernel(
    const bf16* __restrict__ u, const float* __restrict__ stats4,
    bf16* __restrict__ ref_attn)
{
    int idx8 = blockIdx.x * 256 + threadIdx.x;    // < 802816
    int g = idx8 / 12544;
    size_t base = (size_t)idx8 * 8;
    float sum = 0.f, sq = 0.f;
    #pragma unroll
    for (int q = 0; q < 4; ++q) {
        sum += stats4[(g * 4 + q) * 2];
        sq  += stats4[(g * 4 + q) * 2 + 1];
    }
    float mean = sum * (1.f / 100352.f);
    float var  = sq * (1.f / 100352.f) - mean * mean;
    var = fmaxf(var, 0.f);
    float rstd = rsqrtf(var + 1e-5f);
    V16 uv; uv.u4 = *(const uint4*)(u + base);
    V16 rv; rv.u4 = *(const uint4*)(ref_attn + base);
    bf16 outv[8];
    #pragma unroll
    for (int j = 0; j < 8; ++j) {
        unsigned shu = uv.u[j >> 1];
        unsigned shr = rv.u[j >> 1];
        unsigned bu = (j & 1) ? (shu & 0xffff0000u) : (shu << 16);
        unsigned br = (j & 1) ? (shr & 0xffff0000u) : (shr << 16);
        union { unsigned uu; float fl; } cu, cr; cu.uu = bu; cr.uu = br;
        float v = (cu.fl - mean) * rstd;
        float ge = 0.5f * v * (1.f + erff(v * 0.7071067811865476f));
        outv[j] = f2b(cr.fl + ge);
    }
    *(uint4*)(ref_attn + base) = *(uint4*)outv;
}

// ---------------------------------------------------------------------------
// qnew_pre: per row (b,n): softmax(32)@ref_v + q_sc, LN(256) -> ln_t (bf16).
// ---------------------------------------------------------------------------
__global__ __launch_bounds__(256) void qnew_pre_kernel(
    const bf16* __restrict__ qkv, const bf16* __restrict__ ref_attn,
    const float* __restrict__ ref_v_t,
    const float* __restrict__ qnw, const float* __restrict__ qnb,
    bf16* __restrict__ ln_t)
{
    int ww = threadIdx.x >> 6, lane = threadIdx.x & 63;
    int row = blockIdx.x * 4 + ww;            // < 25088
    int b = row / 49, n = row % 49;
    int r = b >> 6, w = b & 63;
    int h = lane >> 3, d0 = (lane & 7) * 4;

    const bf16* la = ref_attn + ((size_t)(((r * 8 + h) * 64 + w) * 49 + n)) * 32 + d0;
    ushort4 lu = *(const ushort4*)la;
    float lg[4] = { bu2f(lu.x), bu2f(lu.y), bu2f(lu.z), bu2f(lu.w) };

    float m = fmaxf(fmaxf(lg[0], lg[1]), fmaxf(lg[2], lg[3]));
    m = fmaxf(m, __shfl_xor(m, 1));
    m = fmaxf(m, __shfl_xor(m, 2));
    m = fmaxf(m, __shfl_xor(m, 4));
    float p[4], s = 0.f;
    #pragma unroll
    for (int j = 0; j < 4; ++j) { p[j] = __expf(lg[j] - m); s += p[j]; }
    s += __shfl_xor(s, 1);
    s += __shfl_xor(s, 2);
    s += __shfl_xor(s, 4);
    float inv = 1.f / s;
    #pragma unroll
    for (int j = 0; j < 4; ++j) p[j] *= inv;

    const float* rv = ref_v_t + ((size_t)(r * 8 + h) * 32) * 32 + d0;
    float y[4] = {0.f, 0.f, 0.f, 0.f};
    #pragma unroll
    for (int f = 0; f < 32; ++f) {
        int src = (lane & 56) | (f >> 2);
        float pf = __shfl(p[f & 3], src);
        float4 rvf = *(const float4*)(rv + f * 32);
        y[0] += pf * rvf.x; y[1] += pf * rvf.y;
        y[2] += pf * rvf.z; y[3] += pf * rvf.w;
    }

    ushort4 qu = *(const ushort4*)(qkv + (size_t)row * 768 + lane * 4);
    float z[4] = { y[0] + bu2f(qu.x), y[1] + bu2f(qu.y),
                   y[2] + bu2f(qu.z), y[3] + bu2f(qu.w) };

    float s1 = z[0] + z[1] + z[2] + z[3];
    #pragma unroll
    for (int off = 1; off < 64; off <<= 1) s1 += __shfl_xor(s1, off);
    float mean = s1 * (1.f / 256.f);
    float zc[4] = { z[0] - mean, z[1] - mean, z[2] - mean, z[3] - mean };
    float s2 = zc[0]*zc[0] + zc[1]*zc[1] + zc[2]*zc[2] + zc[3]*zc[3];
    #pragma unroll
    for (int off = 1; off < 64; off <<= 1) s2 += __shfl_xor(s2, off);
    float rstd = rsqrtf(s2 * (1.f / 256.f) + 1e-5f);

    float4 wv = *(const float4*)(qnw + lane * 4);
    float4 bv = *(const float4*)(qnb + lane * 4);
    bf16 outv[4];
    outv[0] = f2b(zc[0] * rstd * wv.x + bv.x);
    outv[1] = f2b(zc[1] * rstd * wv.y + bv.y);
    outv[2] = f2b(zc[2] * rstd * wv.z + bv.z);
    outv[3] = f2b(zc[3] * rstd * wv.w + bv.w);
    *(ushort4*)(ln_t + (size_t)row * 256 + lane * 4) = *(ushort4*)outv;
}

// ---------------------------------------------------------------------------
// MFMA window attention: ONE WAVE per (b,h), no __syncthreads.
// ---------------------------------------------------------------------------
__global__ __launch_bounds__(256) void winattn_kernel(
    const bf16* __restrict__ qkv, const bf16* __restrict__ q_new,
    const float* __restrict__ rel_bias, bf16* __restrict__ attn_out)
{
    const int wv = threadIdx.x >> 6, lane = threadIdx.x & 63;
    const int quad = lane >> 4, l15 = lane & 15;
    const int b = blockIdx.x >> 1;
    const int h = (blockIdx.x & 1) * 4 + wv;

    __shared__ bf16 lds[4 * 6912];           // per wave: P[64*72] + vT[32*72]
    bf16* P  = &lds[wv * 6912];
    bf16* vT = P + 4608;

    {
        int m = lane;
        if (m < 49) {
            const bf16* vp = qkv + ((size_t)(b * 49 + m)) * 768 + 512 + h * 32;
            V16 v0, v1, v2, v3;
            v0.u4 = *(const uint4*)(vp);
            v1.u4 = *(const uint4*)(vp + 8);
            v2.u4 = *(const uint4*)(vp + 16);
            v3.u4 = *(const uint4*)(vp + 24);
            #pragma unroll
            for (int d = 0; d < 8; ++d) {
                ((unsigned short*)vT)[d * 72 + m]        = v0.s[d];
                ((unsigned short*)vT)[(d + 8) * 72 + m]  = v1.s[d];
                ((unsigned short*)vT)[(d + 16) * 72 + m] = v2.s[d];
                ((unsigned short*)vT)[(d + 24) * 72 + m] = v3.s[d];
            }
        } else {
            #pragma unroll
            for (int d = 0; d < 32; ++d)
                ((unsigned short*)vT)[d * 72 + m] = 0;
        }
    }

    s16x8 aq[4], bk[4];
    #pragma unroll
    for (int t = 0; t < 4; ++t) {
        int qr = t * 16 + l15; qr = qr > 48 ? 48 : qr;
        aq[t] = ld16g(q_new + ((size_t)(b * 49 + qr)) * 256 + h * 32 + quad * 8);
        bk[t] = ld16g(qkv + ((size_t)(b * 49 + qr)) * 768 + 256 + h * 32 + quad * 8);
    }
    f32x4 S[4][4];
    #pragma unroll
    for (int tn = 0; tn < 4; ++tn)
        #pragma unroll
        for (int tm = 0; tm < 4; ++tm) {
            #pragma unroll
            for (int r = 0; r < 4; ++r) S[tn][tm][r] = 0.f;
            S[tn][tm] = __builtin_amdgcn_mfma_f32_16x16x32_bf16(aq[tn], bk[tm], S[tn][tm], 0, 0, 0);
        }

    int mvalid[4], mi[4], mj[4];
    #pragma unroll
    for (int tm = 0; tm < 4; ++tm) {
        int m0 = tm * 16 + l15;
        mvalid[tm] = (m0 < 49);
        int mc = m0 > 48 ? 48 : m0;
        mi[tm] = mc / 7; mj[tm] = mc - mi[tm] * 7;
    }
    #pragma unroll
    for (int tn = 0; tn < 4; ++tn) {
        #pragma unroll
        for (int r = 0; r < 4; ++r) {
            int n0 = tn * 16 + quad * 4 + r;
            int nc = n0 > 48 ? 48 : n0;
            int ni = nc / 7, nj = nc - (nc / 7) * 7;
            float vals[4];
            float mx = -1e30f;
            #pragma unroll
            for (int tm = 0; tm < 4; ++tm) {
                float v = S[tn][tm][r]
                        + rel_bias[((ni - mi[tm] + 6) * 13 + (nj - mj[tm] + 6)) * 8 + h];
                if (!mvalid[tm]) v = -1e30f;
                vals[tm] = v;
                mx = fmaxf(mx, v);
            }
            mx = fmaxf(mx, __shfl_xor(mx, 1));
            mx = fmaxf(mx, __shfl_xor(mx, 2));
            mx = fmaxf(mx, __shfl_xor(mx, 4));
            mx = fmaxf(mx, __shfl_xor(mx, 8));
            float s = 0.f;
            #pragma unroll
            for (int tm = 0; tm < 4; ++tm) { vals[tm] = __expf(vals[tm] - mx); s += vals[tm]; }
            s += __shfl_xor(s, 1);
            s += __shfl_xor(s, 2);
            s += __shfl_xor(s, 4);
            s += __shfl_xor(s, 8);
            float inv = 1.f / s;
            #pragma unroll
            for (int tm = 0; tm < 4; ++tm)
                ((unsigned short*)P)[n0 * 72 + tm * 16 + l15] = f2bs(vals[tm] * inv);
        }
    }

    f32x4 O[4][2];
    #pragma unroll
    for (int tn = 0; tn < 4; ++tn)
        #pragma unroll
        for (int td = 0; td < 2; ++td)
            #pragma unroll
            for (int r = 0; r < 4; ++r) O[tn][td][r] = 0.f;

    #pragma unroll
    for (int ks = 0; ks < 2; ++ks) {
        s16x8 bv0 = *(const s16x8*)&vT[(0 * 16 + l15) * 72 + ks * 32 + quad * 8];
        s16x8 bv1 = *(const s16x8*)&vT[(1 * 16 + l15) * 72 + ks * 32 + quad * 8];
        #pragma unroll
        for (int tn = 0; tn < 4; ++tn) {
            s16x8 ap = *(const s16x8*)&P[(tn * 16 + l15) * 72 + ks * 32 + quad * 8];
            O[tn][0] = __builtin_amdgcn_mfma_f32_16x16x32_bf16(ap, bv0, O[tn][0], 0, 0, 0);
            O[tn][1] = __builtin_amdgcn_mfma_f32_16x16x32_bf16(ap, bv1, O[tn][1], 0, 0, 0);
        }
    }

    #pragma unroll
    for (int tn = 0; tn < 4; ++tn)
        #pragma unroll
        for (int r = 0; r < 4; ++r) {
            int n0 = tn * 16 + quad * 4 + r;
            if (n0 < 49) {
                size_t base = ((size_t)(b * 49 + n0)) * 256 + h * 32;
                attn_out[base + l15]      = f2b(O[tn][0][r]);
                attn_out[base + 16 + l15] = f2b(O[tn][1][r]);
            }
        }
}

// ---------------------------------------------------------------------------
// MFMA class-token attention: ONE WAVE per (b,h), no __syncthreads.
// ---------------------------------------------------------------------------
__global__ __launch_bounds__(256) void clsattn_kernel(
    const bf16* __restrict__ tkv,
    const bf16* __restrict__ depth_q, const bf16* __restrict__ seg_q,
    bf16* __restrict__ d_pre, bf16* __restrict__ s_pre)
{
    const int wv = threadIdx.x >> 6, lane = threadIdx.x & 63;
    const int quad = lane >> 4, l15 = lane & 15;
    const int bh = blockIdx.x * 4 + wv;      // < 4096
    const int b = bh >> 3, h = bh & 7;

    __shared__ bf16 lds[4 * 5760];
    unsigned short* QP = (unsigned short*)&lds[wv * 5760];   // 16 x 72
    unsigned short* KV = QP + 1152;                          // 64 x 72 (max use 4608)

    {
        int n = lane;
        V16 dv, sv;
        if (n < 49) {
            dv.u4 = *(const uint4*)(depth_q + ((size_t)(b * 49 + n)) * 64 + h * 8);
            sv.u4 = *(const uint4*)(seg_q   + ((size_t)(b * 49 + n)) * 64 + h * 8);
        } else {
            dv.u4 = make_uint4(0, 0, 0, 0); sv.u4 = make_uint4(0, 0, 0, 0);
        }
        #pragma unroll
        for (int c = 0; c < 8; ++c) {
            QP[c * 72 + n]       = dv.s[c];
            QP[(8 + c) * 72 + n] = sv.s[c];
        }
    }
    {
        int n = lane;
        V16 k[6];
        if (n < 49) {
            const bf16* kp = tkv + ((size_t)(b * 49 + n)) * 768 + h * 48;
            #pragma unroll
            for (int c6 = 0; c6 < 6; ++c6) k[c6].u4 = *(const uint4*)(kp + c6 * 8);
        } else {
            #pragma unroll
            for (int c6 = 0; c6 < 6; ++c6) k[c6].u4 = make_uint4(0, 0, 0, 0);
        }
        #pragma unroll
        for (int c6 = 0; c6 < 6; ++c6)
            #pragma unroll
            for (int j = 0; j < 8; ++j)
                KV[(c6 * 8 + j) * 72 + n] = k[c6].s[j];
    }

    f32x4 S[3];
    #pragma unroll
    for (int t3 = 0; t3 < 3; ++t3)
        #pragma unroll
        for (int r = 0; r < 4; ++r) S[t3][r] = 0.f;
    #pragma unroll
    for (int ks = 0; ks < 2; ++ks) {
        s16x8 a = *(const s16x8*)&QP[l15 * 72 + ks * 32 + quad * 8];
        #pragma unroll
        for (int t3 = 0; t3 < 3; ++t3) {
            s16x8 bf = *(const s16x8*)&KV[(t3 * 16 + l15) * 72 + ks * 32 + quad * 8];
            S[t3] = __builtin_amdgcn_mfma_f32_16x16x32_bf16(a, bf, S[t3], 0, 0, 0);
        }
    }

    #pragma unroll
    for (int r = 0; r < 4; ++r) {
        float v0 = S[0][r], v1 = S[1][r], v2 = S[2][r];
        float mx = fmaxf(fmaxf(v0, v1), v2);
        mx = fmaxf(mx, __shfl_xor(mx, 1));
        mx = fmaxf(mx, __shfl_xor(mx, 2));
        mx = fmaxf(mx, __shfl_xor(mx, 4));
        mx = fmaxf(mx, __shfl_xor(mx, 8));
        float e0 = __expf(v0 - mx), e1 = __expf(v1 - mx), e2 = __expf(v2 - mx);
        float s = e0 + e1 + e2;
        s += __shfl_xor(s, 1);
        s += __shfl_xor(s, 2);
        s += __shfl_xor(s, 4);
        s += __shfl_xor(s, 8);
        float inv = 1.f / s;
        int c = quad * 4 + r;
        QP[c * 72 + 0 * 16 + l15] = f2bs(e0 * inv);
        QP[c * 72 + 1 * 16 + l15] = f2bs(e1 * inv);
        QP[c * 72 + 2 * 16 + l15] = f2bs(e2 * inv);
    }
    #pragma unroll
    for (int z = 0; z < 4; ++z)
        QP[(lane & 15) * 72 + 48 + (lane >> 4) * 4 + z] = 0;

    {
        int n = lane;
        V16 v[6], zv; zv.u4 = make_uint4(0, 0, 0, 0);
        if (n < 49) {
            const bf16* vp = tkv + ((size_t)(b * 49 + n)) * 768 + 384 + h * 48;
            #pragma unroll
            for (int c6 = 0; c6 < 6; ++c6) v[c6].u4 = *(const uint4*)(vp + c6 * 8);
        } else {
            #pragma unroll
            for (int c6 = 0; c6 < 6; ++c6) v[c6].u4 = zv.u4;
        }
        #pragma unroll
        for (int c6 = 0; c6 < 6; ++c6)
            *(uint4*)&KV[n * 72 + c6 * 8] = v[c6].u4;
        *(uint4*)&KV[n * 72 + 48] = zv.u4;
        *(uint4*)&KV[n * 72 + 56] = zv.u4;
    }

    f32x4 O[4];
    #pragma unroll
    for (int t4 = 0; t4 < 4; ++t4)
        #pragma unroll
        for (int r = 0; r < 4; ++r) O[t4][r] = 0.f;
    #pragma unroll
    for (int ks = 0; ks < 2; ++ks) {
        s16x8 a = *(const s16x8*)&QP[l15 * 72 + ks * 32 + quad * 8];
        #pragma unroll
        for (int t4 = 0; t4 < 4; ++t4) {
            s16x8 bf = *(const s16x8*)&KV[(t4 * 16 + l15) * 72 + ks * 32 + quad * 8];
            O[t4] = __builtin_amdgcn_mfma_f32_16x16x32_bf16(a, bf, O[t4], 0, 0, 0);
        }
    }

    #pragma unroll
    for (int t4 = 0; t4 < 4; ++t4) {
        int n = t4 * 16 + l15;
        if (n < 49) {
            size_t base = ((size_t)(b * 49 + n)) * 64 + h * 8;
            #pragma unroll
            for (int r = 0; r < 4; ++r) {
                int c = quad * 4 + r;
                if (c < 8) d_pre[base + c] = f2b(O[t4][r]);
                else       s_pre[base + c - 8] = f2b(O[t4][r]);
            }
        }
    }
}

// ---------------------------------------------------------------------------
extern "C" void kernel_launch(void* const* d_in, const int* in_sizes, int n_in,
                              void* d_out, int out_size, void* d_ws, size_t ws_size,
                              hipStream_t stream)
{
    const float* x          = (const float*)d_in[0];
    const float* x_ref      = (const float*)d_in[1];
    const float* dth_tok    = (const float*)d_in[2];
    const float* seg_tok    = (const float*)d_in[3];
    const float* qkv_w      = (const float*)d_in[4];
    const float* qkv_b      = (const float*)d_in[5];
    const float* proj_w     = (const float*)d_in[6];
    const float* proj_b     = (const float*)d_in[7];
    const float* rel_bias   = (const float*)d_in[8];
    const float* diff_mu    = (const float*)d_in[9];
    const float* diff_ls    = (const float*)d_in[10];
    const float* ref_qk_w   = (const float*)d_in[11];
    const float* ref_qk_b   = (const float*)d_in[12];
    const float* conv_w     = (const float*)d_in[13];
    const float* conv_b     = (const float*)d_in[14];
    const float* q_norm_w   = (const float*)d_in[15];
    const float* q_norm_b   = (const float*)d_in[16];
    const float* q_proj_w   = (const float*)d_in[17];
    const float* q_proj_b   = (const float*)d_in[18];
    const float* cls_dth_w  = (const float*)d_in[19];
    const float* cls_dth_b  = (const float*)d_in[20];
    const float* cls_seg_w  = (const float*)d_in[21];
    const float* cls_seg_b  = (const float*)d_in[22];
    const float* glob_k_w   = (const float*)d_in[23];
    const float* glob_k_b   = (const float*)d_in[24];
    const float* glob_v_w   = (const float*)d_in[25];
    const float* glob_v_b   = (const float*)d_in[26];
    const float* proj_dth_w = (const float*)d_in[27];
    const float* proj_dth_b = (const float*)d_in[28];

    // ---- workspace layout ----
    bf16* wsb = (bf16*)d_ws;
    bf16* qkv      = wsb;                      // [25088,768]; later tkv [25088,768]
    bf16* tkv      = wsb;
    bf16* ref_attn = wsb + 19267584;           // R1
    bf16* q_new    = ref_attn;
    bf16* out0b    = ref_attn;
    bf16* depth_q  = ref_attn;
    bf16* seg_q    = ref_attn + 1605632;
    bf16* d_pre    = ref_attn + 3211264;
    bf16* s_pre    = ref_attn + 4816896;
    bf16* u_buf    = wsb + 25690112;           // R3
    bf16* xb       = u_buf;
    bf16* ln_t     = u_buf;
    bf16* attn_out = u_buf;
    float* ref_qk  = (float*)((char*)d_ws + 64225280);
    float* ref_q_t = ref_qk + 131072;
    float* ref_v_t = ref_q_t + 65536;
    float* stats4  = ref_qk;                   // 512 f32, reuses dead ref_qk

    float* out0  = (float*)d_out;
    float* out_d = out0 + 6422528;
    float* out_s = out0 + 8028160;

    // scratch in output regions (dead until final small64)
    bf16* Wt_all = (bf16*)out_d;               // 622592 elems = 1.19 MiB
    bf16* tokb   = (bf16*)out_s;               // [25088,128] bf16 = 6.125 MiB

    // 0. weight prep + input conversions
    prep_weights<<<2432, 256, 0, stream>>>(qkv_w, q_proj_w, proj_w, glob_k_w, glob_v_w, Wt_all);
    convert_f32_bf16<<<6272, 256, 0, stream>>>(x, xb);
    tok2b_kernel<<<1568, 256, 0, stream>>>(dth_tok, seg_tok, tokb);

    // 1. qkv = x @ qkv_w + b
    gemm_pipe<0><<<dim3(6, 196), 256, 0, stream>>>(xb, 256, nullptr,
        Wt_all, qkv_b, nullptr, nullptr, 0, nullptr, qkv, 768, 256, 768, 1.f);
    // 2. ref_qk = x_ref @ ref_qk_w + b (small)
    mfma_gemm<<<dim3(8, 4), 256, 0, stream>>>(x_ref, 0, ref_qk_w, ref_qk_b,
                                              ref_qk, nullptr, 256, 256, 512, 1.f);
    // 3. ref_q_t / ref_v_t
    refprep_kernel<<<256, 256, 0, stream>>>(ref_qk, diff_mu, diff_ls, ref_q_t, ref_v_t);
    // 4. ref_attn scores
    refattn_kernel<<<4096, 256, 0, stream>>>(qkv, ref_q_t, ref_attn);
    // 5. 3x diffusion
    for (int it = 0; it < 3; ++it) {
        conv_kernel<<<392, 256, 0, stream>>>(ref_attn, conv_w, conv_b, u_buf);
        lnstats_kernel<<<256, 256, 0, stream>>>(u_buf, stats4);
        lngelu_kernel<<<3136, 256, 0, stream>>>(u_buf, stats4, ref_attn);
    }
    // 6. softmax @ ref_v + shortcut + LN -> ln_t
    qnew_pre_kernel<<<6272, 256, 0, stream>>>(qkv, ref_attn, ref_v_t,
                                              q_norm_w, q_norm_b, ln_t);
    // 7. q_new = (ln_t @ q_proj_w + b + qsc) * SCALE
    gemm_pipe<0><<<dim3(2, 196), 256, 0, stream>>>(ln_t, 256, nullptr,
        Wt_all + 196608, q_proj_b, nullptr, qkv, 768, nullptr, q_new, 256, 256, 256, SCALE_T);
    // 8. window attention
    winattn_kernel<<<1024, 256, 0, stream>>>(qkv, q_new, rel_bias, attn_out);
    // 9. out0 = attn_out @ proj_w + b   (f32 to d_out, bf16 copy to out0b)
    gemm_pipe<0><<<dim3(2, 196), 256, 0, stream>>>(attn_out, 256, nullptr,
        Wt_all + 262144, proj_b, nullptr, nullptr, 0, out0, out0b, 256, 256, 256, 1.f);
    // 10. fused t_k|t_v = concat(out0b, tokb) @ [gk|gv] + b -> tkv [25088,768]
    gemm_pipe<1><<<dim3(6, 196), 256, 0, stream>>>(out0b, 256, tokb,
        Wt_all + 327680, glob_k_b, glob_v_b, nullptr, 0, nullptr, tkv, 768, 384, 768, 1.f);
    // 12/13. depth_q, seg_q in ONE launch
    small64<1, 0><<<dim3(392, 2), 256, 0, stream>>>(dth_tok, seg_tok,
        cls_dth_w, cls_seg_w, cls_dth_b, cls_seg_b, depth_q, seg_q, SCALE_T);
    // 14. class-token attention
    clsattn_kernel<<<1024, 256, 0, stream>>>(tkv, depth_q, seg_q, d_pre, s_pre);
    // 15/16. final proj_dth in ONE launch (f32 out; overwrites Wt/tokb scratch)
    small64<0, 1><<<dim3(392, 2), 256, 0, stream>>>(d_pre, s_pre,
        proj_dth_w, proj_dth_w, proj_dth_b, proj_dth_b, out_d, out_s, 1.f);
}

// Round 6
// 477.152 us; speedup vs baseline: 1.0839x; 1.0401x over previous
//
#include <hip/hip_runtime.h>
#include <hip/hip_bf16.h>

typedef __hip_bfloat16 bf16;
typedef short s16x8 __attribute__((ext_vector_type(8)));
typedef float f32x4 __attribute__((ext_vector_type(4)));
union V16 { uint4 u4; s16x8 s8; unsigned u[4]; unsigned short s[8]; };

static __device__ __forceinline__ float b2f(bf16 v){ return __bfloat162float(v); }
static __device__ __forceinline__ bf16  f2b(float v){ return __float2bfloat16(v); }
static __device__ __forceinline__ unsigned short f2bs(float x){
    union { float f; unsigned u; } c; c.f = x;
    unsigned r = c.u + 0x7fff + ((c.u >> 16) & 1);
    return (unsigned short)(r >> 16);
}
static __device__ __forceinline__ float bu2f(unsigned short b){
    union { unsigned u; float f; } c; c.u = ((unsigned)b) << 16; return c.f;
}
static __device__ __forceinline__ s16x8 ld16g(const bf16* p){
    V16 u; u.u4 = *(const uint4*)p; return u.s8;
}
static __device__ __forceinline__ void glds16(const void* g, void* l){
    __builtin_amdgcn_global_load_lds(
        (const __attribute__((address_space(1))) unsigned*)g,
        (__attribute__((address_space(3))) unsigned*)l, 16, 0, 0);
}

#define SCALE_T 0.17677669529663687f   // 32^-0.5

// ---------------------------------------------------------------------------
// prep_all: one launch for all input prep.
//  blocks [0,2432):    weight transpose+convert -> Wt (622592 elems)
//  blocks [2432,8704): x f32 -> xb bf16 (1605632 x 4 elems)
//  blocks [8704,10272): tokens -> tokb[row][128] bf16 (401408 x 8 elems)
// ---------------------------------------------------------------------------
__global__ __launch_bounds__(256) void prep_all(
    const float* __restrict__ qkvw, const float* __restrict__ qpw,
    const float* __restrict__ pw,   const float* __restrict__ gkw,
    const float* __restrict__ gvw,  bf16* __restrict__ Wt,
    const float* __restrict__ x,    bf16* __restrict__ xb,
    const float* __restrict__ dth,  const float* __restrict__ seg,
    bf16* __restrict__ tokb)
{
    int blk = blockIdx.x, tid = threadIdx.x;
    if (blk < 2432) {
        int idx = blk * 256 + tid;   // < 622592
        float v;
        if (idx < 196608)      { int j = idx;          int n = j >> 8, k = j & 255; v = qkvw[k * 768 + n]; }
        else if (idx < 262144) { int j = idx - 196608; int n = j >> 8, k = j & 255; v = qpw[k * 256 + n]; }
        else if (idx < 327680) { int j = idx - 262144; int n = j >> 8, k = j & 255; v = pw[k * 256 + n]; }
        else if (idx < 475136) { int j = idx - 327680; int n = j / 384, k = j - n * 384; v = gkw[k * 384 + n]; }
        else                   { int j = idx - 475136; int n = j / 384, k = j - n * 384; v = gvw[k * 384 + n]; }
        ((unsigned short*)Wt)[idx] = f2bs(v);
    } else if (blk < 8704) {
        int i = (blk - 2432) * 256 + tid;   // < 1605632
        float4 v = ((const float4*)x)[i];
        ushort4 o;
        o.x = f2bs(v.x); o.y = f2bs(v.y); o.z = f2bs(v.z); o.w = f2bs(v.w);
        ((ushort4*)xb)[i] = o;
    } else {
        int i = (blk - 8704) * 256 + tid;   // < 401408
        int row = i >> 4, j8 = i & 15;
        const float* src = (j8 < 8) ? (dth + (size_t)row * 64 + j8 * 8)
                                    : (seg + (size_t)row * 64 + (j8 - 8) * 8);
        float4 u0 = ((const float4*)src)[0];
        float4 u1 = ((const float4*)src)[1];
        V16 o;
        o.s[0] = f2bs(u0.x); o.s[1] = f2bs(u0.y);
        o.s[2] = f2bs(u0.z); o.s[3] = f2bs(u0.w);
        o.s[4] = f2bs(u1.x); o.s[5] = f2bs(u1.y);
        o.s[6] = f2bs(u1.z); o.s[7] = f2bs(u1.w);
        *(uint4*)(tokb + (size_t)row * 128 + j8 * 8) = o.u4;
    }
}

// ---------------------------------------------------------------------------
// gemm_pipe: out = (A[M,K]bf16 @ Wt[N,K]^T + bias [+ add]) * scale
// 128x128 tile, BK=32, 4 waves (2x2). 4-deep LDS ring (64KB), counted-vmcnt
// software pipeline (measured-passing round-4 version, verbatim).
// TOK: K-tiles >= 256 come from A2 (bf16, lda 128).
// ---------------------------------------------------------------------------
template<int TOK>
__global__ __launch_bounds__(256, 2) void gemm_pipe(
    const bf16* __restrict__ A, int lda, const bf16* __restrict__ A2,
    const bf16* __restrict__ Wt, const float* __restrict__ bias,
    const float* __restrict__ bias2,
    const bf16* __restrict__ addp, int addStride,
    float* __restrict__ outF, bf16* __restrict__ outB, int outStrideB,
    int K, int N, float scale)
{
    __shared__ char lds[4][16384];            // ring: per buf A 8KB | B 8KB

    const int tid = threadIdx.x;
    const int wv = tid >> 6, lane = tid & 63;
    const int quad = lane >> 4, l15 = lane & 15;
    const int wr = wv >> 1, wc = wv & 1;

    const int gx = (int)gridDim.x;
    const int nwg = gx * (int)gridDim.y;
    int bid = (int)blockIdx.y * gx + (int)blockIdx.x;
    if ((nwg & 7) == 0) bid = (bid & 7) * (nwg >> 3) + (bid >> 3);
    const int bx = bid % gx, by = bid / gx;
    const int rowBase = by * 128, colBase = bx * 128;

    // staging: row srow = tid>>2, slot s = tid&3 holds k-quad (s ^ ((srow>>1)&3))
    const int srow = tid >> 2;
    const int kOffE = (((tid & 3) ^ ((srow >> 1) & 3)) << 3);   // elems

    // read: quad q of row l15 lives at slot (q ^ ((l15>>1)&3))
    const unsigned swz = (unsigned)((quad ^ ((l15 >> 1) & 3)) << 4);
    const unsigned aoff0 = (unsigned)(wr * 4096 + l15 * 64) + swz;
    const unsigned boff0 = (unsigned)(wc * 4096 + l15 * 64) + swz;

    f32x4 acc[4][4];
    #pragma unroll
    for (int m = 0; m < 4; ++m)
        #pragma unroll
        for (int n = 0; n < 4; ++n)
            #pragma unroll
            for (int r = 0; r < 4; ++r) acc[m][n][r] = 0.f;

    const int nsteps = K >> 5;

    auto stageN = [&](int i) {                // stage K-step i into buf i&3
        int kt = i << 5;
        char* base = &lds[i & 3][0];
        #pragma unroll
        for (int c = 0; c < 2; ++c)
            glds16(Wt + (size_t)(colBase + c * 64 + srow) * K + (kt + kOffE),
                   base + 8192 + c * 4096 + tid * 16);
        if (!TOK || kt < 256) {
            #pragma unroll
            for (int c = 0; c < 2; ++c)
                glds16(A + (size_t)(rowBase + c * 64 + srow) * lda + (kt + kOffE),
                       base + c * 4096 + tid * 16);
        } else {
            #pragma unroll
            for (int c = 0; c < 2; ++c)
                glds16(A2 + (size_t)(rowBase + c * 64 + srow) * 128 + (kt - 256 + kOffE),
                       base + c * 4096 + tid * 16);
        }
    };

    stageN(0);
    if (nsteps > 1) stageN(1);
    if (nsteps > 2) stageN(2);

    for (int i = 0; i < nsteps; ++i) {
        // wait only for stage i (leave younger stages in flight)
        int a = nsteps - 1 - i; if (a > 2) a = 2;
        if (a == 2)      asm volatile("s_waitcnt vmcnt(8)" ::: "memory");
        else if (a == 1) asm volatile("s_waitcnt vmcnt(4)" ::: "memory");
        else             asm volatile("s_waitcnt vmcnt(0)" ::: "memory");
        __builtin_amdgcn_sched_barrier(0);
        __builtin_amdgcn_s_barrier();        // all waves: stage i landed in LDS
        __builtin_amdgcn_sched_barrier(0);

        if (i + 3 < nsteps) stageN(i + 3);   // targets buf (i-1)&3: readers done

        const char* Ab2 = &lds[i & 3][0];
        const char* Bb2 = Ab2 + 8192;
        s16x8 af[4], bfr[4];
        #pragma unroll
        for (int m = 0; m < 4; ++m) af[m]  = *(const s16x8*)(Ab2 + aoff0 + m * 1024);
        #pragma unroll
        for (int n = 0; n < 4; ++n) bfr[n] = *(const s16x8*)(Bb2 + boff0 + n * 1024);
        #pragma unroll
        for (int m = 0; m < 4; ++m)
            #pragma unroll
            for (int n = 0; n < 4; ++n)
                acc[m][n] = __builtin_amdgcn_mfma_f32_16x16x32_bf16(af[m], bfr[n], acc[m][n], 0, 0, 0);
    }
    // last compute reads buf 3 (K=256/384 -> (nsteps-1)&3 == 3); epilogue
    // scratch uses bytes 0..32767 (bufs 0-1) -> disjoint; __syncthreads below
    // orders the repack phases.

    // ---- epilogue ----
    if (outB) {
        #pragma unroll
        for (int n = 0; n < 4; ++n) {
            int col = colBase + wc * 64 + n * 16 + l15;
            float bb = bias2 ? (col < 384 ? bias[col] : bias2[col - 384]) : bias[col];
            #pragma unroll
            for (int m = 0; m < 4; ++m) {
                #pragma unroll
                for (int r = 0; r < 4; ++r) {
                    int rl = wr * 64 + m * 16 + quad * 4 + r;
                    float v = acc[m][n][r] + bb;
                    if (addp) v += b2f(addp[(size_t)(rowBase + rl) * addStride + col]);
                    v *= scale;
                    if (outF) outF[(size_t)(rowBase + rl) * N + col] = v;
                    int cbyte = (wc * 64 + n * 16 + l15) * 2;
                    int blk = ((cbyte >> 5) ^ ((rl >> 2) & 7)) & 7;
                    *(unsigned short*)((char*)lds + rl * 256 + (blk << 5) + (cbyte & 31)) = f2bs(v);
                }
            }
        }
        __syncthreads();
        #pragma unroll
        for (int i = 0; i < 8; ++i) {
            int lin = i * 256 + tid;
            int rl = lin >> 4, cb = lin & 15;
            int cb2 = ((((cb >> 1) ^ ((rl >> 2) & 7)) & 7) << 1) | (cb & 1);
            uint4 val = *(const uint4*)((const char*)lds + rl * 256 + cb2 * 16);
            *(uint4*)(outB + (size_t)(rowBase + rl) * outStrideB + colBase + cb * 8) = val;
        }
    } else {
        #pragma unroll
        for (int n = 0; n < 4; ++n) {
            int col = colBase + wc * 64 + n * 16 + l15;
            float bb = bias2 ? (col < 384 ? bias[col] : bias2[col - 384]) : bias[col];
            #pragma unroll
            for (int m = 0; m < 4; ++m) {
                #pragma unroll
                for (int r = 0; r < 4; ++r) {
                    int rl = wr * 64 + m * 16 + quad * 4 + r;
                    float v = acc[m][n][r] + bb;
                    if (addp) v += b2f(addp[(size_t)(rowBase + rl) * addStride + col]);
                    v *= scale;
                    if (outF) outF[(size_t)(rowBase + rl) * N + col] = v;
                }
            }
        }
    }
}

// ---------------------------------------------------------------------------
// small64: out[M,64] = (A[M,64] @ W[64,64] + bias) * scale, two tasks via
// blockIdx.y.
// ---------------------------------------------------------------------------
template<int AF32, int OF32>
__global__ __launch_bounds__(256) void small64(
    const void* __restrict__ a0, const void* __restrict__ a1,
    const float* __restrict__ w0, const float* __restrict__ w1,
    const float* __restrict__ b0, const float* __restrict__ b1,
    void* __restrict__ o0, void* __restrict__ o1, float scale)
{
    __shared__ unsigned short WT[64 * 72];
    __shared__ float bsh[64];
    const int task = blockIdx.y;
    const void*  A    = task ? a1 : a0;
    const float* W    = task ? w1 : w0;
    const float* bias = task ? b1 : b0;
    void*        outp = task ? o1 : o0;

    int tid = threadIdx.x;
    for (int l = tid; l < 4096; l += 256) {
        int k = l >> 6, n = l & 63;
        WT[n * 72 + k] = f2bs(W[l]);
    }
    if (tid < 64) bsh[tid] = bias[tid];
    __syncthreads();

    const int wv = tid >> 6, lane = tid & 63;
    const int quad = lane >> 4, l15 = lane & 15;
    const int rowBase = blockIdx.x * 64;
    const int arow = rowBase + wv * 16 + l15;

    s16x8 a[2];
    if (AF32) {
        const float* Ar = (const float*)A + (size_t)arow * 64;
        #pragma unroll
        for (int ks = 0; ks < 2; ++ks) {
            float4 u0 = *(const float4*)(Ar + ks * 32 + quad * 8);
            float4 u1 = *(const float4*)(Ar + ks * 32 + quad * 8 + 4);
            V16 o;
            o.s[0] = f2bs(u0.x); o.s[1] = f2bs(u0.y);
            o.s[2] = f2bs(u0.z); o.s[3] = f2bs(u0.w);
            o.s[4] = f2bs(u1.x); o.s[5] = f2bs(u1.y);
            o.s[6] = f2bs(u1.z); o.s[7] = f2bs(u1.w);
            a[ks] = o.s8;
        }
    } else {
        const bf16* Ar = (const bf16*)A + (size_t)arow * 64;
        #pragma unroll
        for (int ks = 0; ks < 2; ++ks)
            a[ks] = ld16g(Ar + ks * 32 + quad * 8);
    }

    f32x4 acc[4];
    #pragma unroll
    for (int n = 0; n < 4; ++n)
        #pragma unroll
        for (int r = 0; r < 4; ++r) acc[n][r] = 0.f;

    #pragma unroll
    for (int ks = 0; ks < 2; ++ks)
        #pragma unroll
        for (int n = 0; n < 4; ++n) {
            s16x8 b = *(const s16x8*)&WT[(n * 16 + l15) * 72 + ks * 32 + quad * 8];
            acc[n] = __builtin_amdgcn_mfma_f32_16x16x32_bf16(a[ks], b, acc[n], 0, 0, 0);
        }

    #pragma unroll
    for (int n = 0; n < 4; ++n) {
        int col = n * 16 + l15;
        float bb = bsh[col];
        #pragma unroll
        for (int r = 0; r < 4; ++r) {
            int row = rowBase + wv * 16 + quad * 4 + r;
            float v = (acc[n][r] + bb) * scale;
            if (OF32) ((float*)outp)[(size_t)row * 64 + col] = v;
            else      ((bf16*)outp)[(size_t)row * 64 + col] = f2b(v);
        }
    }
}

// ---------------------------------------------------------------------------
// Small MFMA GEMM (kept for step 2's tiny 256x512 shape).
// ---------------------------------------------------------------------------
__global__ __launch_bounds__(256) void mfma_gemm(
    const void* __restrict__ A, int a_mode,
    const float* __restrict__ W, const float* __restrict__ bias,
    float* __restrict__ outF, bf16* __restrict__ outB,
    int M, int K, int N, float scale)
{
    __shared__ __hip_bfloat16 Al[64][48];
    __shared__ __hip_bfloat16 Bl[64][48];

    const int tid  = threadIdx.x;
    const int wv   = tid >> 6, lane = tid & 63;
    const int quad = lane >> 4, l15 = lane & 15;
    const int rowBase = blockIdx.y * 64, colBase = blockIdx.x * 64;

    const int am = tid >> 2, ak = (tid & 3) * 8;
    const int bn = tid & 63, bk = (tid >> 6) * 8;

    f32x4 acc[4];
    #pragma unroll
    for (int t = 0; t < 4; ++t)
        #pragma unroll
        for (int r = 0; r < 4; ++r) acc[t][r] = 0.f;

    for (int kt = 0; kt < K; kt += 32) {
        s16x8 sa;
        if (a_mode == 1) {
            const bf16* Ab = (const bf16*)A;
            V16 u; u.u4 = *(const uint4*)(Ab + (size_t)(rowBase + am) * K + kt + ak);
            sa = u.s8;
        } else {
            const float* src = (const float*)A;
            const float4* p = (const float4*)(src + (size_t)(rowBase + am) * K + kt + ak);
            float4 u0 = p[0], u1 = p[1];
            sa[0] = (short)f2bs(u0.x); sa[1] = (short)f2bs(u0.y);
            sa[2] = (short)f2bs(u0.z); sa[3] = (short)f2bs(u0.w);
            sa[4] = (short)f2bs(u1.x); sa[5] = (short)f2bs(u1.y);
            sa[6] = (short)f2bs(u1.z); sa[7] = (short)f2bs(u1.w);
        }
        *(s16x8*)&Al[am][ak] = sa;

        s16x8 sb;
        #pragma unroll
        for (int j = 0; j < 8; ++j)
            sb[j] = (short)f2bs(W[(size_t)(kt + bk + j) * N + colBase + bn]);
        *(s16x8*)&Bl[bn][bk] = sb;

        __syncthreads();

        s16x8 a = *(const s16x8*)&Al[wv * 16 + l15][quad * 8];
        #pragma unroll
        for (int t = 0; t < 4; ++t) {
            s16x8 b = *(const s16x8*)&Bl[t * 16 + l15][quad * 8];
            acc[t] = __builtin_amdgcn_mfma_f32_16x16x32_bf16(a, b, acc[t], 0, 0, 0);
        }
        __syncthreads();
    }

    #pragma unroll
    for (int t = 0; t < 4; ++t) {
        int col = colBase + t * 16 + l15;
        float bb = bias[col];
        #pragma unroll
        for (int r = 0; r < 4; ++r) {
            int row = rowBase + wv * 16 + quad * 4 + r;
            float v = (acc[t][r] + bb) * scale;
            if (outF) outF[(size_t)row * N + col] = v;
            if (outB) outB[(size_t)row * N + col] = f2b(v);
        }
    }
}

// ---------------------------------------------------------------------------
// refprep: rq_b[r,h,f,d] = bf16( (mu[c] + exp(ls[c])*ref_qk[..]) * SCALE_T )
//          ref_v_t f32 from +256.  SCALE_T folded into rq (scores = q.(S*rq)).
// ---------------------------------------------------------------------------
__global__ __launch_bounds__(256) void refprep_kernel(
    const float* __restrict__ ref_qk, const float* __restrict__ mu,
    const float* __restrict__ ls, bf16* __restrict__ rq_b,
    float* __restrict__ ref_v_t)
{
    int idx = blockIdx.x * 256 + threadIdx.x;          // [r,h,f,d]
    int d = idx & 31, h = (idx >> 10) & 7;
    int c = h * 32 + d;
    int f = (idx >> 5) & 31, r = idx >> 13;
    size_t src = (size_t)(r * 32 + f) * 512 + c;
    ((unsigned short*)rq_b)[idx] = f2bs((mu[c] + __expf(ls[c]) * ref_qk[src]) * SCALE_T);
    ref_v_t[idx] = ref_qk[src + 256];
}

// ---------------------------------------------------------------------------
// refattn (MFMA): ref_attn[rh,w,n,f] = sum_d q[b,h,n,d] * rq_b[rh,f,d]
// One wave per (rh,w): 8 MFMA, no LDS, no barriers. grid = 1024 x 256.
// ---------------------------------------------------------------------------
__global__ __launch_bounds__(256) void refattn_kernel(
    const bf16* __restrict__ qkv, const bf16* __restrict__ rq_b,
    bf16* __restrict__ ref_attn)
{
    const int wv = threadIdx.x >> 6, lane = threadIdx.x & 63;
    const int quad = lane >> 4, l15 = lane & 15;
    int blk = blockIdx.x;                 // < 1024
    int rh = blk >> 4;                    // r*8+h
    int h = rh & 7;
    int w = (blk & 15) * 4 + wv;
    int b = (rh >> 3) * 64 + w;

    s16x8 bk0 = ld16g(rq_b + ((size_t)(rh * 32 + l15)) * 32 + quad * 8);
    s16x8 bk1 = ld16g(rq_b + ((size_t)(rh * 32 + 16 + l15)) * 32 + quad * 8);

    s16x8 aq[4];
    #pragma unroll
    for (int t = 0; t < 4; ++t) {
        int qr = t * 16 + l15; qr = qr > 48 ? 48 : qr;
        aq[t] = ld16g(qkv + ((size_t)(b * 49 + qr)) * 768 + h * 32 + quad * 8);
    }

    #pragma unroll
    for (int t = 0; t < 4; ++t) {
        f32x4 S0, S1;
        #pragma unroll
        for (int r = 0; r < 4; ++r) { S0[r] = 0.f; S1[r] = 0.f; }
        S0 = __builtin_amdgcn_mfma_f32_16x16x32_bf16(aq[t], bk0, S0, 0, 0, 0);
        S1 = __builtin_amdgcn_mfma_f32_16x16x32_bf16(aq[t], bk1, S1, 0, 0, 0);
        #pragma unroll
        for (int r = 0; r < 4; ++r) {
            int n0 = t * 16 + quad * 4 + r;
            if (n0 < 49) {
                size_t base = ((size_t)(rh * 64 + w) * 49 + n0) * 32;
                ref_attn[base + l15]      = f2b(S0[r]);
                ref_attn[base + 16 + l15] = f2b(S1[r]);
            }
        }
    }
}

// ---------------------------------------------------------------------------
// 3x3 SAME conv over [RB=8, 8ch, 3136, 32].
// ---------------------------------------------------------------------------
__global__ __launch_bounds__(256) void conv_kernel(
    const bf16* __restrict__ in, const float* __restrict__ conv_w,
    const float* __restrict__ conv_b, bf16* __restrict__ u)
{
    __shared__ float w_s[576];
    __shared__ float b_s[8];
    int tid = threadIdx.x;
    for (int l = tid; l < 576; l += 256) w_s[l] = conv_w[l];
    if (tid < 8) b_s[tid] = conv_b[tid];
    __syncthreads();

    int idx = blockIdx.x * 256 + tid;          // < 100352
    int fb = idx & 3;
    int p  = (idx >> 2) % 3136;
    int r  = idx / 12544;
    int f0 = fb * 8;

    float acc[8][8];
    #pragma unroll
    for (int o = 0; o < 8; ++o) {
        float bo = b_s[o];
        #pragma unroll
        for (int f = 0; f < 8; ++f) acc[o][f] = bo;
    }

    for (int i = 0; i < 8; ++i) {
        float ext[3][10];
        #pragma unroll
        for (int dy = 0; dy < 3; ++dy) {
            int pp = p + dy - 1;
            bool pv = (unsigned)pp < 3136u;
            size_t base = ((size_t)((r * 8 + i) * 3136 + (pv ? pp : 0))) * 32 + f0;
            V16 uv;
            uv.u4 = pv ? *(const uint4*)(in + base) : make_uint4(0, 0, 0, 0);
            #pragma unroll
            for (int j = 0; j < 8; ++j) {
                unsigned sh = uv.u[j >> 1];
                unsigned bits = (j & 1) ? (sh & 0xffff0000u) : (sh << 16);
                union { unsigned uu; float fl; } cv; cv.uu = bits;
                ext[dy][j + 1] = cv.fl;
            }
            ext[dy][0] = (pv && f0 > 0)      ? b2f(in[base - 1]) : 0.f;
            ext[dy][9] = (pv && f0 + 8 < 32) ? b2f(in[base + 8]) : 0.f;
        }
        #pragma unroll
        for (int o = 0; o < 8; ++o) {
            #pragma unroll
            for (int ky = 0; ky < 3; ++ky) {
                const float* wp = &w_s[((o * 8 + i) * 3 + ky) * 3];
                float w0 = wp[0], w1 = wp[1], w2 = wp[2];
                #pragma unroll
                for (int f = 0; f < 8; ++f)
                    acc[o][f] += ext[ky][f] * w0 + ext[ky][f + 1] * w1 + ext[ky][f + 2] * w2;
            }
        }
    }

    #pragma unroll
    for (int o = 0; o < 8; ++o) {
        bf16 ov[8];
        #pragma unroll
        for (int f = 0; f < 8; ++f) ov[f] = f2b(acc[o][f]);
        *(uint4*)(u + ((size_t)((r * 8 + o) * 3136 + p)) * 32 + f0) = *(uint4*)ov;
    }
}

// ---------------------------------------------------------------------------
// Partial sums per (group, quarter): 256 blocks, each reduces 25088 elems.
// ---------------------------------------------------------------------------
__global__ __launch_bounds__(256) void lnstats_kernel(
    const bf16* __restrict__ u, float* __restrict__ stats4)
{
    int g4 = blockIdx.x;
    const bf16* p = u + (size_t)g4 * 25088;
    int tid = threadIdx.x;
    float s = 0.f, s2 = 0.f;
    for (int it = tid; it < 3136; it += 256) {
        V16 uv; uv.u4 = *(const uint4*)(p + it * 8);
        #pragma unroll
        for (int j = 0; j < 8; ++j) {
            unsigned sh = uv.u[j >> 1];
            unsigned bits = (j & 1) ? (sh & 0xffff0000u) : (sh << 16);
            union { unsigned uu; float fl; } cv; cv.uu = bits;
            s += cv.fl; s2 += cv.fl * cv.fl;
        }
    }
    __shared__ float r1[256], r2[256];
    r1[tid] = s; r2[tid] = s2; __syncthreads();
    for (int st = 128; st > 0; st >>= 1) {
        if (tid < st) { r1[tid] += r1[tid + st]; r2[tid] += r2[tid + st]; }
        __syncthreads();
    }
    if (tid == 0) {
        stats4[g4 * 2]     = r1[0];
        stats4[g4 * 2 + 1] = r2[0];
    }
}

// ref_attn += gelu_exact( (u - mean) * rstd );  bf16x8, grid = 3136 blocks.
__global__ __launch_bounds__(256) void lngelu_kernel(
    const bf16* __restrict__ u, const float* __restrict__ stats4,
    bf16* __restrict__ ref_attn)
{
    int idx8 = blockIdx.x * 256 + threadIdx.x;    // < 802816
    int g = idx8 / 12544;
    size_t base = (size_t)idx8 * 8;
    float sum = 0.f, sq = 0.f;
    #pragma unroll
    for (int q = 0; q < 4; ++q) {
        sum += stats4[(g * 4 + q) * 2];
        sq  += stats4[(g * 4 + q) * 2 + 1];
    }
    float mean = sum * (1.f / 100352.f);
    float var  = sq * (1.f / 100352.f) - mean * mean;
    var = fmaxf(var, 0.f);
    float rstd = rsqrtf(var + 1e-5f);
    V16 uv; uv.u4 = *(const uint4*)(u + base);
    V16 rv; rv.u4 = *(const uint4*)(ref_attn + base);
    bf16 outv[8];
    #pragma unroll
    for (int j = 0; j < 8; ++j) {
        unsigned shu = uv.u[j >> 1];
        unsigned shr = rv.u[j >> 1];
        unsigned bu = (j & 1) ? (shu & 0xffff0000u) : (shu << 16);
        unsigned br = (j & 1) ? (shr & 0xffff0000u) : (shr << 16);
        union { unsigned uu; float fl; } cu, cr; cu.uu = bu; cr.uu = br;
        float v = (cu.fl - mean) * rstd;
        float ge = 0.5f * v * (1.f + erff(v * 0.7071067811865476f));
        outv[j] = f2b(cr.fl + ge);
    }
    *(uint4*)(ref_attn + base) = *(uint4*)outv;
}

// ---------------------------------------------------------------------------
// qnew_pre: per row (b,n): softmax(32)@ref_v + q_sc, LN(256) -> ln_t (bf16).
// ---------------------------------------------------------------------------
__global__ __launch_bounds__(256) void qnew_pre_kernel(
    const bf16* __restrict__ qkv, const bf16* __restrict__ ref_attn,
    const float* __restrict__ ref_v_t,
    const float* __restrict__ qnw, const float* __restrict__ qnb,
    bf16* __restrict__ ln_t)
{
    int ww = threadIdx.x >> 6, lane = threadIdx.x & 63;
    int row = blockIdx.x * 4 + ww;            // < 25088
    int b = row / 49, n = row % 49;
    int r = b >> 6, w = b & 63;
    int h = lane >> 3, d0 = (lane & 7) * 4;

    const bf16* la = ref_attn + ((size_t)(((r * 8 + h) * 64 + w) * 49 + n)) * 32 + d0;
    ushort4 lu = *(const ushort4*)la;
    float lg[4] = { bu2f(lu.x), bu2f(lu.y), bu2f(lu.z), bu2f(lu.w) };

    float m = fmaxf(fmaxf(lg[0], lg[1]), fmaxf(lg[2], lg[3]));
    m = fmaxf(m, __shfl_xor(m, 1));
    m = fmaxf(m, __shfl_xor(m, 2));
    m = fmaxf(m, __shfl_xor(m, 4));
    float p[4], s = 0.f;
    #pragma unroll
    for (int j = 0; j < 4; ++j) { p[j] = __expf(lg[j] - m); s += p[j]; }
    s += __shfl_xor(s, 1);
    s += __shfl_xor(s, 2);
    s += __shfl_xor(s, 4);
    float inv = 1.f / s;
    #pragma unroll
    for (int j = 0; j < 4; ++j) p[j] *= inv;

    const float* rv = ref_v_t + ((size_t)(r * 8 + h) * 32) * 32 + d0;
    float y[4] = {0.f, 0.f, 0.f, 0.f};
    #pragma unroll
    for (int f = 0; f < 32; ++f) {
        int src = (lane & 56) | (f >> 2);
        float pf = __shfl(p[f & 3], src);
        float4 rvf = *(const float4*)(rv + f * 32);
        y[0] += pf * rvf.x; y[1] += pf * rvf.y;
        y[2] += pf * rvf.z; y[3] += pf * rvf.w;
    }

    ushort4 qu = *(const ushort4*)(qkv + (size_t)row * 768 + lane * 4);
    float z[4] = { y[0] + bu2f(qu.x), y[1] + bu2f(qu.y),
                   y[2] + bu2f(qu.z), y[3] + bu2f(qu.w) };

    float s1 = z[0] + z[1] + z[2] + z[3];
    #pragma unroll
    for (int off = 1; off < 64; off <<= 1) s1 += __shfl_xor(s1, off);
    float mean = s1 * (1.f / 256.f);
    float zc[4] = { z[0] - mean, z[1] - mean, z[2] - mean, z[3] - mean };
    float s2 = zc[0]*zc[0] + zc[1]*zc[1] + zc[2]*zc[2] + zc[3]*zc[3];
    #pragma unroll
    for (int off = 1; off < 64; off <<= 1) s2 += __shfl_xor(s2, off);
    float rstd = rsqrtf(s2 * (1.f / 256.f) + 1e-5f);

    float4 wv = *(const float4*)(qnw + lane * 4);
    float4 bv = *(const float4*)(qnb + lane * 4);
    bf16 outv[4];
    outv[0] = f2b(zc[0] * rstd * wv.x + bv.x);
    outv[1] = f2b(zc[1] * rstd * wv.y + bv.y);
    outv[2] = f2b(zc[2] * rstd * wv.z + bv.z);
    outv[3] = f2b(zc[3] * rstd * wv.w + bv.w);
    *(ushort4*)(ln_t + (size_t)row * 256 + lane * 4) = *(ushort4*)outv;
}

// ---------------------------------------------------------------------------
// MFMA window attention: ONE WAVE per (b,h), no __syncthreads.
// ---------------------------------------------------------------------------
__global__ __launch_bounds__(256) void winattn_kernel(
    const bf16* __restrict__ qkv, const bf16* __restrict__ q_new,
    const float* __restrict__ rel_bias, bf16* __restrict__ attn_out)
{
    const int wv = threadIdx.x >> 6, lane = threadIdx.x & 63;
    const int quad = lane >> 4, l15 = lane & 15;
    const int b = blockIdx.x >> 1;
    const int h = (blockIdx.x & 1) * 4 + wv;

    __shared__ bf16 lds[4 * 6912];           // per wave: P[64*72] + vT[32*72]
    bf16* P  = &lds[wv * 6912];
    bf16* vT = P + 4608;

    {
        int m = lane;
        if (m < 49) {
            const bf16* vp = qkv + ((size_t)(b * 49 + m)) * 768 + 512 + h * 32;
            V16 v0, v1, v2, v3;
            v0.u4 = *(const uint4*)(vp);
            v1.u4 = *(const uint4*)(vp + 8);
            v2.u4 = *(const uint4*)(vp + 16);
            v3.u4 = *(const uint4*)(vp + 24);
            #pragma unroll
            for (int d = 0; d < 8; ++d) {
                ((unsigned short*)vT)[d * 72 + m]        = v0.s[d];
                ((unsigned short*)vT)[(d + 8) * 72 + m]  = v1.s[d];
                ((unsigned short*)vT)[(d + 16) * 72 + m] = v2.s[d];
                ((unsigned short*)vT)[(d + 24) * 72 + m] = v3.s[d];
            }
        } else {
            #pragma unroll
            for (int d = 0; d < 32; ++d)
                ((unsigned short*)vT)[d * 72 + m] = 0;
        }
    }

    s16x8 aq[4], bk[4];
    #pragma unroll
    for (int t = 0; t < 4; ++t) {
        int qr = t * 16 + l15; qr = qr > 48 ? 48 : qr;
        aq[t] = ld16g(q_new + ((size_t)(b * 49 + qr)) * 256 + h * 32 + quad * 8);
        bk[t] = ld16g(qkv + ((size_t)(b * 49 + qr)) * 768 + 256 + h * 32 + quad * 8);
    }
    f32x4 S[4][4];
    #pragma unroll
    for (int tn = 0; tn < 4; ++tn)
        #pragma unroll
        for (int tm = 0; tm < 4; ++tm) {
            #pragma unroll
            for (int r = 0; r < 4; ++r) S[tn][tm][r] = 0.f;
            S[tn][tm] = __builtin_amdgcn_mfma_f32_16x16x32_bf16(aq[tn], bk[tm], S[tn][tm], 0, 0, 0);
        }

    int mvalid[4], mi[4], mj[4];
    #pragma unroll
    for (int tm = 0; tm < 4; ++tm) {
        int m0 = tm * 16 + l15;
        mvalid[tm] = (m0 < 49);
        int mc = m0 > 48 ? 48 : m0;
        mi[tm] = mc / 7; mj[tm] = mc - mi[tm] * 7;
    }
    #pragma unroll
    for (int tn = 0; tn < 4; ++tn) {
        #pragma unroll
        for (int r = 0; r < 4; ++r) {
            int n0 = tn * 16 + quad * 4 + r;
            int nc = n0 > 48 ? 48 : n0;
            int ni = nc / 7, nj = nc - (nc / 7) * 7;
            float vals[4];
            float mx = -1e30f;
            #pragma unroll
            for (int tm = 0; tm < 4; ++tm) {
                float v = S[tn][tm][r]
                        + rel_bias[((ni - mi[tm] + 6) * 13 + (nj - mj[tm] + 6)) * 8 + h];
                if (!mvalid[tm]) v = -1e30f;
                vals[tm] = v;
                mx = fmaxf(mx, v);
            }
            mx = fmaxf(mx, __shfl_xor(mx, 1));
            mx = fmaxf(mx, __shfl_xor(mx, 2));
            mx = fmaxf(mx, __shfl_xor(mx, 4));
            mx = fmaxf(mx, __shfl_xor(mx, 8));
            float s = 0.f;
            #pragma unroll
            for (int tm = 0; tm < 4; ++tm) { vals[tm] = __expf(vals[tm] - mx); s += vals[tm]; }
            s += __shfl_xor(s, 1);
            s += __shfl_xor(s, 2);
            s += __shfl_xor(s, 4);
            s += __shfl_xor(s, 8);
            float inv = 1.f / s;
            #pragma unroll
            for (int tm = 0; tm < 4; ++tm)
                ((unsigned short*)P)[n0 * 72 + tm * 16 + l15] = f2bs(vals[tm] * inv);
        }
    }

    f32x4 O[4][2];
    #pragma unroll
    for (int tn = 0; tn < 4; ++tn)
        #pragma unroll
        for (int td = 0; td < 2; ++td)
            #pragma unroll
            for (int r = 0; r < 4; ++r) O[tn][td][r] = 0.f;

    #pragma unroll
    for (int ks = 0; ks < 2; ++ks) {
        s16x8 bv0 = *(const s16x8*)&vT[(0 * 16 + l15) * 72 + ks * 32 + quad * 8];
        s16x8 bv1 = *(const s16x8*)&vT[(1 * 16 + l15) * 72 + ks * 32 + quad * 8];
        #pragma unroll
        for (int tn = 0; tn < 4; ++tn) {
            s16x8 ap = *(const s16x8*)&P[(tn * 16 + l15) * 72 + ks * 32 + quad * 8];
            O[tn][0] = __builtin_amdgcn_mfma_f32_16x16x32_bf16(ap, bv0, O[tn][0], 0, 0, 0);
            O[tn][1] = __builtin_amdgcn_mfma_f32_16x16x32_bf16(ap, bv1, O[tn][1], 0, 0, 0);
        }
    }

    #pragma unroll
    for (int tn = 0; tn < 4; ++tn)
        #pragma unroll
        for (int r = 0; r < 4; ++r) {
            int n0 = tn * 16 + quad * 4 + r;
            if (n0 < 49) {
                size_t base = ((size_t)(b * 49 + n0)) * 256 + h * 32;
                attn_out[base + l15]      = f2b(O[tn][0][r]);
                attn_out[base + 16 + l15] = f2b(O[tn][1][r]);
            }
        }
}

// ---------------------------------------------------------------------------
// MFMA class-token attention: ONE WAVE per (b,h), no __syncthreads.
// ---------------------------------------------------------------------------
__global__ __launch_bounds__(256) void clsattn_kernel(
    const bf16* __restrict__ tkv,
    const bf16* __restrict__ depth_q, const bf16* __restrict__ seg_q,
    bf16* __restrict__ d_pre, bf16* __restrict__ s_pre)
{
    const int wv = threadIdx.x >> 6, lane = threadIdx.x & 63;
    const int quad = lane >> 4, l15 = lane & 15;
    const int bh = blockIdx.x * 4 + wv;      // < 4096
    const int b = bh >> 3, h = bh & 7;

    __shared__ bf16 lds[4 * 5760];
    unsigned short* QP = (unsigned short*)&lds[wv * 5760];   // 16 x 72
    unsigned short* KV = QP + 1152;                          // 64 x 72 (max use 4608)

    {
        int n = lane;
        V16 dv, sv;
        if (n < 49) {
            dv.u4 = *(const uint4*)(depth_q + ((size_t)(b * 49 + n)) * 64 + h * 8);
            sv.u4 = *(const uint4*)(seg_q   + ((size_t)(b * 49 + n)) * 64 + h * 8);
        } else {
            dv.u4 = make_uint4(0, 0, 0, 0); sv.u4 = make_uint4(0, 0, 0, 0);
        }
        #pragma unroll
        for (int c = 0; c < 8; ++c) {
            QP[c * 72 + n]       = dv.s[c];
            QP[(8 + c) * 72 + n] = sv.s[c];
        }
    }
    {
        int n = lane;
        V16 k[6];
        if (n < 49) {
            const bf16* kp = tkv + ((size_t)(b * 49 + n)) * 768 + h * 48;
            #pragma unroll
            for (int c6 = 0; c6 < 6; ++c6) k[c6].u4 = *(const uint4*)(kp + c6 * 8);
        } else {
            #pragma unroll
            for (int c6 = 0; c6 < 6; ++c6) k[c6].u4 = make_uint4(0, 0, 0, 0);
        }
        #pragma unroll
        for (int c6 = 0; c6 < 6; ++c6)
            #pragma unroll
            for (int j = 0; j < 8; ++j)
                KV[(c6 * 8 + j) * 72 + n] = k[c6].s[j];
    }

    f32x4 S[3];
    #pragma unroll
    for (int t3 = 0; t3 < 3; ++t3)
        #pragma unroll
        for (int r = 0; r < 4; ++r) S[t3][r] = 0.f;
    #pragma unroll
    for (int ks = 0; ks < 2; ++ks) {
        s16x8 a = *(const s16x8*)&QP[l15 * 72 + ks * 32 + quad * 8];
        #pragma unroll
        for (int t3 = 0; t3 < 3; ++t3) {
            s16x8 bf = *(const s16x8*)&KV[(t3 * 16 + l15) * 72 + ks * 32 + quad * 8];
            S[t3] = __builtin_amdgcn_mfma_f32_16x16x32_bf16(a, bf, S[t3], 0, 0, 0);
        }
    }

    #pragma unroll
    for (int r = 0; r < 4; ++r) {
        float v0 = S[0][r], v1 = S[1][r], v2 = S[2][r];
        float mx = fmaxf(fmaxf(v0, v1), v2);
        mx = fmaxf(mx, __shfl_xor(mx, 1));
        mx = fmaxf(mx, __shfl_xor(mx, 2));
        mx = fmaxf(mx, __shfl_xor(mx, 4));
        mx = fmaxf(mx, __shfl_xor(mx, 8));
        float e0 = __expf(v0 - mx), e1 = __expf(v1 - mx), e2 = __expf(v2 - mx);
        float s = e0 + e1 + e2;
        s += __shfl_xor(s, 1);
        s += __shfl_xor(s, 2);
        s += __shfl_xor(s, 4);
        s += __shfl_xor(s, 8);
        float inv = 1.f / s;
        int c = quad * 4 + r;
        QP[c * 72 + 0 * 16 + l15] = f2bs(e0 * inv);
        QP[c * 72 + 1 * 16 + l15] = f2bs(e1 * inv);
        QP[c * 72 + 2 * 16 + l15] = f2bs(e2 * inv);
    }
    #pragma unroll
    for (int z = 0; z < 4; ++z)
        QP[(lane & 15) * 72 + 48 + (lane >> 4) * 4 + z] = 0;

    {
        int n = lane;
        V16 v[6], zv; zv.u4 = make_uint4(0, 0, 0, 0);
        if (n < 49) {
            const bf16* vp = tkv + ((size_t)(b * 49 + n)) * 768 + 384 + h * 48;
            #pragma unroll
            for (int c6 = 0; c6 < 6; ++c6) v[c6].u4 = *(const uint4*)(vp + c6 * 8);
        } else {
            #pragma unroll
            for (int c6 = 0; c6 < 6; ++c6) v[c6].u4 = zv.u4;
        }
        #pragma unroll
        for (int c6 = 0; c6 < 6; ++c6)
            *(uint4*)&KV[n * 72 + c6 * 8] = v[c6].u4;
        *(uint4*)&KV[n * 72 + 48] = zv.u4;
        *(uint4*)&KV[n * 72 + 56] = zv.u4;
    }

    f32x4 O[4];
    #pragma unroll
    for (int t4 = 0; t4 < 4; ++t4)
        #pragma unroll
        for (int r = 0; r < 4; ++r) O[t4][r] = 0.f;
    #pragma unroll
    for (int ks = 0; ks < 2; ++ks) {
        s16x8 a = *(const s16x8*)&QP[l15 * 72 + ks * 32 + quad * 8];
        #pragma unroll
        for (int t4 = 0; t4 < 4; ++t4) {
            s16x8 bf = *(const s16x8*)&KV[(t4 * 16 + l15) * 72 + ks * 32 + quad * 8];
            O[t4] = __builtin_amdgcn_mfma_f32_16x16x32_bf16(a, bf, O[t4], 0, 0, 0);
        }
    }

    #pragma unroll
    for (int t4 = 0; t4 < 4; ++t4) {
        int n = t4 * 16 + l15;
        if (n < 49) {
            size_t base = ((size_t)(b * 49 + n)) * 64 + h * 8;
            #pragma unroll
            for (int r = 0; r < 4; ++r) {
                int c = quad * 4 + r;
                if (c < 8) d_pre[base + c] = f2b(O[t4][r]);
                else       s_pre[base + c - 8] = f2b(O[t4][r]);
            }
        }
    }
}

// ---------------------------------------------------------------------------
extern "C" void kernel_launch(void* const* d_in, const int* in_sizes, int n_in,
                              void* d_out, int out_size, void* d_ws, size_t ws_size,
                              hipStream_t stream)
{
    const float* x          = (const float*)d_in[0];
    const float* x_ref      = (const float*)d_in[1];
    const float* dth_tok    = (const float*)d_in[2];
    const float* seg_tok    = (const float*)d_in[3];
    const float* qkv_w      = (const float*)d_in[4];
    const float* qkv_b      = (const float*)d_in[5];
    const float* proj_w     = (const float*)d_in[6];
    const float* proj_b     = (const float*)d_in[7];
    const float* rel_bias   = (const float*)d_in[8];
    const float* diff_mu    = (const float*)d_in[9];
    const float* diff_ls    = (const float*)d_in[10];
    const float* ref_qk_w   = (const float*)d_in[11];
    const float* ref_qk_b   = (const float*)d_in[12];
    const float* conv_w     = (const float*)d_in[13];
    const float* conv_b     = (const float*)d_in[14];
    const float* q_norm_w   = (const float*)d_in[15];
    const float* q_norm_b   = (const float*)d_in[16];
    const float* q_proj_w   = (const float*)d_in[17];
    const float* q_proj_b   = (const float*)d_in[18];
    const float* cls_dth_w  = (const float*)d_in[19];
    const float* cls_dth_b  = (const float*)d_in[20];
    const float* cls_seg_w  = (const float*)d_in[21];
    const float* cls_seg_b  = (const float*)d_in[22];
    const float* glob_k_w   = (const float*)d_in[23];
    const float* glob_k_b   = (const float*)d_in[24];
    const float* glob_v_w   = (const float*)d_in[25];
    const float* glob_v_b   = (const float*)d_in[26];
    const float* proj_dth_w = (const float*)d_in[27];
    const float* proj_dth_b = (const float*)d_in[28];

    // ---- workspace layout ----
    bf16* wsb = (bf16*)d_ws;
    bf16* qkv      = wsb;                      // [25088,768]; later tkv [25088,768]
    bf16* tkv      = wsb;
    bf16* ref_attn = wsb + 19267584;           // R1
    bf16* q_new    = ref_attn;
    bf16* out0b    = ref_attn;
    bf16* depth_q  = ref_attn;
    bf16* seg_q    = ref_attn + 1605632;
    bf16* d_pre    = ref_attn + 3211264;
    bf16* s_pre    = ref_attn + 4816896;
    bf16* u_buf    = wsb + 25690112;           // R3
    bf16* xb       = u_buf;
    bf16* ln_t     = u_buf;
    bf16* attn_out = u_buf;
    float* ref_qk  = (float*)((char*)d_ws + 64225280);
    bf16*  rq_b    = (bf16*)(ref_qk + 131072);     // [64,32,32] bf16 (scaled)
    float* ref_v_t = ref_qk + 131072 + 65536;      // [64,32,32] f32
    float* stats4  = ref_qk;                       // 512 f32, reuses dead ref_qk

    float* out0  = (float*)d_out;
    float* out_d = out0 + 6422528;
    float* out_s = out0 + 8028160;

    // scratch in output regions (dead until final small64)
    bf16* Wt_all = (bf16*)out_d;               // 622592 elems = 1.19 MiB
    bf16* tokb   = (bf16*)out_s;               // [25088,128] bf16 = 6.125 MiB

    // 0. all input prep in one launch
    prep_all<<<10272, 256, 0, stream>>>(qkv_w, q_proj_w, proj_w, glob_k_w, glob_v_w,
                                        Wt_all, x, xb, dth_tok, seg_tok, tokb);

    // 1. qkv = x @ qkv_w + b
    gemm_pipe<0><<<dim3(6, 196), 256, 0, stream>>>(xb, 256, nullptr,
        Wt_all, qkv_b, nullptr, nullptr, 0, nullptr, qkv, 768, 256, 768, 1.f);
    // 2. ref_qk = x_ref @ ref_qk_w + b (small)
    mfma_gemm<<<dim3(8, 4), 256, 0, stream>>>(x_ref, 0, ref_qk_w, ref_qk_b,
                                              ref_qk, nullptr, 256, 256, 512, 1.f);
    // 3. rq_b (bf16, scaled) / ref_v_t
    refprep_kernel<<<256, 256, 0, stream>>>(ref_qk, diff_mu, diff_ls, rq_b, ref_v_t);
    // 4. ref_attn scores (MFMA, 1 wave per (rh,w))
    refattn_kernel<<<1024, 256, 0, stream>>>(qkv, rq_b, ref_attn);
    // 5. 3x diffusion
    for (int it = 0; it < 3; ++it) {
        conv_kernel<<<392, 256, 0, stream>>>(ref_attn, conv_w, conv_b, u_buf);
        lnstats_kernel<<<256, 256, 0, stream>>>(u_buf, stats4);
        lngelu_kernel<<<3136, 256, 0, stream>>>(u_buf, stats4, ref_attn);
    }
    // 6. softmax @ ref_v + shortcut + LN -> ln_t
    qnew_pre_kernel<<<6272, 256, 0, stream>>>(qkv, ref_attn, ref_v_t,
                                              q_norm_w, q_norm_b, ln_t);
    // 7. q_new = (ln_t @ q_proj_w + b + qsc) * SCALE
    gemm_pipe<0><<<dim3(2, 196), 256, 0, stream>>>(ln_t, 256, nullptr,
        Wt_all + 196608, q_proj_b, nullptr, qkv, 768, nullptr, q_new, 256, 256, 256, SCALE_T);
    // 8. window attention
    winattn_kernel<<<1024, 256, 0, stream>>>(qkv, q_new, rel_bias, attn_out);
    // 9. out0 = attn_out @ proj_w + b   (f32 to d_out, bf16 copy to out0b)
    gemm_pipe<0><<<dim3(2, 196), 256, 0, stream>>>(attn_out, 256, nullptr,
        Wt_all + 262144, proj_b, nullptr, nullptr, 0, out0, out0b, 256, 256, 256, 1.f);
    // 10. fused t_k|t_v = concat(out0b, tokb) @ [gk|gv] + b -> tkv [25088,768]
    gemm_pipe<1><<<dim3(6, 196), 256, 0, stream>>>(out0b, 256, tokb,
        Wt_all + 327680, glob_k_b, glob_v_b, nullptr, 0, nullptr, tkv, 768, 384, 768, 1.f);
    // 12/13. depth_q, seg_q in ONE launch
    small64<1, 0><<<dim3(392, 2), 256, 0, stream>>>(dth_tok, seg_tok,
        cls_dth_w, cls_seg_w, cls_dth_b, cls_seg_b, depth_q, seg_q, SCALE_T);
    // 14. class-token attention
    clsattn_kernel<<<1024, 256, 0, stream>>>(tkv, depth_q, seg_q, d_pre, s_pre);
    // 15/16. final proj_dth in ONE launch (f32 out; overwrites Wt/tokb scratch)
    small64<0, 1><<<dim3(392, 2), 256, 0, stream>>>(d_pre, s_pre,
        proj_dth_w, proj_dth_w, proj_dth_b, proj_dth_b, out_d, out_s, 1.f);
}

// Round 7
// 464.235 us; speedup vs baseline: 1.1140x; 1.0278x over previous
//
#include <hip/hip_runtime.h>
#include <hip/hip_bf16.h>

typedef __hip_bfloat16 bf16;
typedef short s16x8 __attribute__((ext_vector_type(8)));
typedef float f32x4 __attribute__((ext_vector_type(4)));
union V16 { uint4 u4; s16x8 s8; unsigned u[4]; unsigned short s[8]; };

static __device__ __forceinline__ float b2f(bf16 v){ return __bfloat162float(v); }
static __device__ __forceinline__ bf16  f2b(float v){ return __float2bfloat16(v); }
static __device__ __forceinline__ unsigned short f2bs(float x){
    union { float f; unsigned u; } c; c.f = x;
    unsigned r = c.u + 0x7fff + ((c.u >> 16) & 1);
    return (unsigned short)(r >> 16);
}
static __device__ __forceinline__ float bu2f(unsigned short b){
    union { unsigned u; float f; } c; c.u = ((unsigned)b) << 16; return c.f;
}
static __device__ __forceinline__ s16x8 ld16g(const bf16* p){
    V16 u; u.u4 = *(const uint4*)p; return u.s8;
}
static __device__ __forceinline__ void glds16(const void* g, void* l){
    __builtin_amdgcn_global_load_lds(
        (const __attribute__((address_space(1))) unsigned*)g,
        (__attribute__((address_space(3))) unsigned*)l, 16, 0, 0);
}

#define SCALE_T 0.17677669529663687f   // 32^-0.5

// ---------------------------------------------------------------------------
// prep_all: one launch for all input prep.
//  blocks [0,2432):    weight transpose+convert -> Wt (622592 elems)
//  blocks [2432,8704): x f32 -> xb bf16 (1605632 x 4 elems)
//  blocks [8704,10272): tokens -> tokb[row][128] bf16 (401408 x 8 elems)
// ---------------------------------------------------------------------------
__global__ __launch_bounds__(256) void prep_all(
    const float* __restrict__ qkvw, const float* __restrict__ qpw,
    const float* __restrict__ pw,   const float* __restrict__ gkw,
    const float* __restrict__ gvw,  bf16* __restrict__ Wt,
    const float* __restrict__ x,    bf16* __restrict__ xb,
    const float* __restrict__ dth,  const float* __restrict__ seg,
    bf16* __restrict__ tokb)
{
    int blk = blockIdx.x, tid = threadIdx.x;
    if (blk < 2432) {
        int idx = blk * 256 + tid;   // < 622592
        float v;
        if (idx < 196608)      { int j = idx;          int n = j >> 8, k = j & 255; v = qkvw[k * 768 + n]; }
        else if (idx < 262144) { int j = idx - 196608; int n = j >> 8, k = j & 255; v = qpw[k * 256 + n]; }
        else if (idx < 327680) { int j = idx - 262144; int n = j >> 8, k = j & 255; v = pw[k * 256 + n]; }
        else if (idx < 475136) { int j = idx - 327680; int n = j / 384, k = j - n * 384; v = gkw[k * 384 + n]; }
        else                   { int j = idx - 475136; int n = j / 384, k = j - n * 384; v = gvw[k * 384 + n]; }
        ((unsigned short*)Wt)[idx] = f2bs(v);
    } else if (blk < 8704) {
        int i = (blk - 2432) * 256 + tid;   // < 1605632
        float4 v = ((const float4*)x)[i];
        ushort4 o;
        o.x = f2bs(v.x); o.y = f2bs(v.y); o.z = f2bs(v.z); o.w = f2bs(v.w);
        ((ushort4*)xb)[i] = o;
    } else {
        int i = (blk - 8704) * 256 + tid;   // < 401408
        int row = i >> 4, j8 = i & 15;
        const float* src = (j8 < 8) ? (dth + (size_t)row * 64 + j8 * 8)
                                    : (seg + (size_t)row * 64 + (j8 - 8) * 8);
        float4 u0 = ((const float4*)src)[0];
        float4 u1 = ((const float4*)src)[1];
        V16 o;
        o.s[0] = f2bs(u0.x); o.s[1] = f2bs(u0.y);
        o.s[2] = f2bs(u0.z); o.s[3] = f2bs(u0.w);
        o.s[4] = f2bs(u1.x); o.s[5] = f2bs(u1.y);
        o.s[6] = f2bs(u1.z); o.s[7] = f2bs(u1.w);
        *(uint4*)(tokb + (size_t)row * 128 + j8 * 8) = o.u4;
    }
}

// ---------------------------------------------------------------------------
// gemm_pipe: out = (A[M,K]bf16 @ Wt[N,K]^T + bias [+ add]) * scale
// 128x128 tile, BK=32, 4 waves (2x2). 3-deep LDS ring (48KB -> 3 blocks/CU),
// counted-vmcnt pipeline: prologue stages 0,1; per iter: vmcnt(4) (oldest
// stage landed, newest in flight), s_barrier, issue stage i+2, compute buf.
// Hazards: stage(i+2) targets buf (i-1)%3, whose ds_reads completed chip-wide
// before barrier i; post-loop __syncthreads orders last-compute vs epilogue
// scratch. TOK: K-tiles >= 256 come from A2 (bf16, lda 128).
// ---------------------------------------------------------------------------
template<int TOK>
__global__ __launch_bounds__(256, 3) void gemm_pipe(
    const bf16* __restrict__ A, int lda, const bf16* __restrict__ A2,
    const bf16* __restrict__ Wt, const float* __restrict__ bias,
    const float* __restrict__ bias2,
    const bf16* __restrict__ addp, int addStride,
    float* __restrict__ outF, bf16* __restrict__ outB, int outStrideB,
    int K, int N, float scale)
{
    __shared__ char lds[3][16384];            // ring: per buf A 8KB | B 8KB

    const int tid = threadIdx.x;
    const int wv = tid >> 6, lane = tid & 63;
    const int quad = lane >> 4, l15 = lane & 15;
    const int wr = wv >> 1, wc = wv & 1;

    const int gx = (int)gridDim.x;
    const int nwg = gx * (int)gridDim.y;
    int bid = (int)blockIdx.y * gx + (int)blockIdx.x;
    if ((nwg & 7) == 0) bid = (bid & 7) * (nwg >> 3) + (bid >> 3);
    const int bx = bid % gx, by = bid / gx;
    const int rowBase = by * 128, colBase = bx * 128;

    // staging: row srow = tid>>2, slot s = tid&3 holds k-quad (s ^ ((srow>>1)&3))
    const int srow = tid >> 2;
    const int kOffE = (((tid & 3) ^ ((srow >> 1) & 3)) << 3);   // elems

    // read: quad q of row l15 lives at slot (q ^ ((l15>>1)&3))
    const unsigned swz = (unsigned)((quad ^ ((l15 >> 1) & 3)) << 4);
    const unsigned aoff0 = (unsigned)(wr * 4096 + l15 * 64) + swz;
    const unsigned boff0 = (unsigned)(wc * 4096 + l15 * 64) + swz;

    f32x4 acc[4][4];
    #pragma unroll
    for (int m = 0; m < 4; ++m)
        #pragma unroll
        for (int n = 0; n < 4; ++n)
            #pragma unroll
            for (int r = 0; r < 4; ++r) acc[m][n][r] = 0.f;

    const int nsteps = K >> 5;

    auto stageN = [&](int i) {                // stage K-step i into buf i%3
        int kt = i << 5;
        char* base = &lds[i % 3][0];
        #pragma unroll
        for (int c = 0; c < 2; ++c)
            glds16(Wt + (size_t)(colBase + c * 64 + srow) * K + (kt + kOffE),
                   base + 8192 + c * 4096 + tid * 16);
        if (!TOK || kt < 256) {
            #pragma unroll
            for (int c = 0; c < 2; ++c)
                glds16(A + (size_t)(rowBase + c * 64 + srow) * lda + (kt + kOffE),
                       base + c * 4096 + tid * 16);
        } else {
            #pragma unroll
            for (int c = 0; c < 2; ++c)
                glds16(A2 + (size_t)(rowBase + c * 64 + srow) * 128 + (kt - 256 + kOffE),
                       base + c * 4096 + tid * 16);
        }
    };

    stageN(0);
    if (nsteps > 1) stageN(1);

    int bufi = 0;
    for (int i = 0; i < nsteps; ++i) {
        // wait only for stage i (leave stage i+1 in flight)
        if (i + 1 < nsteps) asm volatile("s_waitcnt vmcnt(4)" ::: "memory");
        else                asm volatile("s_waitcnt vmcnt(0)" ::: "memory");
        __builtin_amdgcn_sched_barrier(0);
        __builtin_amdgcn_s_barrier();        // all waves: stage i landed in LDS
        __builtin_amdgcn_sched_barrier(0);

        if (i + 2 < nsteps) stageN(i + 2);   // targets buf (i-1)%3: readers done

        const char* Ab2 = &lds[bufi][0];
        const char* Bb2 = Ab2 + 8192;
        s16x8 af[4], bfr[4];
        #pragma unroll
        for (int m = 0; m < 4; ++m) af[m]  = *(const s16x8*)(Ab2 + aoff0 + m * 1024);
        #pragma unroll
        for (int n = 0; n < 4; ++n) bfr[n] = *(const s16x8*)(Bb2 + boff0 + n * 1024);
        #pragma unroll
        for (int m = 0; m < 4; ++m)
            #pragma unroll
            for (int n = 0; n < 4; ++n)
                acc[m][n] = __builtin_amdgcn_mfma_f32_16x16x32_bf16(af[m], bfr[n], acc[m][n], 0, 0, 0);
        bufi = (bufi == 2) ? 0 : bufi + 1;
    }
    __syncthreads();   // all waves done reading ring before epilogue scratch

    // ---- epilogue ----
    if (outB) {
        #pragma unroll
        for (int n = 0; n < 4; ++n) {
            int col = colBase + wc * 64 + n * 16 + l15;
            float bb = bias2 ? (col < 384 ? bias[col] : bias2[col - 384]) : bias[col];
            #pragma unroll
            for (int m = 0; m < 4; ++m) {
                #pragma unroll
                for (int r = 0; r < 4; ++r) {
                    int rl = wr * 64 + m * 16 + quad * 4 + r;
                    float v = acc[m][n][r] + bb;
                    if (addp) v += b2f(addp[(size_t)(rowBase + rl) * addStride + col]);
                    v *= scale;
                    if (outF) outF[(size_t)(rowBase + rl) * N + col] = v;
                    int cbyte = (wc * 64 + n * 16 + l15) * 2;
                    int blk = ((cbyte >> 5) ^ ((rl >> 2) & 7)) & 7;
                    *(unsigned short*)((char*)lds + rl * 256 + (blk << 5) + (cbyte & 31)) = f2bs(v);
                }
            }
        }
        __syncthreads();
        #pragma unroll
        for (int i = 0; i < 8; ++i) {
            int lin = i * 256 + tid;
            int rl = lin >> 4, cb = lin & 15;
            int cb2 = ((((cb >> 1) ^ ((rl >> 2) & 7)) & 7) << 1) | (cb & 1);
            uint4 val = *(const uint4*)((const char*)lds + rl * 256 + cb2 * 16);
            *(uint4*)(outB + (size_t)(rowBase + rl) * outStrideB + colBase + cb * 8) = val;
        }
    } else {
        #pragma unroll
        for (int n = 0; n < 4; ++n) {
            int col = colBase + wc * 64 + n * 16 + l15;
            float bb = bias2 ? (col < 384 ? bias[col] : bias2[col - 384]) : bias[col];
            #pragma unroll
            for (int m = 0; m < 4; ++m) {
                #pragma unroll
                for (int r = 0; r < 4; ++r) {
                    int rl = wr * 64 + m * 16 + quad * 4 + r;
                    float v = acc[m][n][r] + bb;
                    if (addp) v += b2f(addp[(size_t)(rowBase + rl) * addStride + col]);
                    v *= scale;
                    if (outF) outF[(size_t)(rowBase + rl) * N + col] = v;
                }
            }
        }
    }
}

// ---------------------------------------------------------------------------
// small64: out[M,64] = (A[M,64] @ W[64,64] + bias) * scale, two tasks via
// blockIdx.y.
// ---------------------------------------------------------------------------
template<int AF32, int OF32>
__global__ __launch_bounds__(256) void small64(
    const void* __restrict__ a0, const void* __restrict__ a1,
    const float* __restrict__ w0, const float* __restrict__ w1,
    const float* __restrict__ b0, const float* __restrict__ b1,
    void* __restrict__ o0, void* __restrict__ o1, float scale)
{
    __shared__ unsigned short WT[64 * 72];
    __shared__ float bsh[64];
    const int task = blockIdx.y;
    const void*  A    = task ? a1 : a0;
    const float* W    = task ? w1 : w0;
    const float* bias = task ? b1 : b0;
    void*        outp = task ? o1 : o0;

    int tid = threadIdx.x;
    for (int l = tid; l < 4096; l += 256) {
        int k = l >> 6, n = l & 63;
        WT[n * 72 + k] = f2bs(W[l]);
    }
    if (tid < 64) bsh[tid] = bias[tid];
    __syncthreads();

    const int wv = tid >> 6, lane = tid & 63;
    const int quad = lane >> 4, l15 = lane & 15;
    const int rowBase = blockIdx.x * 64;
    const int arow = rowBase + wv * 16 + l15;

    s16x8 a[2];
    if (AF32) {
        const float* Ar = (const float*)A + (size_t)arow * 64;
        #pragma unroll
        for (int ks = 0; ks < 2; ++ks) {
            float4 u0 = *(const float4*)(Ar + ks * 32 + quad * 8);
            float4 u1 = *(const float4*)(Ar + ks * 32 + quad * 8 + 4);
            V16 o;
            o.s[0] = f2bs(u0.x); o.s[1] = f2bs(u0.y);
            o.s[2] = f2bs(u0.z); o.s[3] = f2bs(u0.w);
            o.s[4] = f2bs(u1.x); o.s[5] = f2bs(u1.y);
            o.s[6] = f2bs(u1.z); o.s[7] = f2bs(u1.w);
            a[ks] = o.s8;
        }
    } else {
        const bf16* Ar = (const bf16*)A + (size_t)arow * 64;
        #pragma unroll
        for (int ks = 0; ks < 2; ++ks)
            a[ks] = ld16g(Ar + ks * 32 + quad * 8);
    }

    f32x4 acc[4];
    #pragma unroll
    for (int n = 0; n < 4; ++n)
        #pragma unroll
        for (int r = 0; r < 4; ++r) acc[n][r] = 0.f;

    #pragma unroll
    for (int ks = 0; ks < 2; ++ks)
        #pragma unroll
        for (int n = 0; n < 4; ++n) {
            s16x8 b = *(const s16x8*)&WT[(n * 16 + l15) * 72 + ks * 32 + quad * 8];
            acc[n] = __builtin_amdgcn_mfma_f32_16x16x32_bf16(a[ks], b, acc[n], 0, 0, 0);
        }

    #pragma unroll
    for (int n = 0; n < 4; ++n) {
        int col = n * 16 + l15;
        float bb = bsh[col];
        #pragma unroll
        for (int r = 0; r < 4; ++r) {
            int row = rowBase + wv * 16 + quad * 4 + r;
            float v = (acc[n][r] + bb) * scale;
            if (OF32) ((float*)outp)[(size_t)row * 64 + col] = v;
            else      ((bf16*)outp)[(size_t)row * 64 + col] = f2b(v);
        }
    }
}

// ---------------------------------------------------------------------------
// Small MFMA GEMM (kept for step 2's tiny 256x512 shape).
// ---------------------------------------------------------------------------
__global__ __launch_bounds__(256) void mfma_gemm(
    const void* __restrict__ A, int a_mode,
    const float* __restrict__ W, const float* __restrict__ bias,
    float* __restrict__ outF, bf16* __restrict__ outB,
    int M, int K, int N, float scale)
{
    __shared__ __hip_bfloat16 Al[64][48];
    __shared__ __hip_bfloat16 Bl[64][48];

    const int tid  = threadIdx.x;
    const int wv   = tid >> 6, lane = tid & 63;
    const int quad = lane >> 4, l15 = lane & 15;
    const int rowBase = blockIdx.y * 64, colBase = blockIdx.x * 64;

    const int am = tid >> 2, ak = (tid & 3) * 8;
    const int bn = tid & 63, bk = (tid >> 6) * 8;

    f32x4 acc[4];
    #pragma unroll
    for (int t = 0; t < 4; ++t)
        #pragma unroll
        for (int r = 0; r < 4; ++r) acc[t][r] = 0.f;

    for (int kt = 0; kt < K; kt += 32) {
        s16x8 sa;
        if (a_mode == 1) {
            const bf16* Ab = (const bf16*)A;
            V16 u; u.u4 = *(const uint4*)(Ab + (size_t)(rowBase + am) * K + kt + ak);
            sa = u.s8;
        } else {
            const float* src = (const float*)A;
            const float4* p = (const float4*)(src + (size_t)(rowBase + am) * K + kt + ak);
            float4 u0 = p[0], u1 = p[1];
            sa[0] = (short)f2bs(u0.x); sa[1] = (short)f2bs(u0.y);
            sa[2] = (short)f2bs(u0.z); sa[3] = (short)f2bs(u0.w);
            sa[4] = (short)f2bs(u1.x); sa[5] = (short)f2bs(u1.y);
            sa[6] = (short)f2bs(u1.z); sa[7] = (short)f2bs(u1.w);
        }
        *(s16x8*)&Al[am][ak] = sa;

        s16x8 sb;
        #pragma unroll
        for (int j = 0; j < 8; ++j)
            sb[j] = (short)f2bs(W[(size_t)(kt + bk + j) * N + colBase + bn]);
        *(s16x8*)&Bl[bn][bk] = sb;

        __syncthreads();

        s16x8 a = *(const s16x8*)&Al[wv * 16 + l15][quad * 8];
        #pragma unroll
        for (int t = 0; t < 4; ++t) {
            s16x8 b = *(const s16x8*)&Bl[t * 16 + l15][quad * 8];
            acc[t] = __builtin_amdgcn_mfma_f32_16x16x32_bf16(a, b, acc[t], 0, 0, 0);
        }
        __syncthreads();
    }

    #pragma unroll
    for (int t = 0; t < 4; ++t) {
        int col = colBase + t * 16 + l15;
        float bb = bias[col];
        #pragma unroll
        for (int r = 0; r < 4; ++r) {
            int row = rowBase + wv * 16 + quad * 4 + r;
            float v = (acc[t][r] + bb) * scale;
            if (outF) outF[(size_t)row * N + col] = v;
            if (outB) outB[(size_t)row * N + col] = f2b(v);
        }
    }
}

// ---------------------------------------------------------------------------
// refprep: rq_b[r,h,f,d] = bf16( (mu[c] + exp(ls[c])*ref_qk[..]) * SCALE_T )
//          ref_v_t f32 from +256.  SCALE_T folded into rq (scores = q.(S*rq)).
// ---------------------------------------------------------------------------
__global__ __launch_bounds__(256) void refprep_kernel(
    const float* __restrict__ ref_qk, const float* __restrict__ mu,
    const float* __restrict__ ls, bf16* __restrict__ rq_b,
    float* __restrict__ ref_v_t)
{
    int idx = blockIdx.x * 256 + threadIdx.x;          // [r,h,f,d]
    int d = idx & 31, h = (idx >> 10) & 7;
    int c = h * 32 + d;
    int f = (idx >> 5) & 31, r = idx >> 13;
    size_t src = (size_t)(r * 32 + f) * 512 + c;
    ((unsigned short*)rq_b)[idx] = f2bs((mu[c] + __expf(ls[c]) * ref_qk[src]) * SCALE_T);
    ref_v_t[idx] = ref_qk[src + 256];
}

// ---------------------------------------------------------------------------
// refattn (MFMA): ref_attn[rh,w,n,f] = sum_d q[b,h,n,d] * rq_b[rh,f,d]
// One wave per (rh,w): 8 MFMA, no LDS, no barriers. grid = 1024 x 256.
// ---------------------------------------------------------------------------
__global__ __launch_bounds__(256) void refattn_kernel(
    const bf16* __restrict__ qkv, const bf16* __restrict__ rq_b,
    bf16* __restrict__ ref_attn)
{
    const int wv = threadIdx.x >> 6, lane = threadIdx.x & 63;
    const int quad = lane >> 4, l15 = lane & 15;
    int blk = blockIdx.x;                 // < 1024
    int rh = blk >> 4;                    // r*8+h
    int h = rh & 7;
    int w = (blk & 15) * 4 + wv;
    int b = (rh >> 3) * 64 + w;

    s16x8 bk0 = ld16g(rq_b + ((size_t)(rh * 32 + l15)) * 32 + quad * 8);
    s16x8 bk1 = ld16g(rq_b + ((size_t)(rh * 32 + 16 + l15)) * 32 + quad * 8);

    s16x8 aq[4];
    #pragma unroll
    for (int t = 0; t < 4; ++t) {
        int qr = t * 16 + l15; qr = qr > 48 ? 48 : qr;
        aq[t] = ld16g(qkv + ((size_t)(b * 49 + qr)) * 768 + h * 32 + quad * 8);
    }

    #pragma unroll
    for (int t = 0; t < 4; ++t) {
        f32x4 S0, S1;
        #pragma unroll
        for (int r = 0; r < 4; ++r) { S0[r] = 0.f; S1[r] = 0.f; }
        S0 = __builtin_amdgcn_mfma_f32_16x16x32_bf16(aq[t], bk0, S0, 0, 0, 0);
        S1 = __builtin_amdgcn_mfma_f32_16x16x32_bf16(aq[t], bk1, S1, 0, 0, 0);
        #pragma unroll
        for (int r = 0; r < 4; ++r) {
            int n0 = t * 16 + quad * 4 + r;
            if (n0 < 49) {
                size_t base = ((size_t)(rh * 64 + w) * 49 + n0) * 32;
                ref_attn[base + l15]      = f2b(S0[r]);
                ref_attn[base + 16 + l15] = f2b(S1[r]);
            }
        }
    }
}

// ---------------------------------------------------------------------------
// 3x3 SAME conv over [RB=8, 8ch, 3136, 32].
// ---------------------------------------------------------------------------
__global__ __launch_bounds__(256) void conv_kernel(
    const bf16* __restrict__ in, const float* __restrict__ conv_w,
    const float* __restrict__ conv_b, bf16* __restrict__ u)
{
    __shared__ float w_s[576];
    __shared__ float b_s[8];
    int tid = threadIdx.x;
    for (int l = tid; l < 576; l += 256) w_s[l] = conv_w[l];
    if (tid < 8) b_s[tid] = conv_b[tid];
    __syncthreads();

    int idx = blockIdx.x * 256 + tid;          // < 100352
    int fb = idx & 3;
    int p  = (idx >> 2) % 3136;
    int r  = idx / 12544;
    int f0 = fb * 8;

    float acc[8][8];
    #pragma unroll
    for (int o = 0; o < 8; ++o) {
        float bo = b_s[o];
        #pragma unroll
        for (int f = 0; f < 8; ++f) acc[o][f] = bo;
    }

    for (int i = 0; i < 8; ++i) {
        float ext[3][10];
        #pragma unroll
        for (int dy = 0; dy < 3; ++dy) {
            int pp = p + dy - 1;
            bool pv = (unsigned)pp < 3136u;
            size_t base = ((size_t)((r * 8 + i) * 3136 + (pv ? pp : 0))) * 32 + f0;
            V16 uv;
            uv.u4 = pv ? *(const uint4*)(in + base) : make_uint4(0, 0, 0, 0);
            #pragma unroll
            for (int j = 0; j < 8; ++j) {
                unsigned sh = uv.u[j >> 1];
                unsigned bits = (j & 1) ? (sh & 0xffff0000u) : (sh << 16);
                union { unsigned uu; float fl; } cv; cv.uu = bits;
                ext[dy][j + 1] = cv.fl;
            }
            ext[dy][0] = (pv && f0 > 0)      ? b2f(in[base - 1]) : 0.f;
            ext[dy][9] = (pv && f0 + 8 < 32) ? b2f(in[base + 8]) : 0.f;
        }
        #pragma unroll
        for (int o = 0; o < 8; ++o) {
            #pragma unroll
            for (int ky = 0; ky < 3; ++ky) {
                const float* wp = &w_s[((o * 8 + i) * 3 + ky) * 3];
                float w0 = wp[0], w1 = wp[1], w2 = wp[2];
                #pragma unroll
                for (int f = 0; f < 8; ++f)
                    acc[o][f] += ext[ky][f] * w0 + ext[ky][f + 1] * w1 + ext[ky][f + 2] * w2;
            }
        }
    }

    #pragma unroll
    for (int o = 0; o < 8; ++o) {
        bf16 ov[8];
        #pragma unroll
        for (int f = 0; f < 8; ++f) ov[f] = f2b(acc[o][f]);
        *(uint4*)(u + ((size_t)((r * 8 + o) * 3136 + p)) * 32 + f0) = *(uint4*)ov;
    }
}

// ---------------------------------------------------------------------------
// Partial sums per (group, quarter): 256 blocks, each reduces 25088 elems.
// ---------------------------------------------------------------------------
__global__ __launch_bounds__(256) void lnstats_kernel(
    const bf16* __restrict__ u, float* __restrict__ stats4)
{
    int g4 = blockIdx.x;
    const bf16* p = u + (size_t)g4 * 25088;
    int tid = threadIdx.x;
    float s = 0.f, s2 = 0.f;
    for (int it = tid; it < 3136; it += 256) {
        V16 uv; uv.u4 = *(const uint4*)(p + it * 8);
        #pragma unroll
        for (int j = 0; j < 8; ++j) {
            unsigned sh = uv.u[j >> 1];
            unsigned bits = (j & 1) ? (sh & 0xffff0000u) : (sh << 16);
            union { unsigned uu; float fl; } cv; cv.uu = bits;
            s += cv.fl; s2 += cv.fl * cv.fl;
        }
    }
    __shared__ float r1[256], r2[256];
    r1[tid] = s; r2[tid] = s2; __syncthreads();
    for (int st = 128; st > 0; st >>= 1) {
        if (tid < st) { r1[tid] += r1[tid + st]; r2[tid] += r2[tid + st]; }
        __syncthreads();
    }
    if (tid == 0) {
        stats4[g4 * 2]     = r1[0];
        stats4[g4 * 2 + 1] = r2[0];
    }
}

// ref_attn += gelu_exact( (u - mean) * rstd );  bf16x8, grid = 3136 blocks.
__global__ __launch_bounds__(256) void lngelu_kernel(
    const bf16* __restrict__ u, const float* __restrict__ stats4,
    bf16* __restrict__ ref_attn)
{
    int idx8 = blockIdx.x * 256 + threadIdx.x;    // < 802816
    int g = idx8 / 12544;
    size_t base = (size_t)idx8 * 8;
    float sum = 0.f, sq = 0.f;
    #pragma unroll
    for (int q = 0; q < 4; ++q) {
        sum += stats4[(g * 4 + q) * 2];
        sq  += stats4[(g * 4 + q) * 2 + 1];
    }
    float mean = sum * (1.f / 100352.f);
    float var  = sq * (1.f / 100352.f) - mean * mean;
    var = fmaxf(var, 0.f);
    float rstd = rsqrtf(var + 1e-5f);
    V16 uv; uv.u4 = *(const uint4*)(u + base);
    V16 rv; rv.u4 = *(const uint4*)(ref_attn + base);
    bf16 outv[8];
    #pragma unroll
    for (int j = 0; j < 8; ++j) {
        unsigned shu = uv.u[j >> 1];
        unsigned shr = rv.u[j >> 1];
        unsigned bu = (j & 1) ? (shu & 0xffff0000u) : (shu << 16);
        unsigned br = (j & 1) ? (shr & 0xffff0000u) : (shr << 16);
        union { unsigned uu; float fl; } cu, cr; cu.uu = bu; cr.uu = br;
        float v = (cu.fl - mean) * rstd;
        float ge = 0.5f * v * (1.f + erff(v * 0.7071067811865476f));
        outv[j] = f2b(cr.fl + ge);
    }
    *(uint4*)(ref_attn + base) = *(uint4*)outv;
}

// ---------------------------------------------------------------------------
// qnew_pre: per row (b,n): softmax(32)@ref_v + q_sc, LN(256) -> ln_t (bf16).
// ---------------------------------------------------------------------------
__global__ __launch_bounds__(256) void qnew_pre_kernel(
    const bf16* __restrict__ qkv, const bf16* __restrict__ ref_attn,
    const float* __restrict__ ref_v_t,
    const float* __restrict__ qnw, const float* __restrict__ qnb,
    bf16* __restrict__ ln_t)
{
    int ww = threadIdx.x >> 6, lane = threadIdx.x & 63;
    int row = blockIdx.x * 4 + ww;            // < 25088
    int b = row / 49, n = row % 49;
    int r = b >> 6, w = b & 63;
    int h = lane >> 3, d0 = (lane & 7) * 4;

    const bf16* la = ref_attn + ((size_t)(((r * 8 + h) * 64 + w) * 49 + n)) * 32 + d0;
    ushort4 lu = *(const ushort4*)la;
    float lg[4] = { bu2f(lu.x), bu2f(lu.y), bu2f(lu.z), bu2f(lu.w) };

    float m = fmaxf(fmaxf(lg[0], lg[1]), fmaxf(lg[2], lg[3]));
    m = fmaxf(m, __shfl_xor(m, 1));
    m = fmaxf(m, __shfl_xor(m, 2));
    m = fmaxf(m, __shfl_xor(m, 4));
    float p[4], s = 0.f;
    #pragma unroll
    for (int j = 0; j < 4; ++j) { p[j] = __expf(lg[j] - m); s += p[j]; }
    s += __shfl_xor(s, 1);
    s += __shfl_xor(s, 2);
    s += __shfl_xor(s, 4);
    float inv = 1.f / s;
    #pragma unroll
    for (int j = 0; j < 4; ++j) p[j] *= inv;

    const float* rv = ref_v_t + ((size_t)(r * 8 + h) * 32) * 32 + d0;
    float y[4] = {0.f, 0.f, 0.f, 0.f};
    #pragma unroll
    for (int f = 0; f < 32; ++f) {
        int src = (lane & 56) | (f >> 2);
        float pf = __shfl(p[f & 3], src);
        float4 rvf = *(const float4*)(rv + f * 32);
        y[0] += pf * rvf.x; y[1] += pf * rvf.y;
        y[2] += pf * rvf.z; y[3] += pf * rvf.w;
    }

    ushort4 qu = *(const ushort4*)(qkv + (size_t)row * 768 + lane * 4);
    float z[4] = { y[0] + bu2f(qu.x), y[1] + bu2f(qu.y),
                   y[2] + bu2f(qu.z), y[3] + bu2f(qu.w) };

    float s1 = z[0] + z[1] + z[2] + z[3];
    #pragma unroll
    for (int off = 1; off < 64; off <<= 1) s1 += __shfl_xor(s1, off);
    float mean = s1 * (1.f / 256.f);
    float zc[4] = { z[0] - mean, z[1] - mean, z[2] - mean, z[3] - mean };
    float s2 = zc[0]*zc[0] + zc[1]*zc[1] + zc[2]*zc[2] + zc[3]*zc[3];
    #pragma unroll
    for (int off = 1; off < 64; off <<= 1) s2 += __shfl_xor(s2, off);
    float rstd = rsqrtf(s2 * (1.f / 256.f) + 1e-5f);

    float4 wv = *(const float4*)(qnw + lane * 4);
    float4 bv = *(const float4*)(qnb + lane * 4);
    bf16 outv[4];
    outv[0] = f2b(zc[0] * rstd * wv.x + bv.x);
    outv[1] = f2b(zc[1] * rstd * wv.y + bv.y);
    outv[2] = f2b(zc[2] * rstd * wv.z + bv.z);
    outv[3] = f2b(zc[3] * rstd * wv.w + bv.w);
    *(ushort4*)(ln_t + (size_t)row * 256 + lane * 4) = *(ushort4*)outv;
}

// ---------------------------------------------------------------------------
// MFMA window attention: ONE WAVE per (b,h), no __syncthreads.
// ---------------------------------------------------------------------------
__global__ __launch_bounds__(256) void winattn_kernel(
    const bf16* __restrict__ qkv, const bf16* __restrict__ q_new,
    const float* __restrict__ rel_bias, bf16* __restrict__ attn_out)
{
    const int wv = threadIdx.x >> 6, lane = threadIdx.x & 63;
    const int quad = lane >> 4, l15 = lane & 15;
    const int b = blockIdx.x >> 1;
    const int h = (blockIdx.x & 1) * 4 + wv;

    __shared__ bf16 lds[4 * 6912];           // per wave: P[64*72] + vT[32*72]
    bf16* P  = &lds[wv * 6912];
    bf16* vT = P + 4608;

    {
        int m = lane;
        if (m < 49) {
            const bf16* vp = qkv + ((size_t)(b * 49 + m)) * 768 + 512 + h * 32;
            V16 v0, v1, v2, v3;
            v0.u4 = *(const uint4*)(vp);
            v1.u4 = *(const uint4*)(vp + 8);
            v2.u4 = *(const uint4*)(vp + 16);
            v3.u4 = *(const uint4*)(vp + 24);
            #pragma unroll
            for (int d = 0; d < 8; ++d) {
                ((unsigned short*)vT)[d * 72 + m]        = v0.s[d];
                ((unsigned short*)vT)[(d + 8) * 72 + m]  = v1.s[d];
                ((unsigned short*)vT)[(d + 16) * 72 + m] = v2.s[d];
                ((unsigned short*)vT)[(d + 24) * 72 + m] = v3.s[d];
            }
        } else {
            #pragma unroll
            for (int d = 0; d < 32; ++d)
                ((unsigned short*)vT)[d * 72 + m] = 0;
        }
    }

    s16x8 aq[4], bk[4];
    #pragma unroll
    for (int t = 0; t < 4; ++t) {
        int qr = t * 16 + l15; qr = qr > 48 ? 48 : qr;
        aq[t] = ld16g(q_new + ((size_t)(b * 49 + qr)) * 256 + h * 32 + quad * 8);
        bk[t] = ld16g(qkv + ((size_t)(b * 49 + qr)) * 768 + 256 + h * 32 + quad * 8);
    }
    f32x4 S[4][4];
    #pragma unroll
    for (int tn = 0; tn < 4; ++tn)
        #pragma unroll
        for (int tm = 0; tm < 4; ++tm) {
            #pragma unroll
            for (int r = 0; r < 4; ++r) S[tn][tm][r] = 0.f;
            S[tn][tm] = __builtin_amdgcn_mfma_f32_16x16x32_bf16(aq[tn], bk[tm], S[tn][tm], 0, 0, 0);
        }

    int mvalid[4], mi[4], mj[4];
    #pragma unroll
    for (int tm = 0; tm < 4; ++tm) {
        int m0 = tm * 16 + l15;
        mvalid[tm] = (m0 < 49);
        int mc = m0 > 48 ? 48 : m0;
        mi[tm] = mc / 7; mj[tm] = mc - mi[tm] * 7;
    }
    #pragma unroll
    for (int tn = 0; tn < 4; ++tn) {
        #pragma unroll
        for (int r = 0; r < 4; ++r) {
            int n0 = tn * 16 + quad * 4 + r;
            int nc = n0 > 48 ? 48 : n0;
            int ni = nc / 7, nj = nc - (nc / 7) * 7;
            float vals[4];
            float mx = -1e30f;
            #pragma unroll
            for (int tm = 0; tm < 4; ++tm) {
                float v = S[tn][tm][r]
                        + rel_bias[((ni - mi[tm] + 6) * 13 + (nj - mj[tm] + 6)) * 8 + h];
                if (!mvalid[tm]) v = -1e30f;
                vals[tm] = v;
                mx = fmaxf(mx, v);
            }
            mx = fmaxf(mx, __shfl_xor(mx, 1));
            mx = fmaxf(mx, __shfl_xor(mx, 2));
            mx = fmaxf(mx, __shfl_xor(mx, 4));
            mx = fmaxf(mx, __shfl_xor(mx, 8));
            float s = 0.f;
            #pragma unroll
            for (int tm = 0; tm < 4; ++tm) { vals[tm] = __expf(vals[tm] - mx); s += vals[tm]; }
            s += __shfl_xor(s, 1);
            s += __shfl_xor(s, 2);
            s += __shfl_xor(s, 4);
            s += __shfl_xor(s, 8);
            float inv = 1.f / s;
            #pragma unroll
            for (int tm = 0; tm < 4; ++tm)
                ((unsigned short*)P)[n0 * 72 + tm * 16 + l15] = f2bs(vals[tm] * inv);
        }
    }

    f32x4 O[4][2];
    #pragma unroll
    for (int tn = 0; tn < 4; ++tn)
        #pragma unroll
        for (int td = 0; td < 2; ++td)
            #pragma unroll
            for (int r = 0; r < 4; ++r) O[tn][td][r] = 0.f;

    #pragma unroll
    for (int ks = 0; ks < 2; ++ks) {
        s16x8 bv0 = *(const s16x8*)&vT[(0 * 16 + l15) * 72 + ks * 32 + quad * 8];
        s16x8 bv1 = *(const s16x8*)&vT[(1 * 16 + l15) * 72 + ks * 32 + quad * 8];
        #pragma unroll
        for (int tn = 0; tn < 4; ++tn) {
            s16x8 ap = *(const s16x8*)&P[(tn * 16 + l15) * 72 + ks * 32 + quad * 8];
            O[tn][0] = __builtin_amdgcn_mfma_f32_16x16x32_bf16(ap, bv0, O[tn][0], 0, 0, 0);
            O[tn][1] = __builtin_amdgcn_mfma_f32_16x16x32_bf16(ap, bv1, O[tn][1], 0, 0, 0);
        }
    }

    #pragma unroll
    for (int tn = 0; tn < 4; ++tn)
        #pragma unroll
        for (int r = 0; r < 4; ++r) {
            int n0 = tn * 16 + quad * 4 + r;
            if (n0 < 49) {
                size_t base = ((size_t)(b * 49 + n0)) * 256 + h * 32;
                attn_out[base + l15]      = f2b(O[tn][0][r]);
                attn_out[base + 16 + l15] = f2b(O[tn][1][r]);
            }
        }
}

// ---------------------------------------------------------------------------
// MFMA class-token attention: ONE WAVE per (b,h), no __syncthreads.
// ---------------------------------------------------------------------------
__global__ __launch_bounds__(256) void clsattn_kernel(
    const bf16* __restrict__ tkv,
    const bf16* __restrict__ depth_q, const bf16* __restrict__ seg_q,
    bf16* __restrict__ d_pre, bf16* __restrict__ s_pre)
{
    const int wv = threadIdx.x >> 6, lane = threadIdx.x & 63;
    const int quad = lane >> 4, l15 = lane & 15;
    const int bh = blockIdx.x * 4 + wv;      // < 4096
    const int b = bh >> 3, h = bh & 7;

    __shared__ bf16 lds[4 * 5760];
    unsigned short* QP = (unsigned short*)&lds[wv * 5760];   // 16 x 72
    unsigned short* KV = QP + 1152;                          // 64 x 72 (max use 4608)

    {
        int n = lane;
        V16 dv, sv;
        if (n < 49) {
            dv.u4 = *(const uint4*)(depth_q + ((size_t)(b * 49 + n)) * 64 + h * 8);
            sv.u4 = *(const uint4*)(seg_q   + ((size_t)(b * 49 + n)) * 64 + h * 8);
        } else {
            dv.u4 = make_uint4(0, 0, 0, 0); sv.u4 = make_uint4(0, 0, 0, 0);
        }
        #pragma unroll
        for (int c = 0; c < 8; ++c) {
            QP[c * 72 + n]       = dv.s[c];
            QP[(8 + c) * 72 + n] = sv.s[c];
        }
    }
    {
        int n = lane;
        V16 k[6];
        if (n < 49) {
            const bf16* kp = tkv + ((size_t)(b * 49 + n)) * 768 + h * 48;
            #pragma unroll
            for (int c6 = 0; c6 < 6; ++c6) k[c6].u4 = *(const uint4*)(kp + c6 * 8);
        } else {
            #pragma unroll
            for (int c6 = 0; c6 < 6; ++c6) k[c6].u4 = make_uint4(0, 0, 0, 0);
        }
        #pragma unroll
        for (int c6 = 0; c6 < 6; ++c6)
            #pragma unroll
            for (int j = 0; j < 8; ++j)
                KV[(c6 * 8 + j) * 72 + n] = k[c6].s[j];
    }

    f32x4 S[3];
    #pragma unroll
    for (int t3 = 0; t3 < 3; ++t3)
        #pragma unroll
        for (int r = 0; r < 4; ++r) S[t3][r] = 0.f;
    #pragma unroll
    for (int ks = 0; ks < 2; ++ks) {
        s16x8 a = *(const s16x8*)&QP[l15 * 72 + ks * 32 + quad * 8];
        #pragma unroll
        for (int t3 = 0; t3 < 3; ++t3) {
            s16x8 bf = *(const s16x8*)&KV[(t3 * 16 + l15) * 72 + ks * 32 + quad * 8];
            S[t3] = __builtin_amdgcn_mfma_f32_16x16x32_bf16(a, bf, S[t3], 0, 0, 0);
        }
    }

    #pragma unroll
    for (int r = 0; r < 4; ++r) {
        float v0 = S[0][r], v1 = S[1][r], v2 = S[2][r];
        float mx = fmaxf(fmaxf(v0, v1), v2);
        mx = fmaxf(mx, __shfl_xor(mx, 1));
        mx = fmaxf(mx, __shfl_xor(mx, 2));
        mx = fmaxf(mx, __shfl_xor(mx, 4));
        mx = fmaxf(mx, __shfl_xor(mx, 8));
        float e0 = __expf(v0 - mx), e1 = __expf(v1 - mx), e2 = __expf(v2 - mx);
        float s = e0 + e1 + e2;
        s += __shfl_xor(s, 1);
        s += __shfl_xor(s, 2);
        s += __shfl_xor(s, 4);
        s += __shfl_xor(s, 8);
        float inv = 1.f / s;
        int c = quad * 4 + r;
        QP[c * 72 + 0 * 16 + l15] = f2bs(e0 * inv);
        QP[c * 72 + 1 * 16 + l15] = f2bs(e1 * inv);
        QP[c * 72 + 2 * 16 + l15] = f2bs(e2 * inv);
    }
    #pragma unroll
    for (int z = 0; z < 4; ++z)
        QP[(lane & 15) * 72 + 48 + (lane >> 4) * 4 + z] = 0;

    {
        int n = lane;
        V16 v[6], zv; zv.u4 = make_uint4(0, 0, 0, 0);
        if (n < 49) {
            const bf16* vp = tkv + ((size_t)(b * 49 + n)) * 768 + 384 + h * 48;
            #pragma unroll
            for (int c6 = 0; c6 < 6; ++c6) v[c6].u4 = *(const uint4*)(vp + c6 * 8);
        } else {
            #pragma unroll
            for (int c6 = 0; c6 < 6; ++c6) v[c6].u4 = zv.u4;
        }
        #pragma unroll
        for (int c6 = 0; c6 < 6; ++c6)
            *(uint4*)&KV[n * 72 + c6 * 8] = v[c6].u4;
        *(uint4*)&KV[n * 72 + 48] = zv.u4;
        *(uint4*)&KV[n * 72 + 56] = zv.u4;
    }

    f32x4 O[4];
    #pragma unroll
    for (int t4 = 0; t4 < 4; ++t4)
        #pragma unroll
        for (int r = 0; r < 4; ++r) O[t4][r] = 0.f;
    #pragma unroll
    for (int ks = 0; ks < 2; ++ks) {
        s16x8 a = *(const s16x8*)&QP[l15 * 72 + ks * 32 + quad * 8];
        #pragma unroll
        for (int t4 = 0; t4 < 4; ++t4) {
            s16x8 bf = *(const s16x8*)&KV[(t4 * 16 + l15) * 72 + ks * 32 + quad * 8];
            O[t4] = __builtin_amdgcn_mfma_f32_16x16x32_bf16(a, bf, O[t4], 0, 0, 0);
        }
    }

    #pragma unroll
    for (int t4 = 0; t4 < 4; ++t4) {
        int n = t4 * 16 + l15;
        if (n < 49) {
            size_t base = ((size_t)(b * 49 + n)) * 64 + h * 8;
            #pragma unroll
            for (int r = 0; r < 4; ++r) {
                int c = quad * 4 + r;
                if (c < 8) d_pre[base + c] = f2b(O[t4][r]);
                else       s_pre[base + c - 8] = f2b(O[t4][r]);
            }
        }
    }
}

// ---------------------------------------------------------------------------
extern "C" void kernel_launch(void* const* d_in, const int* in_sizes, int n_in,
                              void* d_out, int out_size, void* d_ws, size_t ws_size,
                              hipStream_t stream)
{
    const float* x          = (const float*)d_in[0];
    const float* x_ref      = (const float*)d_in[1];
    const float* dth_tok    = (const float*)d_in[2];
    const float* seg_tok    = (const float*)d_in[3];
    const float* qkv_w      = (const float*)d_in[4];
    const float* qkv_b      = (const float*)d_in[5];
    const float* proj_w     = (const float*)d_in[6];
    const float* proj_b     = (const float*)d_in[7];
    const float* rel_bias   = (const float*)d_in[8];
    const float* diff_mu    = (const float*)d_in[9];
    const float* diff_ls    = (const float*)d_in[10];
    const float* ref_qk_w   = (const float*)d_in[11];
    const float* ref_qk_b   = (const float*)d_in[12];
    const float* conv_w     = (const float*)d_in[13];
    const float* conv_b     = (const float*)d_in[14];
    const float* q_norm_w   = (const float*)d_in[15];
    const float* q_norm_b   = (const float*)d_in[16];
    const float* q_proj_w   = (const float*)d_in[17];
    const float* q_proj_b   = (const float*)d_in[18];
    const float* cls_dth_w  = (const float*)d_in[19];
    const float* cls_dth_b  = (const float*)d_in[20];
    const float* cls_seg_w  = (const float*)d_in[21];
    const float* cls_seg_b  = (const float*)d_in[22];
    const float* glob_k_w   = (const float*)d_in[23];
    const float* glob_k_b   = (const float*)d_in[24];
    const float* glob_v_w   = (const float*)d_in[25];
    const float* glob_v_b   = (const float*)d_in[26];
    const float* proj_dth_w = (const float*)d_in[27];
    const float* proj_dth_b = (const float*)d_in[28];

    // ---- workspace layout ----
    bf16* wsb = (bf16*)d_ws;
    bf16* qkv      = wsb;                      // [25088,768]; later tkv [25088,768]
    bf16* tkv      = wsb;
    bf16* ref_attn = wsb + 19267584;           // R1
    bf16* q_new    = ref_attn;
    bf16* out0b    = ref_attn;
    bf16* depth_q  = ref_attn;
    bf16* seg_q    = ref_attn + 1605632;
    bf16* d_pre    = ref_attn + 3211264;
    bf16* s_pre    = ref_attn + 4816896;
    bf16* u_buf    = wsb + 25690112;           // R3
    bf16* xb       = u_buf;
    bf16* ln_t     = u_buf;
    bf16* attn_out = u_buf;
    float* ref_qk  = (float*)((char*)d_ws + 64225280);
    bf16*  rq_b    = (bf16*)(ref_qk + 131072);     // [64,32,32] bf16 (scaled)
    float* ref_v_t = ref_qk + 131072 + 65536;      // [64,32,32] f32
    float* stats4  = ref_qk;                       // 512 f32, reuses dead ref_qk

    float* out0  = (float*)d_out;
    float* out_d = out0 + 6422528;
    float* out_s = out0 + 8028160;

    // scratch in output regions (dead until final small64)
    bf16* Wt_all = (bf16*)out_d;               // 622592 elems = 1.19 MiB
    bf16* tokb   = (bf16*)out_s;               // [25088,128] bf16 = 6.125 MiB

    // 0. all input prep in one launch
    prep_all<<<10272, 256, 0, stream>>>(qkv_w, q_proj_w, proj_w, glob_k_w, glob_v_w,
                                        Wt_all, x, xb, dth_tok, seg_tok, tokb);

    // 1. qkv = x @ qkv_w + b
    gemm_pipe<0><<<dim3(6, 196), 256, 0, stream>>>(xb, 256, nullptr,
        Wt_all, qkv_b, nullptr, nullptr, 0, nullptr, qkv, 768, 256, 768, 1.f);
    // 2. ref_qk = x_ref @ ref_qk_w + b (small)
    mfma_gemm<<<dim3(8, 4), 256, 0, stream>>>(x_ref, 0, ref_qk_w, ref_qk_b,
                                              ref_qk, nullptr, 256, 256, 512, 1.f);
    // 3. rq_b (bf16, scaled) / ref_v_t
    refprep_kernel<<<256, 256, 0, stream>>>(ref_qk, diff_mu, diff_ls, rq_b, ref_v_t);
    // 4. ref_attn scores (MFMA, 1 wave per (rh,w))
    refattn_kernel<<<1024, 256, 0, stream>>>(qkv, rq_b, ref_attn);
    // 5. 3x diffusion
    for (int it = 0; it < 3; ++it) {
        conv_kernel<<<392, 256, 0, stream>>>(ref_attn, conv_w, conv_b, u_buf);
        lnstats_kernel<<<256, 256, 0, stream>>>(u_buf, stats4);
        lngelu_kernel<<<3136, 256, 0, stream>>>(u_buf, stats4, ref_attn);
    }
    // 6. softmax @ ref_v + shortcut + LN -> ln_t
    qnew_pre_kernel<<<6272, 256, 0, stream>>>(qkv, ref_attn, ref_v_t,
                                              q_norm_w, q_norm_b, ln_t);
    // 7. q_new = (ln_t @ q_proj_w + b + qsc) * SCALE
    gemm_pipe<0><<<dim3(2, 196), 256, 0, stream>>>(ln_t, 256, nullptr,
        Wt_all + 196608, q_proj_b, nullptr, qkv, 768, nullptr, q_new, 256, 256, 256, SCALE_T);
    // 8. window attention
    winattn_kernel<<<1024, 256, 0, stream>>>(qkv, q_new, rel_bias, attn_out);
    // 9. out0 = attn_out @ proj_w + b   (f32 to d_out, bf16 copy to out0b)
    gemm_pipe<0><<<dim3(2, 196), 256, 0, stream>>>(attn_out, 256, nullptr,
        Wt_all + 262144, proj_b, nullptr, nullptr, 0, out0, out0b, 256, 256, 256, 1.f);
    // 10. fused t_k|t_v = concat(out0b, tokb) @ [gk|gv] + b -> tkv [25088,768]
    gemm_pipe<1><<<dim3(6, 196), 256, 0, stream>>>(out0b, 256, tokb,
        Wt_all + 327680, glob_k_b, glob_v_b, nullptr, 0, nullptr, tkv, 768, 384, 768, 1.f);
    // 12/13. depth_q, seg_q in ONE launch
    small64<1, 0><<<dim3(392, 2), 256, 0, stream>>>(dth_tok, seg_tok,
        cls_dth_w, cls_seg_w, cls_dth_b, cls_seg_b, depth_q, seg_q, SCALE_T);
    // 14. class-token attention
    clsattn_kernel<<<1024, 256, 0, stream>>>(tkv, depth_q, seg_q, d_pre, s_pre);
    // 15/16. final proj_dth in ONE launch (f32 out; overwrites Wt/tokb scratch)
    small64<0, 1><<<dim3(392, 2), 256, 0, stream>>>(d_pre, s_pre,
        proj_dth_w, proj_dth_w, proj_dth_b, proj_dth_b, out_d, out_s, 1.f);
}